// Round 2
// baseline (498.115 us; speedup 1.0000x reference)
//
#include <hip/hip_runtime.h>
#include <math.h>

#define HW 4096
#define NB 8
#define NK 19
#define CIN 512
#define CTC 256

// ---------------------------------------------------------------------------
// K1: per-pixel argmax over K=19 logits; per-class max/sum-exp (masked softmax
// over pixels of that class); outputs: cls[B,HW], normalized wgt[B,HW],
// countf[B,K].
// ---------------------------------------------------------------------------
__global__ __launch_bounds__(256) void k1_stats(
    const float* __restrict__ preds, int* __restrict__ cls_g,
    float* __restrict__ wgt_g, float* __restrict__ countf_g) {
  int b = blockIdx.x;
  __shared__ float s_lds[HW];
  __shared__ unsigned char c_lds[HW];
  __shared__ unsigned int Mu[NK];
  __shared__ float Mf[NK];
  __shared__ float Zf[NK];
  __shared__ unsigned int cnt[NK];
  int tid = threadIdx.x;
  if (tid < NK) { Mu[tid] = 0u; Zf[tid] = 0.f; cnt[tid] = 0u; }
  __syncthreads();
  const float* pb = preds + (size_t)b * NK * HW;
  for (int p = tid; p < HW; p += 256) {
    float best = pb[p];
    int bi = 0;
#pragma unroll
    for (int k = 1; k < NK; ++k) {
      float v = pb[k * HW + p];
      if (v > best) { best = v; bi = k; }  // strict > keeps first index (jnp.argmax)
    }
    s_lds[p] = best;
    c_lds[p] = (unsigned char)bi;
    unsigned int fb = __float_as_uint(best);
    // order-preserving uint key for float atomicMax
    unsigned int key = (fb & 0x80000000u) ? ~fb : (fb | 0x80000000u);
    atomicMax(&Mu[bi], key);
    atomicAdd(&cnt[bi], 1u);
  }
  __syncthreads();
  if (tid < NK) {
    unsigned int key = Mu[tid];
    float m = -1e30f;
    if (key != 0u) {
      unsigned int fb = (key & 0x80000000u) ? (key & 0x7fffffffu) : ~key;
      m = __uint_as_float(fb);
    }
    Mf[tid] = m;
  }
  __syncthreads();
  for (int p = tid; p < HW; p += 256) {
    int c = c_lds[p];
    float e = expf(s_lds[p] - Mf[c]);
    s_lds[p] = e;
    atomicAdd(&Zf[c], e);
  }
  __syncthreads();
  for (int p = tid; p < HW; p += 256) {
    int c = c_lds[p];
    wgt_g[b * HW + p] = s_lds[p] / Zf[c];
    cls_g[b * HW + p] = c;
  }
  if (tid < NK) countf_g[b * NK + tid] = (float)cnt[tid];
}

// ---------------------------------------------------------------------------
// K2: cls_feat[b,k,c] = sum_p wgt[p]*[cls(p)==k]*x[b,c,p]. Predicated
// accumulation into 19 per-thread registers, partial sums over a 512-pixel
// chunk, global atomicAdd. cls_feat must be zeroed before launch.
// ---------------------------------------------------------------------------
__global__ __launch_bounds__(64) void k2_clsfeat(
    const float* __restrict__ x, const float* __restrict__ wgt_g,
    const int* __restrict__ cls_g, float* __restrict__ cls_feat) {
  int b = blockIdx.z;
  int c = blockIdx.y * 64 + threadIdx.x;
  int p0 = blockIdx.x * 512;
  __shared__ float wl[512];
  __shared__ int cl[512];
  for (int i = threadIdx.x; i < 512; i += 64) {
    wl[i] = wgt_g[b * HW + p0 + i];
    cl[i] = cls_g[b * HW + p0 + i];
  }
  __syncthreads();
  float acc[NK];
#pragma unroll
  for (int k = 0; k < NK; ++k) acc[k] = 0.f;
  const float* xr = x + ((size_t)b * CIN + c) * HW + p0;
  for (int i = 0; i < 512; ++i) {
    float t = xr[i] * wl[i];
    int cc = cl[i];
#pragma unroll
    for (int k = 0; k < NK; ++k) acc[k] += (cc == k) ? t : 0.f;
  }
#pragma unroll
  for (int k = 0; k < NK; ++k)
    atomicAdd(&cls_feat[((size_t)b * NK + k) * CIN + c], acc[k]);
}

// ---------------------------------------------------------------------------
// K3: per-(b,class) tiny projections of the 512-d class descriptor:
// Kcls = proj2_k(proj1_k(cf)), Vcls = projv(cf). Stored as [b][CT][NK].
// ---------------------------------------------------------------------------
__global__ __launch_bounds__(256) void k3_kv(
    const float* __restrict__ cls_feat,
    const float* __restrict__ kw1, const float* __restrict__ kg1, const float* __restrict__ kb1,
    const float* __restrict__ kw2, const float* __restrict__ kg2, const float* __restrict__ kb2,
    const float* __restrict__ vw, const float* __restrict__ vg, const float* __restrict__ vb,
    float* __restrict__ Kcls, float* __restrict__ Vcls) {
  int bk = blockIdx.x;
  int b = bk / NK, kc = bk % NK;
  __shared__ float cf[CIN];
  __shared__ float h1[CTC];
  int tid = threadIdx.x;
  const float* row = cls_feat + ((size_t)b * NK + kc) * CIN;
  for (int i = tid; i < CIN; i += 256) cf[i] = row[i];
  __syncthreads();
  {
    const float* wr = kw1 + (size_t)tid * CIN;
    float s = 0.f;
    for (int c2 = 0; c2 < CIN; ++c2) s += wr[c2] * cf[c2];
    h1[tid] = fmaxf(s * kg1[tid] + kb1[tid], 0.f);
  }
  {
    const float* wr = vw + (size_t)tid * CIN;
    float s = 0.f;
    for (int c2 = 0; c2 < CIN; ++c2) s += wr[c2] * cf[c2];
    Vcls[((size_t)b * CTC + tid) * NK + kc] = fmaxf(s * vg[tid] + vb[tid], 0.f);
  }
  __syncthreads();
  {
    const float* wr = kw2 + (size_t)tid * CTC;
    float s = 0.f;
    for (int c2 = 0; c2 < CTC; ++c2) s += wr[c2] * h1[c2];
    Kcls[((size_t)b * CTC + tid) * NK + kc] = fmaxf(s * kg2[tid] + kb2[tid], 0.f);
  }
}

// ---------------------------------------------------------------------------
// GEMM: Y[b,m,p] = relu(g[m]*(sum_k W[m,k]*X[b,k,p]) + bias[m]).
// 64x64 tile, BK=16, 256 threads, 4x4 micro-tile. f32 (round 1).
// ---------------------------------------------------------------------------
template <int KDIM>
__global__ __launch_bounds__(256) void gemm_proj(
    const float* __restrict__ X, const float* __restrict__ W,
    const float* __restrict__ g, const float* __restrict__ bb,
    float* __restrict__ Y, int M) {
  __shared__ float Al[16][68];  // [k][m], row stride 68 floats (16B-aligned, pad)
  __shared__ float Xl[16][64];  // [k][p]
  int b = blockIdx.z;
  int m0 = blockIdx.y * 64;
  int p0 = blockIdx.x * 64;
  int tid = threadIdx.x;
  int tx = tid & 15, ty = tid >> 4;
  float acc[4][4] = {};
  const float* Xb = X + (size_t)b * KDIM * HW;
  for (int k0 = 0; k0 < KDIM; k0 += 16) {
    {
      int ml = tid >> 2, kq = (tid & 3) * 4;
      float4 v = *(const float4*)&W[(size_t)(m0 + ml) * KDIM + k0 + kq];
      Al[kq + 0][ml] = v.x;
      Al[kq + 1][ml] = v.y;
      Al[kq + 2][ml] = v.z;
      Al[kq + 3][ml] = v.w;
    }
    {
      int kl = tid >> 4, pq = (tid & 15) * 4;
      float4 v = *(const float4*)&Xb[(size_t)(k0 + kl) * HW + p0 + pq];
      *(float4*)&Xl[kl][pq] = v;
    }
    __syncthreads();
#pragma unroll
    for (int k = 0; k < 16; ++k) {
      float4 a = *(const float4*)&Al[k][ty * 4];
      float4 xv = *(const float4*)&Xl[k][tx * 4];
      float av[4] = {a.x, a.y, a.z, a.w};
      float xvv[4] = {xv.x, xv.y, xv.z, xv.w};
#pragma unroll
      for (int i = 0; i < 4; ++i)
#pragma unroll
        for (int j = 0; j < 4; ++j) acc[i][j] += av[i] * xvv[j];
    }
    __syncthreads();
  }
#pragma unroll
  for (int i = 0; i < 4; ++i) {
    int m = m0 + ty * 4 + i;
    float gm = g[m], bm = bb[m];
    float4 o;
    o.x = fmaxf(acc[i][0] * gm + bm, 0.f);
    o.y = fmaxf(acc[i][1] * gm + bm, 0.f);
    o.z = fmaxf(acc[i][2] * gm + bm, 0.f);
    o.w = fmaxf(acc[i][3] * gm + bm, 0.f);
    *(float4*)&Y[((size_t)b * M + m) * HW + p0 + tx * 4] = o;
  }
}

// ---------------------------------------------------------------------------
// K5: collapsed attention. Per pixel: simc[k] = (1/16)*sum_c q2[b,c,p]*Kcls[c,k];
// u_k = count_k*exp(simc_k - m); ctx[b,c,p] = sum_k (u_k/Σu)*Vcls[c,k].
// Exactly equals softmax over 4096 pixels grouped by class.
// ---------------------------------------------------------------------------
__global__ __launch_bounds__(256) void k5_ctx(
    const float* __restrict__ q2, const float* __restrict__ Kcls,
    const float* __restrict__ Vcls, const float* __restrict__ countf,
    float* __restrict__ ctx) {
  int b = blockIdx.y;
  int p = blockIdx.x * 256 + threadIdx.x;
  __shared__ float Kl[CTC * NK];
  __shared__ float Vl[CTC * NK];
  __shared__ float cntl[NK];
  int tid = threadIdx.x;
  for (int i = tid; i < CTC * NK; i += 256) {
    Kl[i] = Kcls[(size_t)b * CTC * NK + i];
    Vl[i] = Vcls[(size_t)b * CTC * NK + i];
  }
  if (tid < NK) cntl[tid] = countf[b * NK + tid];
  __syncthreads();
  float sim[NK];
#pragma unroll
  for (int k = 0; k < NK; ++k) sim[k] = 0.f;
  const float* qb = q2 + (size_t)b * CTC * HW + p;
  for (int c = 0; c < CTC; ++c) {
    float qv = qb[(size_t)c * HW];
#pragma unroll
    for (int k = 0; k < NK; ++k) sim[k] += qv * Kl[c * NK + k];
  }
  const float scale = 0.0625f;  // 256^-0.5
  float m = -1e30f;
#pragma unroll
  for (int k = 0; k < NK; ++k) {
    sim[k] *= scale;
    if (cntl[k] > 0.f) m = fmaxf(m, sim[k]);
  }
  float u[NK];
  float d = 0.f;
#pragma unroll
  for (int k = 0; k < NK; ++k) {
    float e = (cntl[k] > 0.f) ? expf(sim[k] - m) : 0.f;  // guard 0*inf
    u[k] = cntl[k] * e;
    d += u[k];
  }
  float inv = 1.f / d;
#pragma unroll
  for (int k = 0; k < NK; ++k) u[k] *= inv;
  float* cb = ctx + (size_t)b * CTC * HW + p;
  for (int c = 0; c < CTC; ++c) {
    float s = 0.f;
#pragma unroll
    for (int k = 0; k < NK; ++k) s += u[k] * Vl[c * NK + k];
    cb[(size_t)c * HW] = s;
  }
}

// ---------------------------------------------------------------------------
extern "C" void kernel_launch(void* const* d_in, const int* in_sizes, int n_in,
                              void* d_out, int out_size, void* d_ws, size_t ws_size,
                              hipStream_t stream) {
  const float* x = (const float*)d_in[0];
  const float* preds = (const float*)d_in[1];
  // d_in[2] = feats_il: unused by the reference
  const float* q_w1 = (const float*)d_in[3];
  const float* q_g1 = (const float*)d_in[4];
  const float* q_b1 = (const float*)d_in[5];
  const float* q_w2 = (const float*)d_in[6];
  const float* q_g2 = (const float*)d_in[7];
  const float* q_b2 = (const float*)d_in[8];
  const float* k_w1 = (const float*)d_in[9];
  const float* k_g1 = (const float*)d_in[10];
  const float* k_b1 = (const float*)d_in[11];
  const float* k_w2 = (const float*)d_in[12];
  const float* k_g2 = (const float*)d_in[13];
  const float* k_b2 = (const float*)d_in[14];
  const float* v_w = (const float*)d_in[15];
  const float* v_g = (const float*)d_in[16];
  const float* v_b = (const float*)d_in[17];
  const float* o_w = (const float*)d_in[18];
  const float* o_g = (const float*)d_in[19];
  const float* o_b = (const float*)d_in[20];
  float* out = (float*)d_out;

  // workspace layout (floats)
  float* ws = (float*)d_ws;
  float* q1 = ws;                          // 8*256*4096
  float* q2 = q1 + (size_t)NB * CTC * HW;  // 8*256*4096
  float* wgt = q2 + (size_t)NB * CTC * HW; // 8*4096
  int* cls = (int*)(wgt + NB * HW);        // 8*4096
  float* countf = (float*)(cls + NB * HW); // 256
  float* cls_feat = countf + 256;          // 8*19*512
  float* Kcls = cls_feat + NB * NK * CIN;  // 8*256*19
  float* Vcls = Kcls + NB * CTC * NK;      // 8*256*19
  float* ctx = q1;                         // reuse q1 (dead after q2)

  hipMemsetAsync(cls_feat, 0, (size_t)NB * NK * CIN * sizeof(float), stream);

  k1_stats<<<NB, 256, 0, stream>>>(preds, cls, wgt, countf);
  k2_clsfeat<<<dim3(8, 8, NB), 64, 0, stream>>>(x, wgt, cls, cls_feat);
  k3_kv<<<NB * NK, 256, 0, stream>>>(cls_feat, k_w1, k_g1, k_b1, k_w2, k_g2,
                                     k_b2, v_w, v_g, v_b, Kcls, Vcls);
  gemm_proj<CIN><<<dim3(64, CTC / 64, NB), 256, 0, stream>>>(x, q_w1, q_g1,
                                                             q_b1, q1, CTC);
  gemm_proj<CTC><<<dim3(64, CTC / 64, NB), 256, 0, stream>>>(q1, q_w2, q_g2,
                                                             q_b2, q2, CTC);
  k5_ctx<<<dim3(HW / 256, NB), 256, 0, stream>>>(q2, Kcls, Vcls, countf, ctx);
  gemm_proj<CTC><<<dim3(64, CIN / 64, NB), 256, 0, stream>>>(ctx, o_w, o_g,
                                                             o_b, out, CIN);
}

// Round 3
// 287.077 us; speedup vs baseline: 1.7351x; 1.7351x over previous
//
#include <hip/hip_runtime.h>
#include <math.h>

#define HW 4096
#define NB 8
#define NK 19
#define CIN 512
#define CTC 256

typedef __attribute__((ext_vector_type(8))) short short8;
typedef __attribute__((ext_vector_type(4))) float f32x4;

__device__ inline unsigned short f2bf(float x) {
  unsigned u = __float_as_uint(x);
  return (unsigned short)((u + 0x7fffu + ((u >> 16) & 1u)) >> 16);  // RNE
}
__device__ inline float bf2f(unsigned short h) {
  return __uint_as_float(((unsigned)h) << 16);
}
__device__ inline void gload16(const void* g, void* l) {
  __builtin_amdgcn_global_load_lds(
      (const __attribute__((address_space(1))) void*)g,
      (__attribute__((address_space(3))) void*)l, 16, 0, 0);
}

// ---------------------------------------------------------------------------
// Weight f32 -> bf16 convert (q_w1, q_w2, o_w).
// ---------------------------------------------------------------------------
__global__ __launch_bounds__(256) void wconv(
    const float* __restrict__ w1, const float* __restrict__ w2,
    const float* __restrict__ wo, unsigned short* __restrict__ wb1,
    unsigned short* __restrict__ wb2, unsigned short* __restrict__ wbo) {
  int i = (blockIdx.x * 256 + threadIdx.x) * 4;
  const float* src;
  unsigned short* dst;
  int off;
  if (i < 131072) { src = w1; dst = wb1; off = i; }
  else if (i < 196608) { src = w2; dst = wb2; off = i - 131072; }
  else { src = wo; dst = wbo; off = i - 196608; }
  float4 v = *(const float4*)(src + off);
  dst[off + 0] = f2bf(v.x);
  dst[off + 1] = f2bf(v.y);
  dst[off + 2] = f2bf(v.z);
  dst[off + 3] = f2bf(v.w);
}

// ---------------------------------------------------------------------------
// x [B][CIN][HW] f32  ->  xT [B][HW][CIN] bf16  (LDS 64x64 tile transpose)
// ---------------------------------------------------------------------------
__global__ __launch_bounds__(256) void xpose(const float* __restrict__ x,
                                             unsigned short* __restrict__ xT) {
  __shared__ float tile[64][65];  // pad 65: column reads conflict-free
  int b = blockIdx.z, c0 = blockIdx.y * 64, p0 = blockIdx.x * 64;
  int tid = threadIdx.x;
  int l = tid & 63, wid = tid >> 6;
#pragma unroll
  for (int r = 0; r < 4; ++r) {
    int cl = r * 16 + (tid >> 4);
    int pl = (tid & 15) * 4;
    float4 v = *(const float4*)&x[((size_t)b * CIN + c0 + cl) * HW + p0 + pl];
    tile[cl][pl + 0] = v.x;
    tile[cl][pl + 1] = v.y;
    tile[cl][pl + 2] = v.z;
    tile[cl][pl + 3] = v.w;
  }
  __syncthreads();
#pragma unroll
  for (int j = 0; j < 16; ++j) {
    int ploc = j * 4 + wid;  // one row per wave per iter -> 128B contiguous
    xT[((size_t)b * HW + p0 + ploc) * CIN + c0 + l] = f2bf(tile[l][ploc]);
  }
}

// ---------------------------------------------------------------------------
// K1: per-pixel argmax + per-class masked softmax stats (unchanged, verified).
// ---------------------------------------------------------------------------
__global__ __launch_bounds__(256) void k1_stats(
    const float* __restrict__ preds, int* __restrict__ cls_g,
    float* __restrict__ wgt_g, float* __restrict__ countf_g) {
  int b = blockIdx.x;
  __shared__ float s_lds[HW];
  __shared__ unsigned char c_lds[HW];
  __shared__ unsigned int Mu[NK];
  __shared__ float Mf[NK];
  __shared__ float Zf[NK];
  __shared__ unsigned int cnt[NK];
  int tid = threadIdx.x;
  if (tid < NK) { Mu[tid] = 0u; Zf[tid] = 0.f; cnt[tid] = 0u; }
  __syncthreads();
  const float* pb = preds + (size_t)b * NK * HW;
  for (int p = tid; p < HW; p += 256) {
    float best = pb[p];
    int bi = 0;
#pragma unroll
    for (int k = 1; k < NK; ++k) {
      float v = pb[k * HW + p];
      if (v > best) { best = v; bi = k; }
    }
    s_lds[p] = best;
    c_lds[p] = (unsigned char)bi;
    unsigned int fb = __float_as_uint(best);
    unsigned int key = (fb & 0x80000000u) ? ~fb : (fb | 0x80000000u);
    atomicMax(&Mu[bi], key);
    atomicAdd(&cnt[bi], 1u);
  }
  __syncthreads();
  if (tid < NK) {
    unsigned int key = Mu[tid];
    float m = -1e30f;
    if (key != 0u) {
      unsigned int fb = (key & 0x80000000u) ? (key & 0x7fffffffu) : ~key;
      m = __uint_as_float(fb);
    }
    Mf[tid] = m;
  }
  __syncthreads();
  for (int p = tid; p < HW; p += 256) {
    int c = c_lds[p];
    float e = expf(s_lds[p] - Mf[c]);
    s_lds[p] = e;
    atomicAdd(&Zf[c], e);
  }
  __syncthreads();
  for (int p = tid; p < HW; p += 256) {
    int c = c_lds[p];
    wgt_g[b * HW + p] = s_lds[p] / Zf[c];
    cls_g[b * HW + p] = c;
  }
  if (tid < NK) countf_g[b * NK + tid] = (float)cnt[tid];
}

// ---------------------------------------------------------------------------
// K2: cls_feat[b,k,c] accumulation (unchanged, verified).
// ---------------------------------------------------------------------------
__global__ __launch_bounds__(64) void k2_clsfeat(
    const float* __restrict__ x, const float* __restrict__ wgt_g,
    const int* __restrict__ cls_g, float* __restrict__ cls_feat) {
  int b = blockIdx.z;
  int c = blockIdx.y * 64 + threadIdx.x;
  int p0 = blockIdx.x * 512;
  __shared__ float wl[512];
  __shared__ int cl[512];
  for (int i = threadIdx.x; i < 512; i += 64) {
    wl[i] = wgt_g[b * HW + p0 + i];
    cl[i] = cls_g[b * HW + p0 + i];
  }
  __syncthreads();
  float acc[NK];
#pragma unroll
  for (int k = 0; k < NK; ++k) acc[k] = 0.f;
  const float* xr = x + ((size_t)b * CIN + c) * HW + p0;
  for (int i = 0; i < 512; ++i) {
    float t = xr[i] * wl[i];
    int cc = cl[i];
#pragma unroll
    for (int k = 0; k < NK; ++k) acc[k] += (cc == k) ? t : 0.f;
  }
#pragma unroll
  for (int k = 0; k < NK; ++k)
    atomicAdd(&cls_feat[((size_t)b * NK + k) * CIN + c], acc[k]);
}

// ---------------------------------------------------------------------------
// K3: tiny per-(b,class) K/V projections, f32 (unchanged, verified).
// ---------------------------------------------------------------------------
__global__ __launch_bounds__(256) void k3_kv(
    const float* __restrict__ cls_feat,
    const float* __restrict__ kw1, const float* __restrict__ kg1, const float* __restrict__ kb1,
    const float* __restrict__ kw2, const float* __restrict__ kg2, const float* __restrict__ kb2,
    const float* __restrict__ vw, const float* __restrict__ vg, const float* __restrict__ vb,
    float* __restrict__ Kcls, float* __restrict__ Vcls) {
  int bk = blockIdx.x;
  int b = bk / NK, kc = bk % NK;
  __shared__ float cf[CIN];
  __shared__ float h1[CTC];
  int tid = threadIdx.x;
  const float* row = cls_feat + ((size_t)b * NK + kc) * CIN;
  for (int i = tid; i < CIN; i += 256) cf[i] = row[i];
  __syncthreads();
  {
    const float* wr = kw1 + (size_t)tid * CIN;
    float s = 0.f;
    for (int c2 = 0; c2 < CIN; ++c2) s += wr[c2] * cf[c2];
    h1[tid] = fmaxf(s * kg1[tid] + kb1[tid], 0.f);
  }
  {
    const float* wr = vw + (size_t)tid * CIN;
    float s = 0.f;
    for (int c2 = 0; c2 < CIN; ++c2) s += wr[c2] * cf[c2];
    Vcls[((size_t)b * CTC + tid) * NK + kc] = fmaxf(s * vg[tid] + vb[tid], 0.f);
  }
  __syncthreads();
  {
    const float* wr = kw2 + (size_t)tid * CTC;
    float s = 0.f;
    for (int c2 = 0; c2 < CTC; ++c2) s += wr[c2] * h1[c2];
    Kcls[((size_t)b * CTC + tid) * NK + kc] = fmaxf(s * kg2[tid] + kb2[tid], 0.f);
  }
}

// ---------------------------------------------------------------------------
// MFMA GEMM: D[n][m] = sum_k A[n][k] * W[m][k], A bf16 [B][4096][KD] (xT-style),
// W bf16 [M][KD]. 128x128 tile, BK=32, 4 waves, double-buffered LDS via
// global_load_lds (source-swizzled so ds_read_b128 is bank-conflict-free).
// Epilogue: relu(g*acc+b); outmode 0: f32 [b][M][HW]; 1: bf16 T [b][HW][M].
// ---------------------------------------------------------------------------
template <int KD>
__global__ __launch_bounds__(256) void gemm_mfma(
    const unsigned short* __restrict__ A, const unsigned short* __restrict__ Wb,
    const float* __restrict__ g, const float* __restrict__ bb,
    void* __restrict__ Y, int M, int outmode) {
  __shared__ __align__(16) unsigned short As[2][128 * 32];
  __shared__ __align__(16) unsigned short Bs[2][128 * 32];
  int b = blockIdx.z;
  int n0 = blockIdx.x * 128;
  int m0 = blockIdx.y * 128;
  int tid = threadIdx.x;
  int l = tid & 63, wid = tid >> 6;
  int wr = wid >> 1, wc = wid & 1;  // wave sub-tile: rows n += wr*64, cols m += wc*64
  const unsigned short* Ab = A + (size_t)b * HW * KD;

  f32x4 acc[4][4];
#pragma unroll
  for (int i = 0; i < 4; ++i)
#pragma unroll
    for (int j = 0; j < 4; ++j) acc[i][j] = (f32x4){0.f, 0.f, 0.f, 0.f};

  const int NT = KD / 32;
  // staging: LDS linear [row][32k]; source k-slot XOR'd by (row>>1)&3 so the
  // swizzled READ below is conflict-free (both-sides rule).
  auto STAGE = [&](int buf, int t) {
    int k0 = t * 32;
#pragma unroll
    for (int q = 0; q < 2; ++q) {
      int e = q * 2048 + tid * 8;
      int rl = e >> 5, sl = (e >> 3) & 3;
      gload16(Ab + (size_t)(n0 + rl) * KD + k0 + 8 * (sl ^ ((rl >> 1) & 3)),
              &As[buf][q * 2048 + wid * 512]);
    }
#pragma unroll
    for (int q = 0; q < 2; ++q) {
      int e = q * 2048 + tid * 8;
      int rl = e >> 5, sl = (e >> 3) & 3;
      gload16(Wb + (size_t)(m0 + rl) * KD + k0 + 8 * (sl ^ ((rl >> 1) & 3)),
              &Bs[buf][q * 2048 + wid * 512]);
    }
  };
  STAGE(0, 0);
  for (int t = 0; t < NT; ++t) {
    __syncthreads();  // drains vmcnt: buf[t&1] staged; other buf's reads done
    if (t + 1 < NT) STAGE((t + 1) & 1, t + 1);
    int cur = t & 1;
    short8 af[4], bf[4];
#pragma unroll
    for (int f = 0; f < 4; ++f) {
      int nl = wr * 64 + f * 16 + (l & 15);
      af[f] = *(const short8*)&As[cur][nl * 32 + 8 * ((l >> 4) ^ ((nl >> 1) & 3))];
      int ml = wc * 64 + f * 16 + (l & 15);
      bf[f] = *(const short8*)&Bs[cur][ml * 32 + 8 * ((l >> 4) ^ ((ml >> 1) & 3))];
    }
#pragma unroll
    for (int i = 0; i < 4; ++i)
#pragma unroll
      for (int j = 0; j < 4; ++j)
        acc[i][j] =
            __builtin_amdgcn_mfma_f32_16x16x32_bf16(af[i], bf[j], acc[i][j], 0, 0, 0);
  }
  // epilogue: lane holds m = base+(l&15), n = base+(l>>4)*4 + reg (4 consecutive)
  if (outmode == 0) {
    float* Yf = (float*)Y + (size_t)b * M * HW;
#pragma unroll
    for (int j = 0; j < 4; ++j) {
      int m = m0 + wc * 64 + j * 16 + (l & 15);
      float gm = g[m], bm = bb[m];
#pragma unroll
      for (int i = 0; i < 4; ++i) {
        int n = n0 + wr * 64 + i * 16 + (l >> 4) * 4;
        float4 o;
        o.x = fmaxf(acc[i][j][0] * gm + bm, 0.f);
        o.y = fmaxf(acc[i][j][1] * gm + bm, 0.f);
        o.z = fmaxf(acc[i][j][2] * gm + bm, 0.f);
        o.w = fmaxf(acc[i][j][3] * gm + bm, 0.f);
        *(float4*)&Yf[(size_t)m * HW + n] = o;
      }
    }
  } else {
    unsigned short* Yt = (unsigned short*)Y + (size_t)b * HW * M;
#pragma unroll
    for (int j = 0; j < 4; ++j) {
      int m = m0 + wc * 64 + j * 16 + (l & 15);
      float gm = g[m], bm = bb[m];
#pragma unroll
      for (int i = 0; i < 4; ++i) {
        int n = n0 + wr * 64 + i * 16 + (l >> 4) * 4;
#pragma unroll
        for (int r = 0; r < 4; ++r)
          Yt[(size_t)(n + r) * M + m] = f2bf(fmaxf(acc[i][j][r] * gm + bm, 0.f));
      }
    }
  }
}

// ---------------------------------------------------------------------------
// K5: collapsed attention on transposed bf16 activations.
// q2T [b][p][CTC] bf16 -> ctxT [b][p][CTC] bf16.
// ---------------------------------------------------------------------------
__global__ __launch_bounds__(256) void k5_ctx(
    const unsigned short* __restrict__ q2T, const float* __restrict__ Kcls,
    const float* __restrict__ Vcls, const float* __restrict__ countf,
    unsigned short* __restrict__ ctxT) {
  int b = blockIdx.y;
  int p = blockIdx.x * 256 + threadIdx.x;
  __shared__ float Kl[CTC * NK];
  __shared__ float Vl[CTC * NK];
  __shared__ float cntl[NK];
  int tid = threadIdx.x;
  for (int i = tid; i < CTC * NK; i += 256) {
    Kl[i] = Kcls[(size_t)b * CTC * NK + i];
    Vl[i] = Vcls[(size_t)b * CTC * NK + i];
  }
  if (tid < NK) cntl[tid] = countf[b * NK + tid];
  __syncthreads();
  float sim[NK];
#pragma unroll
  for (int k = 0; k < NK; ++k) sim[k] = 0.f;
  const unsigned short* q = q2T + ((size_t)b * HW + p) * CTC;
  for (int c0 = 0; c0 < CTC; c0 += 8) {
    short8 v = *(const short8*)&q[c0];
    float qv[8];
#pragma unroll
    for (int i = 0; i < 8; ++i) qv[i] = bf2f((unsigned short)v[i]);
#pragma unroll
    for (int i = 0; i < 8; ++i)
#pragma unroll
      for (int k = 0; k < NK; ++k) sim[k] += qv[i] * Kl[(c0 + i) * NK + k];
  }
  const float scale = 0.0625f;  // 256^-0.5
  float m = -1e30f;
#pragma unroll
  for (int k = 0; k < NK; ++k) {
    sim[k] *= scale;
    if (cntl[k] > 0.f) m = fmaxf(m, sim[k]);
  }
  float d = 0.f;
#pragma unroll
  for (int k = 0; k < NK; ++k) {
    float e = (cntl[k] > 0.f) ? expf(sim[k] - m) : 0.f;
    sim[k] = cntl[k] * e;
    d += sim[k];
  }
  float inv = 1.f / d;
#pragma unroll
  for (int k = 0; k < NK; ++k) sim[k] *= inv;
  unsigned short* cb = ctxT + ((size_t)b * HW + p) * CTC;
  for (int c0 = 0; c0 < CTC; c0 += 8) {
    union { short8 s; unsigned short u[8]; } o;
#pragma unroll
    for (int i = 0; i < 8; ++i) {
      float s = 0.f;
#pragma unroll
      for (int k = 0; k < NK; ++k) s += sim[k] * Vl[(c0 + i) * NK + k];
      o.u[i] = f2bf(s);
    }
    *(short8*)&cb[c0] = o.s;
  }
}

// ---------------------------------------------------------------------------
extern "C" void kernel_launch(void* const* d_in, const int* in_sizes, int n_in,
                              void* d_out, int out_size, void* d_ws, size_t ws_size,
                              hipStream_t stream) {
  const float* x = (const float*)d_in[0];
  const float* preds = (const float*)d_in[1];
  const float* q_w1 = (const float*)d_in[3];
  const float* q_g1 = (const float*)d_in[4];
  const float* q_b1 = (const float*)d_in[5];
  const float* q_w2 = (const float*)d_in[6];
  const float* q_g2 = (const float*)d_in[7];
  const float* q_b2 = (const float*)d_in[8];
  const float* k_w1 = (const float*)d_in[9];
  const float* k_g1 = (const float*)d_in[10];
  const float* k_b1 = (const float*)d_in[11];
  const float* k_w2 = (const float*)d_in[12];
  const float* k_g2 = (const float*)d_in[13];
  const float* k_b2 = (const float*)d_in[14];
  const float* v_w = (const float*)d_in[15];
  const float* v_g = (const float*)d_in[16];
  const float* v_b = (const float*)d_in[17];
  const float* o_w = (const float*)d_in[18];
  const float* o_g = (const float*)d_in[19];
  const float* o_b = (const float*)d_in[20];
  float* out = (float*)d_out;

  // ws layout (bytes). Overlays: q2T reuses xT (dead after gemm1);
  // ctxT reuses q1T (dead after gemm2). Total ~52 MB.
  char* base = (char*)d_ws;
  unsigned short* xT = (unsigned short*)base;                        // 33,554,432 B
  unsigned short* q2T = xT;                                          // overlay
  unsigned short* q1T = (unsigned short*)(base + 33554432);          // 16,777,216 B
  unsigned short* ctxT = q1T;                                        // overlay
  char* f32r = base + 50331648;
  float* wgt = (float*)f32r;                      // 131072 B
  int* cls = (int*)(f32r + 131072);               // 131072 B
  float* countf = (float*)(f32r + 262144);        // 1024 B
  float* cls_feat = (float*)(f32r + 263168);      // 311296 B
  float* Kcls = (float*)(f32r + 574464);          // 155648 B
  float* Vcls = (float*)(f32r + 730112);          // 155648 B
  unsigned short* wb1 = (unsigned short*)(f32r + 885760);   // 262144 B
  unsigned short* wb2 = (unsigned short*)(f32r + 1147904);  // 131072 B
  unsigned short* wbo = (unsigned short*)(f32r + 1278976);  // 262144 B

  hipMemsetAsync(cls_feat, 0, (size_t)NB * NK * CIN * sizeof(float), stream);

  wconv<<<320, 256, 0, stream>>>(q_w1, q_w2, o_w, wb1, wb2, wbo);
  xpose<<<dim3(HW / 64, CIN / 64, NB), 256, 0, stream>>>(x, xT);
  k1_stats<<<NB, 256, 0, stream>>>(preds, cls, wgt, countf);
  k2_clsfeat<<<dim3(8, 8, NB), 64, 0, stream>>>(x, wgt, cls, cls_feat);
  k3_kv<<<NB * NK, 256, 0, stream>>>(cls_feat, k_w1, k_g1, k_b1, k_w2, k_g2,
                                     k_b2, v_w, v_g, v_b, Kcls, Vcls);
  gemm_mfma<CIN><<<dim3(32, 2, NB), 256, 0, stream>>>(xT, wb1, q_g1, q_b1,
                                                      (void*)q1T, CTC, 1);
  gemm_mfma<CTC><<<dim3(32, 2, NB), 256, 0, stream>>>(q1T, wb2, q_g2, q_b2,
                                                      (void*)q2T, CTC, 1);
  k5_ctx<<<dim3(HW / 256, NB), 256, 0, stream>>>(q2T, Kcls, Vcls, countf, ctxT);
  gemm_mfma<CTC><<<dim3(32, 4, NB), 256, 0, stream>>>(ctxT, wbo, o_g, o_b,
                                                      (void*)out, CIN, 0);
}

// Round 4
// 277.751 us; speedup vs baseline: 1.7934x; 1.0336x over previous
//
#include <hip/hip_runtime.h>
#include <math.h>

#define HW 4096
#define NB 8
#define NK 19
#define CIN 512
#define CTC 256

typedef __attribute__((ext_vector_type(8))) short short8;
typedef __attribute__((ext_vector_type(4))) float f32x4;

__device__ inline unsigned short f2bf(float x) {
  unsigned u = __float_as_uint(x);
  return (unsigned short)((u + 0x7fffu + ((u >> 16) & 1u)) >> 16);  // RNE
}
__device__ inline float bf2f(unsigned short h) {
  return __uint_as_float(((unsigned)h) << 16);
}
__device__ inline void gload16(const void* g, void* l) {
  __builtin_amdgcn_global_load_lds(
      (const __attribute__((address_space(1))) void*)g,
      (__attribute__((address_space(3))) void*)l, 16, 0, 0);
}

// ---------------------------------------------------------------------------
// Weight f32 -> bf16 convert (q_w1, q_w2, o_w).
// ---------------------------------------------------------------------------
__global__ __launch_bounds__(256) void wconv(
    const float* __restrict__ w1, const float* __restrict__ w2,
    const float* __restrict__ wo, unsigned short* __restrict__ wb1,
    unsigned short* __restrict__ wb2, unsigned short* __restrict__ wbo) {
  int i = (blockIdx.x * 256 + threadIdx.x) * 4;
  const float* src;
  unsigned short* dst;
  int off;
  if (i < 131072) { src = w1; dst = wb1; off = i; }
  else if (i < 196608) { src = w2; dst = wb2; off = i - 131072; }
  else { src = wo; dst = wbo; off = i - 196608; }
  float4 v = *(const float4*)(src + off);
  dst[off + 0] = f2bf(v.x);
  dst[off + 1] = f2bf(v.y);
  dst[off + 2] = f2bf(v.z);
  dst[off + 3] = f2bf(v.w);
}

// ---------------------------------------------------------------------------
// FUSED: x [B][CIN][HW] f32 -> xT [B][HW][CIN] bf16 transpose, AND
// cls_feat[b,k,c] += sum_p wgt[p]*[cls(p)==k]*x[c,p]  (f32, via LDS atomics).
// Block: 64 channels x 512 pixels, 256 threads, 8 sub-tiles of 64p.
// x is read exactly once by the whole pipeline.
// ---------------------------------------------------------------------------
__global__ __launch_bounds__(256) void xpose_k2(
    const float* __restrict__ x, const float* __restrict__ wgt_g,
    const int* __restrict__ cls_g, unsigned short* __restrict__ xT,
    float* __restrict__ cls_feat) {
  int b = blockIdx.z, c0 = blockIdx.y * 64, p0 = blockIdx.x * 512;
  int tid = threadIdx.x;
  int l = tid & 63, wv = tid >> 6;
  __shared__ float tile[64][65];  // pad 65: column reads conflict-free
  __shared__ float wl[512];
  __shared__ unsigned char clb[512];
  __shared__ float accs[NK * 64];
  for (int i = tid; i < NK * 64; i += 256) accs[i] = 0.f;
  for (int i = tid; i < 512; i += 256) {
    wl[i] = wgt_g[b * HW + p0 + i];
    clb[i] = (unsigned char)cls_g[b * HW + p0 + i];
  }
  for (int s = 0; s < 8; ++s) {
    int ps = p0 + s * 64;
    __syncthreads();  // previous sub-tile fully consumed; staging visible (s=0)
#pragma unroll
    for (int r = 0; r < 4; ++r) {
      int cl = r * 16 + (tid >> 4);
      int pl = (tid & 15) * 4;
      float4 v = *(const float4*)&x[((size_t)b * CIN + c0 + cl) * HW + ps + pl];
      tile[cl][pl + 0] = v.x;
      tile[cl][pl + 1] = v.y;
      tile[cl][pl + 2] = v.z;
      tile[cl][pl + 3] = v.w;
    }
    __syncthreads();
    // consume: lane l = channel, wave wv owns pixels [wv*16, wv*16+16)
#pragma unroll
    for (int j = 0; j < 16; ++j) {
      int pt = wv * 16 + j;
      float v = tile[l][pt];
      xT[((size_t)b * HW + ps + pt) * CIN + c0 + l] = f2bf(v);
      int pp = s * 64 + pt;
      atomicAdd(&accs[(int)clb[pp] * 64 + l], v * wl[pp]);
    }
  }
  __syncthreads();
  for (int i = tid; i < NK * 64; i += 256)
    atomicAdd(&cls_feat[((size_t)b * NK + (i >> 6)) * CIN + c0 + (i & 63)],
              accs[i]);
}

// ---------------------------------------------------------------------------
// K1: per-pixel argmax + per-class masked softmax stats (unchanged, verified).
// ---------------------------------------------------------------------------
__global__ __launch_bounds__(256) void k1_stats(
    const float* __restrict__ preds, int* __restrict__ cls_g,
    float* __restrict__ wgt_g, float* __restrict__ countf_g) {
  int b = blockIdx.x;
  __shared__ float s_lds[HW];
  __shared__ unsigned char c_lds[HW];
  __shared__ unsigned int Mu[NK];
  __shared__ float Mf[NK];
  __shared__ float Zf[NK];
  __shared__ unsigned int cnt[NK];
  int tid = threadIdx.x;
  if (tid < NK) { Mu[tid] = 0u; Zf[tid] = 0.f; cnt[tid] = 0u; }
  __syncthreads();
  const float* pb = preds + (size_t)b * NK * HW;
  for (int p = tid; p < HW; p += 256) {
    float best = pb[p];
    int bi = 0;
#pragma unroll
    for (int k = 1; k < NK; ++k) {
      float v = pb[k * HW + p];
      if (v > best) { best = v; bi = k; }
    }
    s_lds[p] = best;
    c_lds[p] = (unsigned char)bi;
    unsigned int fb = __float_as_uint(best);
    unsigned int key = (fb & 0x80000000u) ? ~fb : (fb | 0x80000000u);
    atomicMax(&Mu[bi], key);
    atomicAdd(&cnt[bi], 1u);
  }
  __syncthreads();
  if (tid < NK) {
    unsigned int key = Mu[tid];
    float m = -1e30f;
    if (key != 0u) {
      unsigned int fb = (key & 0x80000000u) ? (key & 0x7fffffffu) : ~key;
      m = __uint_as_float(fb);
    }
    Mf[tid] = m;
  }
  __syncthreads();
  for (int p = tid; p < HW; p += 256) {
    int c = c_lds[p];
    float e = expf(s_lds[p] - Mf[c]);
    s_lds[p] = e;
    atomicAdd(&Zf[c], e);
  }
  __syncthreads();
  for (int p = tid; p < HW; p += 256) {
    int c = c_lds[p];
    wgt_g[b * HW + p] = s_lds[p] / Zf[c];
    cls_g[b * HW + p] = c;
  }
  if (tid < NK) countf_g[b * NK + tid] = (float)cnt[tid];
}

// ---------------------------------------------------------------------------
// K3: tiny per-(b,class) K/V projections, f32 (unchanged, verified).
// ---------------------------------------------------------------------------
__global__ __launch_bounds__(256) void k3_kv(
    const float* __restrict__ cls_feat,
    const float* __restrict__ kw1, const float* __restrict__ kg1, const float* __restrict__ kb1,
    const float* __restrict__ kw2, const float* __restrict__ kg2, const float* __restrict__ kb2,
    const float* __restrict__ vw, const float* __restrict__ vg, const float* __restrict__ vb,
    float* __restrict__ Kcls, float* __restrict__ Vcls) {
  int bk = blockIdx.x;
  int b = bk / NK, kc = bk % NK;
  __shared__ float cf[CIN];
  __shared__ float h1[CTC];
  int tid = threadIdx.x;
  const float* row = cls_feat + ((size_t)b * NK + kc) * CIN;
  for (int i = tid; i < CIN; i += 256) cf[i] = row[i];
  __syncthreads();
  {
    const float* wr = kw1 + (size_t)tid * CIN;
    float s = 0.f;
    for (int c2 = 0; c2 < CIN; ++c2) s += wr[c2] * cf[c2];
    h1[tid] = fmaxf(s * kg1[tid] + kb1[tid], 0.f);
  }
  {
    const float* wr = vw + (size_t)tid * CIN;
    float s = 0.f;
    for (int c2 = 0; c2 < CIN; ++c2) s += wr[c2] * cf[c2];
    Vcls[((size_t)b * CTC + tid) * NK + kc] = fmaxf(s * vg[tid] + vb[tid], 0.f);
  }
  __syncthreads();
  {
    const float* wr = kw2 + (size_t)tid * CTC;
    float s = 0.f;
    for (int c2 = 0; c2 < CTC; ++c2) s += wr[c2] * h1[c2];
    Kcls[((size_t)b * CTC + tid) * NK + kc] = fmaxf(s * kg2[tid] + kb2[tid], 0.f);
  }
}

// ---------------------------------------------------------------------------
// MFMA GEMM: D[n][m] = sum_k A[n][k] * W[m][k], A bf16 [B][4096][KD],
// W bf16 [M][KD]. 128x128 tile, BK=32, 4 waves, double-buffered LDS via
// global_load_lds (source-swizzled so ds_read_b128 is bank-conflict-free).
// Epilogue: relu(g*acc+b); outmode 0: f32 [b][M][HW]; 1: bf16 T [b][HW][M].
// ---------------------------------------------------------------------------
template <int KD>
__global__ __launch_bounds__(256) void gemm_mfma(
    const unsigned short* __restrict__ A, const unsigned short* __restrict__ Wb,
    const float* __restrict__ g, const float* __restrict__ bb,
    void* __restrict__ Y, int M, int outmode) {
  __shared__ __align__(16) unsigned short As[2][128 * 32];
  __shared__ __align__(16) unsigned short Bs[2][128 * 32];
  int b = blockIdx.z;
  int n0 = blockIdx.x * 128;
  int m0 = blockIdx.y * 128;
  int tid = threadIdx.x;
  int l = tid & 63, wid = tid >> 6;
  int wr = wid >> 1, wc = wid & 1;
  const unsigned short* Ab = A + (size_t)b * HW * KD;

  f32x4 acc[4][4];
#pragma unroll
  for (int i = 0; i < 4; ++i)
#pragma unroll
    for (int j = 0; j < 4; ++j) acc[i][j] = (f32x4){0.f, 0.f, 0.f, 0.f};

  const int NT = KD / 32;
  auto STAGE = [&](int buf, int t) {
    int k0 = t * 32;
#pragma unroll
    for (int q = 0; q < 2; ++q) {
      int e = q * 2048 + tid * 8;
      int rl = e >> 5, sl = (e >> 3) & 3;
      gload16(Ab + (size_t)(n0 + rl) * KD + k0 + 8 * (sl ^ ((rl >> 1) & 3)),
              &As[buf][q * 2048 + wid * 512]);
    }
#pragma unroll
    for (int q = 0; q < 2; ++q) {
      int e = q * 2048 + tid * 8;
      int rl = e >> 5, sl = (e >> 3) & 3;
      gload16(Wb + (size_t)(m0 + rl) * KD + k0 + 8 * (sl ^ ((rl >> 1) & 3)),
              &Bs[buf][q * 2048 + wid * 512]);
    }
  };
  STAGE(0, 0);
  for (int t = 0; t < NT; ++t) {
    __syncthreads();
    if (t + 1 < NT) STAGE((t + 1) & 1, t + 1);
    int cur = t & 1;
    short8 af[4], bf[4];
#pragma unroll
    for (int f = 0; f < 4; ++f) {
      int nl = wr * 64 + f * 16 + (l & 15);
      af[f] = *(const short8*)&As[cur][nl * 32 + 8 * ((l >> 4) ^ ((nl >> 1) & 3))];
      int ml = wc * 64 + f * 16 + (l & 15);
      bf[f] = *(const short8*)&Bs[cur][ml * 32 + 8 * ((l >> 4) ^ ((ml >> 1) & 3))];
    }
#pragma unroll
    for (int i = 0; i < 4; ++i)
#pragma unroll
      for (int j = 0; j < 4; ++j)
        acc[i][j] =
            __builtin_amdgcn_mfma_f32_16x16x32_bf16(af[i], bf[j], acc[i][j], 0, 0, 0);
  }
  if (outmode == 0) {
    float* Yf = (float*)Y + (size_t)b * M * HW;
#pragma unroll
    for (int j = 0; j < 4; ++j) {
      int m = m0 + wc * 64 + j * 16 + (l & 15);
      float gm = g[m], bm = bb[m];
#pragma unroll
      for (int i = 0; i < 4; ++i) {
        int n = n0 + wr * 64 + i * 16 + (l >> 4) * 4;
        float4 o;
        o.x = fmaxf(acc[i][j][0] * gm + bm, 0.f);
        o.y = fmaxf(acc[i][j][1] * gm + bm, 0.f);
        o.z = fmaxf(acc[i][j][2] * gm + bm, 0.f);
        o.w = fmaxf(acc[i][j][3] * gm + bm, 0.f);
        *(float4*)&Yf[(size_t)m * HW + n] = o;
      }
    }
  } else {
    unsigned short* Yt = (unsigned short*)Y + (size_t)b * HW * M;
#pragma unroll
    for (int j = 0; j < 4; ++j) {
      int m = m0 + wc * 64 + j * 16 + (l & 15);
      float gm = g[m], bm = bb[m];
#pragma unroll
      for (int i = 0; i < 4; ++i) {
        int n = n0 + wr * 64 + i * 16 + (l >> 4) * 4;
#pragma unroll
        for (int r = 0; r < 4; ++r)
          Yt[(size_t)(n + r) * M + m] = f2bf(fmaxf(acc[i][j][r] * gm + bm, 0.f));
      }
    }
  }
}

// ---------------------------------------------------------------------------
// K5: collapsed attention on transposed bf16 activations.
// ---------------------------------------------------------------------------
__global__ __launch_bounds__(256) void k5_ctx(
    const unsigned short* __restrict__ q2T, const float* __restrict__ Kcls,
    const float* __restrict__ Vcls, const float* __restrict__ countf,
    unsigned short* __restrict__ ctxT) {
  int b = blockIdx.y;
  int p = blockIdx.x * 256 + threadIdx.x;
  __shared__ float Kl[CTC * NK];
  __shared__ float Vl[CTC * NK];
  __shared__ float cntl[NK];
  int tid = threadIdx.x;
  for (int i = tid; i < CTC * NK; i += 256) {
    Kl[i] = Kcls[(size_t)b * CTC * NK + i];
    Vl[i] = Vcls[(size_t)b * CTC * NK + i];
  }
  if (tid < NK) cntl[tid] = countf[b * NK + tid];
  __syncthreads();
  float sim[NK];
#pragma unroll
  for (int k = 0; k < NK; ++k) sim[k] = 0.f;
  const unsigned short* q = q2T + ((size_t)b * HW + p) * CTC;
  for (int c0 = 0; c0 < CTC; c0 += 8) {
    short8 v = *(const short8*)&q[c0];
    float qv[8];
#pragma unroll
    for (int i = 0; i < 8; ++i) qv[i] = bf2f((unsigned short)v[i]);
#pragma unroll
    for (int i = 0; i < 8; ++i)
#pragma unroll
      for (int k = 0; k < NK; ++k) sim[k] += qv[i] * Kl[(c0 + i) * NK + k];
  }
  const float scale = 0.0625f;
  float m = -1e30f;
#pragma unroll
  for (int k = 0; k < NK; ++k) {
    sim[k] *= scale;
    if (cntl[k] > 0.f) m = fmaxf(m, sim[k]);
  }
  float d = 0.f;
#pragma unroll
  for (int k = 0; k < NK; ++k) {
    float e = (cntl[k] > 0.f) ? expf(sim[k] - m) : 0.f;
    sim[k] = cntl[k] * e;
    d += sim[k];
  }
  float inv = 1.f / d;
#pragma unroll
  for (int k = 0; k < NK; ++k) sim[k] *= inv;
  unsigned short* cb = ctxT + ((size_t)b * HW + p) * CTC;
  for (int c0 = 0; c0 < CTC; c0 += 8) {
    union { short8 s; unsigned short u[8]; } o;
#pragma unroll
    for (int i = 0; i < 8; ++i) {
      float s = 0.f;
#pragma unroll
      for (int k = 0; k < NK; ++k) s += sim[k] * Vl[(c0 + i) * NK + k];
      o.u[i] = f2bf(s);
    }
    *(short8*)&cb[c0] = o.s;
  }
}

// ---------------------------------------------------------------------------
extern "C" void kernel_launch(void* const* d_in, const int* in_sizes, int n_in,
                              void* d_out, int out_size, void* d_ws, size_t ws_size,
                              hipStream_t stream) {
  const float* x = (const float*)d_in[0];
  const float* preds = (const float*)d_in[1];
  const float* q_w1 = (const float*)d_in[3];
  const float* q_g1 = (const float*)d_in[4];
  const float* q_b1 = (const float*)d_in[5];
  const float* q_w2 = (const float*)d_in[6];
  const float* q_g2 = (const float*)d_in[7];
  const float* q_b2 = (const float*)d_in[8];
  const float* k_w1 = (const float*)d_in[9];
  const float* k_g1 = (const float*)d_in[10];
  const float* k_b1 = (const float*)d_in[11];
  const float* k_w2 = (const float*)d_in[12];
  const float* k_g2 = (const float*)d_in[13];
  const float* k_b2 = (const float*)d_in[14];
  const float* v_w = (const float*)d_in[15];
  const float* v_g = (const float*)d_in[16];
  const float* v_b = (const float*)d_in[17];
  const float* o_w = (const float*)d_in[18];
  const float* o_g = (const float*)d_in[19];
  const float* o_b = (const float*)d_in[20];
  float* out = (float*)d_out;

  char* base = (char*)d_ws;
  unsigned short* xT = (unsigned short*)base;               // 33,554,432 B
  unsigned short* q2T = xT;                                 // overlay
  unsigned short* q1T = (unsigned short*)(base + 33554432); // 16,777,216 B
  unsigned short* ctxT = q1T;                               // overlay
  char* f32r = base + 50331648;
  float* wgt = (float*)f32r;
  int* cls = (int*)(f32r + 131072);
  float* countf = (float*)(f32r + 262144);
  float* cls_feat = (float*)(f32r + 263168);
  float* Kcls = (float*)(f32r + 574464);
  float* Vcls = (float*)(f32r + 730112);
  unsigned short* wb1 = (unsigned short*)(f32r + 885760);
  unsigned short* wb2 = (unsigned short*)(f32r + 1147904);
  unsigned short* wbo = (unsigned short*)(f32r + 1278976);

  hipMemsetAsync(cls_feat, 0, (size_t)NB * NK * CIN * sizeof(float), stream);

  wconv<<<320, 256, 0, stream>>>(q_w1, q_w2, o_w, wb1, wb2, wbo);
  k1_stats<<<NB, 256, 0, stream>>>(preds, cls, wgt, countf);
  xpose_k2<<<dim3(HW / 512, CIN / 64, NB), 256, 0, stream>>>(x, wgt, cls, xT,
                                                             cls_feat);
  k3_kv<<<NB * NK, 256, 0, stream>>>(cls_feat, k_w1, k_g1, k_b1, k_w2, k_g2,
                                     k_b2, v_w, v_g, v_b, Kcls, Vcls);
  gemm_mfma<CIN><<<dim3(32, 2, NB), 256, 0, stream>>>(xT, wb1, q_g1, q_b1,
                                                      (void*)q1T, CTC, 1);
  gemm_mfma<CTC><<<dim3(32, 2, NB), 256, 0, stream>>>(q1T, wb2, q_g2, q_b2,
                                                      (void*)q2T, CTC, 1);
  k5_ctx<<<dim3(HW / 256, NB), 256, 0, stream>>>(q2T, Kcls, Vcls, countf, ctxT);
  gemm_mfma<CTC><<<dim3(32, 4, NB), 256, 0, stream>>>(ctxT, wbo, o_g, o_b,
                                                      (void*)out, CIN, 0);
}

// Round 5
// 224.596 us; speedup vs baseline: 2.2178x; 1.2367x over previous
//
#include <hip/hip_runtime.h>
#include <math.h>

#define HW 4096
#define NB 8
#define NK 19
#define CIN 512
#define CTC 256

typedef __attribute__((ext_vector_type(8))) short short8;
typedef __attribute__((ext_vector_type(4))) float f32x4;

__device__ inline unsigned short f2bf(float x) {
  unsigned u = __float_as_uint(x);
  return (unsigned short)((u + 0x7fffu + ((u >> 16) & 1u)) >> 16);  // RNE
}
__device__ inline float bf2f(unsigned short h) {
  return __uint_as_float(((unsigned)h) << 16);
}
__device__ inline void gload16(const void* g, void* l) {
  __builtin_amdgcn_global_load_lds(
      (const __attribute__((address_space(1))) void*)g,
      (__attribute__((address_space(3))) void*)l, 16, 0, 0);
}

// ---------------------------------------------------------------------------
// Weight f32 -> bf16 convert (q_w1, q_w2, o_w).
// ---------------------------------------------------------------------------
__global__ __launch_bounds__(256) void wconv(
    const float* __restrict__ w1, const float* __restrict__ w2,
    const float* __restrict__ wo, unsigned short* __restrict__ wb1,
    unsigned short* __restrict__ wb2, unsigned short* __restrict__ wbo) {
  int i = (blockIdx.x * 256 + threadIdx.x) * 4;
  const float* src;
  unsigned short* dst;
  int off;
  if (i < 131072) { src = w1; dst = wb1; off = i; }
  else if (i < 196608) { src = w2; dst = wb2; off = i - 131072; }
  else { src = wo; dst = wbo; off = i - 196608; }
  float4 v = *(const float4*)(src + off);
  dst[off + 0] = f2bf(v.x);
  dst[off + 1] = f2bf(v.y);
  dst[off + 2] = f2bf(v.z);
  dst[off + 3] = f2bf(v.w);
}

// ---------------------------------------------------------------------------
// K1: per-pixel argmax + per-class masked-softmax stats. Emits the dense
// scatter matrix wgtP[b][32][HW] bf16 (wgtP[c][p] = softmax wgt if cls(p)==c)
// and countf[b][NK]. wgtP must be zeroed before launch.
// ---------------------------------------------------------------------------
__global__ __launch_bounds__(256) void k1_stats(
    const float* __restrict__ preds, unsigned short* __restrict__ wgtP,
    float* __restrict__ countf_g) {
  int b = blockIdx.x;
  __shared__ float s_lds[HW];
  __shared__ unsigned char c_lds[HW];
  __shared__ unsigned int Mu[NK];
  __shared__ float Mf[NK];
  __shared__ float Zf[NK];
  __shared__ unsigned int cnt[NK];
  int tid = threadIdx.x;
  if (tid < NK) { Mu[tid] = 0u; Zf[tid] = 0.f; cnt[tid] = 0u; }
  __syncthreads();
  const float* pb = preds + (size_t)b * NK * HW;
  for (int p = tid; p < HW; p += 256) {
    float best = pb[p];
    int bi = 0;
#pragma unroll
    for (int k = 1; k < NK; ++k) {
      float v = pb[k * HW + p];
      if (v > best) { best = v; bi = k; }
    }
    s_lds[p] = best;
    c_lds[p] = (unsigned char)bi;
    unsigned int fb = __float_as_uint(best);
    unsigned int key = (fb & 0x80000000u) ? ~fb : (fb | 0x80000000u);
    atomicMax(&Mu[bi], key);
    atomicAdd(&cnt[bi], 1u);
  }
  __syncthreads();
  if (tid < NK) {
    unsigned int key = Mu[tid];
    float m = -1e30f;
    if (key != 0u) {
      unsigned int fb = (key & 0x80000000u) ? (key & 0x7fffffffu) : ~key;
      m = __uint_as_float(fb);
    }
    Mf[tid] = m;
  }
  __syncthreads();
  for (int p = tid; p < HW; p += 256) {
    int c = c_lds[p];
    float e = expf(s_lds[p] - Mf[c]);
    s_lds[p] = e;
    atomicAdd(&Zf[c], e);
  }
  __syncthreads();
  for (int p = tid; p < HW; p += 256) {
    int c = c_lds[p];
    wgtP[((size_t)b * 32 + c) * HW + p] = f2bf(s_lds[p] / Zf[c]);
  }
  if (tid < NK) countf_g[b * NK + tid] = (float)cnt[tid];
}

// ---------------------------------------------------------------------------
// x [B][CIN][HW] f32  ->  xT [B][HW][CIN] bf16  (LDS 64x64 tile transpose;
// verified in round 3).
// ---------------------------------------------------------------------------
__global__ __launch_bounds__(256) void xpose(const float* __restrict__ x,
                                             unsigned short* __restrict__ xT) {
  __shared__ float tile[64][65];
  int b = blockIdx.z, c0 = blockIdx.y * 64, p0 = blockIdx.x * 64;
  int tid = threadIdx.x;
  int l = tid & 63, wid = tid >> 6;
#pragma unroll
  for (int r = 0; r < 4; ++r) {
    int cl = r * 16 + (tid >> 4);
    int pl = (tid & 15) * 4;
    float4 v = *(const float4*)&x[((size_t)b * CIN + c0 + cl) * HW + p0 + pl];
    tile[cl][pl + 0] = v.x;
    tile[cl][pl + 1] = v.y;
    tile[cl][pl + 2] = v.z;
    tile[cl][pl + 3] = v.w;
  }
  __syncthreads();
#pragma unroll
  for (int j = 0; j < 16; ++j) {
    int ploc = j * 4 + wid;
    xT[((size_t)b * HW + p0 + ploc) * CIN + c0 + l] = f2bf(tile[l][ploc]);
  }
}

// ---------------------------------------------------------------------------
// K2 as MFMA GEMM: cls_feat[b,k,c] += sum_p wgtP[k][p] * x[c][p].
// Block: 128 c-rows x 32 k-cols, K-range 512 p (8-way split-K, f32 global
// atomics into pre-zeroed cls_feat). Reg-staged bf16 conversion of x.
// ---------------------------------------------------------------------------
__global__ __launch_bounds__(256) void k2_mfma(
    const float* __restrict__ x, const unsigned short* __restrict__ wgtP,
    float* __restrict__ cls_feat) {
  __shared__ __align__(16) unsigned short As[128 * 32];  // [c-row][32 p] swz
  __shared__ __align__(16) unsigned short Bs[32 * 32];   // [k-row][32 p] swz
  int b = blockIdx.z;
  int c0 = blockIdx.x * 128;
  int p_base = blockIdx.y * 512;
  int tid = threadIdx.x;
  int l = tid & 63, wv = tid >> 6;
  const float* xb = x + ((size_t)b * CIN + c0) * HW;
  const unsigned short* wb = wgtP + (size_t)b * 32 * HW;

  f32x4 acc[2][2];
#pragma unroll
  for (int i = 0; i < 2; ++i)
#pragma unroll
    for (int j = 0; j < 2; ++j) acc[i][j] = (f32x4){0.f, 0.f, 0.f, 0.f};

  int ch = tid & 7;           // 8B chunk within a 64B row
  int slot = ch >> 1, half = ch & 1;
  for (int t = 0; t < 16; ++t) {
    int p0 = p_base + t * 32;
    // load to regs (no LDS dependency yet)
    float4 av[4];
#pragma unroll
    for (int pr = 0; pr < 4; ++pr) {
      int crow = pr * 32 + (tid >> 3);
      av[pr] = *(const float4*)&xb[(size_t)crow * HW + p0 + ch * 4];
    }
    uint2 bv = {0, 0};
    {
      int krow = tid >> 3;
      bv = *(const uint2*)&wb[(size_t)krow * HW + p0 + ch * 4];
    }
    __syncthreads();  // previous iter's LDS reads done
#pragma unroll
    for (int pr = 0; pr < 4; ++pr) {
      int crow = pr * 32 + (tid >> 3);
      union { unsigned int u[2]; unsigned short s[4]; } pk;
      pk.s[0] = f2bf(av[pr].x);
      pk.s[1] = f2bf(av[pr].y);
      pk.s[2] = f2bf(av[pr].z);
      pk.s[3] = f2bf(av[pr].w);
      *(uint2*)&As[crow * 32 + 8 * (slot ^ ((crow >> 1) & 3)) + 4 * half] =
          *(uint2*)pk.u;
    }
    {
      int krow = tid >> 3;
      *(uint2*)&Bs[krow * 32 + 8 * (slot ^ ((krow >> 1) & 3)) + 4 * half] = bv;
    }
    __syncthreads();
    short8 af[2], bf[2];
#pragma unroll
    for (int f = 0; f < 2; ++f) {
      int nl = wv * 32 + f * 16 + (l & 15);
      af[f] = *(const short8*)&As[nl * 32 + 8 * ((l >> 4) ^ ((nl >> 1) & 3))];
      int ml = f * 16 + (l & 15);
      bf[f] = *(const short8*)&Bs[ml * 32 + 8 * ((l >> 4) ^ ((ml >> 1) & 3))];
    }
#pragma unroll
    for (int i = 0; i < 2; ++i)
#pragma unroll
      for (int j = 0; j < 2; ++j)
        acc[i][j] =
            __builtin_amdgcn_mfma_f32_16x16x32_bf16(af[i], bf[j], acc[i][j], 0, 0, 0);
  }
  // epilogue: col k = j*16+(l&15), row c = wv*32+i*16+(l>>4)*4+r
#pragma unroll
  for (int j = 0; j < 2; ++j) {
    int k = j * 16 + (l & 15);
    if (k < NK) {
#pragma unroll
      for (int i = 0; i < 2; ++i) {
        int n = wv * 32 + i * 16 + (l >> 4) * 4;
#pragma unroll
        for (int r = 0; r < 4; ++r)
          atomicAdd(&cls_feat[((size_t)b * NK + k) * CIN + c0 + n + r],
                    acc[i][j][r]);
      }
    }
  }
}

// ---------------------------------------------------------------------------
// K3: tiny per-(b,class) K/V projections, f32 (unchanged, verified).
// ---------------------------------------------------------------------------
__global__ __launch_bounds__(256) void k3_kv(
    const float* __restrict__ cls_feat,
    const float* __restrict__ kw1, const float* __restrict__ kg1, const float* __restrict__ kb1,
    const float* __restrict__ kw2, const float* __restrict__ kg2, const float* __restrict__ kb2,
    const float* __restrict__ vw, const float* __restrict__ vg, const float* __restrict__ vb,
    float* __restrict__ Kcls, float* __restrict__ Vcls) {
  int bk = blockIdx.x;
  int b = bk / NK, kc = bk % NK;
  __shared__ float cf[CIN];
  __shared__ float h1[CTC];
  int tid = threadIdx.x;
  const float* row = cls_feat + ((size_t)b * NK + kc) * CIN;
  for (int i = tid; i < CIN; i += 256) cf[i] = row[i];
  __syncthreads();
  {
    const float* wr = kw1 + (size_t)tid * CIN;
    float s = 0.f;
    for (int c2 = 0; c2 < CIN; ++c2) s += wr[c2] * cf[c2];
    h1[tid] = fmaxf(s * kg1[tid] + kb1[tid], 0.f);
  }
  {
    const float* wr = vw + (size_t)tid * CIN;
    float s = 0.f;
    for (int c2 = 0; c2 < CIN; ++c2) s += wr[c2] * cf[c2];
    Vcls[((size_t)b * CTC + tid) * NK + kc] = fmaxf(s * vg[tid] + vb[tid], 0.f);
  }
  __syncthreads();
  {
    const float* wr = kw2 + (size_t)tid * CTC;
    float s = 0.f;
    for (int c2 = 0; c2 < CTC; ++c2) s += wr[c2] * h1[c2];
    Kcls[((size_t)b * CTC + tid) * NK + kc] = fmaxf(s * kg2[tid] + kb2[tid], 0.f);
  }
}

// ---------------------------------------------------------------------------
// MFMA GEMM: D[n][m] = sum_k A[n][k] * W[m][k] (unchanged, verified).
// ---------------------------------------------------------------------------
template <int KD>
__global__ __launch_bounds__(256) void gemm_mfma(
    const unsigned short* __restrict__ A, const unsigned short* __restrict__ Wb,
    const float* __restrict__ g, const float* __restrict__ bb,
    void* __restrict__ Y, int M, int outmode) {
  __shared__ __align__(16) unsigned short As[2][128 * 32];
  __shared__ __align__(16) unsigned short Bs[2][128 * 32];
  int b = blockIdx.z;
  int n0 = blockIdx.x * 128;
  int m0 = blockIdx.y * 128;
  int tid = threadIdx.x;
  int l = tid & 63, wid = tid >> 6;
  int wr = wid >> 1, wc = wid & 1;
  const unsigned short* Ab = A + (size_t)b * HW * KD;

  f32x4 acc[4][4];
#pragma unroll
  for (int i = 0; i < 4; ++i)
#pragma unroll
    for (int j = 0; j < 4; ++j) acc[i][j] = (f32x4){0.f, 0.f, 0.f, 0.f};

  const int NT = KD / 32;
  auto STAGE = [&](int buf, int t) {
    int k0 = t * 32;
#pragma unroll
    for (int q = 0; q < 2; ++q) {
      int e = q * 2048 + tid * 8;
      int rl = e >> 5, sl = (e >> 3) & 3;
      gload16(Ab + (size_t)(n0 + rl) * KD + k0 + 8 * (sl ^ ((rl >> 1) & 3)),
              &As[buf][q * 2048 + wid * 512]);
    }
#pragma unroll
    for (int q = 0; q < 2; ++q) {
      int e = q * 2048 + tid * 8;
      int rl = e >> 5, sl = (e >> 3) & 3;
      gload16(Wb + (size_t)(m0 + rl) * KD + k0 + 8 * (sl ^ ((rl >> 1) & 3)),
              &Bs[buf][q * 2048 + wid * 512]);
    }
  };
  STAGE(0, 0);
  for (int t = 0; t < NT; ++t) {
    __syncthreads();
    if (t + 1 < NT) STAGE((t + 1) & 1, t + 1);
    int cur = t & 1;
    short8 af[4], bf[4];
#pragma unroll
    for (int f = 0; f < 4; ++f) {
      int nl = wr * 64 + f * 16 + (l & 15);
      af[f] = *(const short8*)&As[cur][nl * 32 + 8 * ((l >> 4) ^ ((nl >> 1) & 3))];
      int ml = wc * 64 + f * 16 + (l & 15);
      bf[f] = *(const short8*)&Bs[cur][ml * 32 + 8 * ((l >> 4) ^ ((ml >> 1) & 3))];
    }
#pragma unroll
    for (int i = 0; i < 4; ++i)
#pragma unroll
      for (int j = 0; j < 4; ++j)
        acc[i][j] =
            __builtin_amdgcn_mfma_f32_16x16x32_bf16(af[i], bf[j], acc[i][j], 0, 0, 0);
  }
  if (outmode == 0) {
    float* Yf = (float*)Y + (size_t)b * M * HW;
#pragma unroll
    for (int j = 0; j < 4; ++j) {
      int m = m0 + wc * 64 + j * 16 + (l & 15);
      float gm = g[m], bm = bb[m];
#pragma unroll
      for (int i = 0; i < 4; ++i) {
        int n = n0 + wr * 64 + i * 16 + (l >> 4) * 4;
        float4 o;
        o.x = fmaxf(acc[i][j][0] * gm + bm, 0.f);
        o.y = fmaxf(acc[i][j][1] * gm + bm, 0.f);
        o.z = fmaxf(acc[i][j][2] * gm + bm, 0.f);
        o.w = fmaxf(acc[i][j][3] * gm + bm, 0.f);
        *(float4*)&Yf[(size_t)m * HW + n] = o;
      }
    }
  } else {
    unsigned short* Yt = (unsigned short*)Y + (size_t)b * HW * M;
#pragma unroll
    for (int j = 0; j < 4; ++j) {
      int m = m0 + wc * 64 + j * 16 + (l & 15);
      float gm = g[m], bm = bb[m];
#pragma unroll
      for (int i = 0; i < 4; ++i) {
        int n = n0 + wr * 64 + i * 16 + (l >> 4) * 4;
#pragma unroll
        for (int r = 0; r < 4; ++r)
          Yt[(size_t)(n + r) * M + m] = f2bf(fmaxf(acc[i][j][r] * gm + bm, 0.f));
      }
    }
  }
}

// ---------------------------------------------------------------------------
// K5: collapsed attention on transposed bf16 activations (unchanged).
// ---------------------------------------------------------------------------
__global__ __launch_bounds__(256) void k5_ctx(
    const unsigned short* __restrict__ q2T, const float* __restrict__ Kcls,
    const float* __restrict__ Vcls, const float* __restrict__ countf,
    unsigned short* __restrict__ ctxT) {
  int b = blockIdx.y;
  int p = blockIdx.x * 256 + threadIdx.x;
  __shared__ float Kl[CTC * NK];
  __shared__ float Vl[CTC * NK];
  __shared__ float cntl[NK];
  int tid = threadIdx.x;
  for (int i = tid; i < CTC * NK; i += 256) {
    Kl[i] = Kcls[(size_t)b * CTC * NK + i];
    Vl[i] = Vcls[(size_t)b * CTC * NK + i];
  }
  if (tid < NK) cntl[tid] = countf[b * NK + tid];
  __syncthreads();
  float sim[NK];
#pragma unroll
  for (int k = 0; k < NK; ++k) sim[k] = 0.f;
  const unsigned short* q = q2T + ((size_t)b * HW + p) * CTC;
  for (int c0 = 0; c0 < CTC; c0 += 8) {
    short8 v = *(const short8*)&q[c0];
    float qv[8];
#pragma unroll
    for (int i = 0; i < 8; ++i) qv[i] = bf2f((unsigned short)v[i]);
#pragma unroll
    for (int i = 0; i < 8; ++i)
#pragma unroll
      for (int k = 0; k < NK; ++k) sim[k] += qv[i] * Kl[(c0 + i) * NK + k];
  }
  const float scale = 0.0625f;
  float m = -1e30f;
#pragma unroll
  for (int k = 0; k < NK; ++k) {
    sim[k] *= scale;
    if (cntl[k] > 0.f) m = fmaxf(m, sim[k]);
  }
  float d = 0.f;
#pragma unroll
  for (int k = 0; k < NK; ++k) {
    float e = (cntl[k] > 0.f) ? expf(sim[k] - m) : 0.f;
    sim[k] = cntl[k] * e;
    d += sim[k];
  }
  float inv = 1.f / d;
#pragma unroll
  for (int k = 0; k < NK; ++k) sim[k] *= inv;
  unsigned short* cb = ctxT + ((size_t)b * HW + p) * CTC;
  for (int c0 = 0; c0 < CTC; c0 += 8) {
    union { short8 s; unsigned short u[8]; } o;
#pragma unroll
    for (int i = 0; i < 8; ++i) {
      float s = 0.f;
#pragma unroll
      for (int k = 0; k < NK; ++k) s += sim[k] * Vl[(c0 + i) * NK + k];
      o.u[i] = f2bf(s);
    }
    *(short8*)&cb[c0] = o.s;
  }
}

// ---------------------------------------------------------------------------
extern "C" void kernel_launch(void* const* d_in, const int* in_sizes, int n_in,
                              void* d_out, int out_size, void* d_ws, size_t ws_size,
                              hipStream_t stream) {
  const float* x = (const float*)d_in[0];
  const float* preds = (const float*)d_in[1];
  const float* q_w1 = (const float*)d_in[3];
  const float* q_g1 = (const float*)d_in[4];
  const float* q_b1 = (const float*)d_in[5];
  const float* q_w2 = (const float*)d_in[6];
  const float* q_g2 = (const float*)d_in[7];
  const float* q_b2 = (const float*)d_in[8];
  const float* k_w1 = (const float*)d_in[9];
  const float* k_g1 = (const float*)d_in[10];
  const float* k_b1 = (const float*)d_in[11];
  const float* k_w2 = (const float*)d_in[12];
  const float* k_g2 = (const float*)d_in[13];
  const float* k_b2 = (const float*)d_in[14];
  const float* v_w = (const float*)d_in[15];
  const float* v_g = (const float*)d_in[16];
  const float* v_b = (const float*)d_in[17];
  const float* o_w = (const float*)d_in[18];
  const float* o_g = (const float*)d_in[19];
  const float* o_b = (const float*)d_in[20];
  float* out = (float*)d_out;

  char* base = (char*)d_ws;
  unsigned short* xT = (unsigned short*)base;               // 33,554,432 B
  unsigned short* q2T = xT;                                 // overlay
  unsigned short* q1T = (unsigned short*)(base + 33554432); // 16,777,216 B
  unsigned short* ctxT = q1T;                               // overlay
  char* f32r = base + 50331648;
  unsigned short* wgtP = (unsigned short*)f32r;             // 2,097,152 B
  float* countf = (float*)(f32r + 2097152);                 // 1,024 B
  float* cls_feat = (float*)(f32r + 2098176);               // 311,296 B
  float* Kcls = (float*)(f32r + 2409472);                   // 155,648 B
  float* Vcls = (float*)(f32r + 2565120);                   // 155,648 B
  unsigned short* wb1 = (unsigned short*)(f32r + 2720768);  // 262,144 B
  unsigned short* wb2 = (unsigned short*)(f32r + 2982912);  // 131,072 B
  unsigned short* wbo = (unsigned short*)(f32r + 3113984);  // 262,144 B

  hipMemsetAsync(cls_feat, 0, (size_t)NB * NK * CIN * sizeof(float), stream);
  hipMemsetAsync(wgtP, 0, (size_t)NB * 32 * HW * sizeof(unsigned short), stream);

  wconv<<<320, 256, 0, stream>>>(q_w1, q_w2, o_w, wb1, wb2, wbo);
  k1_stats<<<NB, 256, 0, stream>>>(preds, wgtP, countf);
  xpose<<<dim3(HW / 64, CIN / 64, NB), 256, 0, stream>>>(x, xT);
  k2_mfma<<<dim3(CIN / 128, 8, NB), 256, 0, stream>>>(x, wgtP, cls_feat);
  k3_kv<<<NB * NK, 256, 0, stream>>>(cls_feat, k_w1, k_g1, k_b1, k_w2, k_g2,
                                     k_b2, v_w, v_g, v_b, Kcls, Vcls);
  gemm_mfma<CIN><<<dim3(32, 2, NB), 256, 0, stream>>>(xT, wb1, q_g1, q_b1,
                                                      (void*)q1T, CTC, 1);
  gemm_mfma<CTC><<<dim3(32, 2, NB), 256, 0, stream>>>(q1T, wb2, q_g2, q_b2,
                                                      (void*)q2T, CTC, 1);
  k5_ctx<<<dim3(HW / 256, NB), 256, 0, stream>>>(q2T, Kcls, Vcls, countf, ctxT);
  gemm_mfma<CTC><<<dim3(32, 4, NB), 256, 0, stream>>>(ctxT, wbo, o_g, o_b,
                                                      (void*)out, CIN, 0);
}

// Round 6
// 175.292 us; speedup vs baseline: 2.8416x; 1.2813x over previous
//
#include <hip/hip_runtime.h>
#include <math.h>

#define HW 4096
#define NB 8
#define NK 19
#define CIN 512
#define CTC 256

typedef __attribute__((ext_vector_type(8))) short short8;
typedef __attribute__((ext_vector_type(4))) float f32x4;

__device__ inline unsigned short f2bf(float x) {
  unsigned u = __float_as_uint(x);
  return (unsigned short)((u + 0x7fffu + ((u >> 16) & 1u)) >> 16);  // RNE
}
__device__ inline float bf2f(unsigned short h) {
  return __uint_as_float(((unsigned)h) << 16);
}
__device__ inline void gload16(const void* g, void* l) {
  __builtin_amdgcn_global_load_lds(
      (const __attribute__((address_space(1))) void*)g,
      (__attribute__((address_space(3))) void*)l, 16, 0, 0);
}

// ---------------------------------------------------------------------------
// Weight f32 -> bf16 convert (q_w1, q_w2, o_w).
// ---------------------------------------------------------------------------
__global__ __launch_bounds__(256) void wconv(
    const float* __restrict__ w1, const float* __restrict__ w2,
    const float* __restrict__ wo, unsigned short* __restrict__ wb1,
    unsigned short* __restrict__ wb2, unsigned short* __restrict__ wbo) {
  int i = (blockIdx.x * 256 + threadIdx.x) * 4;
  const float* src;
  unsigned short* dst;
  int off;
  if (i < 131072) { src = w1; dst = wb1; off = i; }
  else if (i < 196608) { src = w2; dst = wb2; off = i - 131072; }
  else { src = wo; dst = wbo; off = i - 196608; }
  float4 v = *(const float4*)(src + off);
  dst[off + 0] = f2bf(v.x);
  dst[off + 1] = f2bf(v.y);
  dst[off + 2] = f2bf(v.z);
  dst[off + 3] = f2bf(v.w);
}

// ---------------------------------------------------------------------------
// K1: per-pixel argmax + per-class masked-softmax stats -> wgtP[b][32][HW]
// bf16 scatter matrix + countf. wgtP pre-zeroed. (verified)
// ---------------------------------------------------------------------------
__global__ __launch_bounds__(256) void k1_stats(
    const float* __restrict__ preds, unsigned short* __restrict__ wgtP,
    float* __restrict__ countf_g) {
  int b = blockIdx.x;
  __shared__ float s_lds[HW];
  __shared__ unsigned char c_lds[HW];
  __shared__ unsigned int Mu[NK];
  __shared__ float Mf[NK];
  __shared__ float Zf[NK];
  __shared__ unsigned int cnt[NK];
  int tid = threadIdx.x;
  if (tid < NK) { Mu[tid] = 0u; Zf[tid] = 0.f; cnt[tid] = 0u; }
  __syncthreads();
  const float* pb = preds + (size_t)b * NK * HW;
  for (int p = tid; p < HW; p += 256) {
    float best = pb[p];
    int bi = 0;
#pragma unroll
    for (int k = 1; k < NK; ++k) {
      float v = pb[k * HW + p];
      if (v > best) { best = v; bi = k; }
    }
    s_lds[p] = best;
    c_lds[p] = (unsigned char)bi;
    unsigned int fb = __float_as_uint(best);
    unsigned int key = (fb & 0x80000000u) ? ~fb : (fb | 0x80000000u);
    atomicMax(&Mu[bi], key);
    atomicAdd(&cnt[bi], 1u);
  }
  __syncthreads();
  if (tid < NK) {
    unsigned int key = Mu[tid];
    float m = -1e30f;
    if (key != 0u) {
      unsigned int fb = (key & 0x80000000u) ? (key & 0x7fffffffu) : ~key;
      m = __uint_as_float(fb);
    }
    Mf[tid] = m;
  }
  __syncthreads();
  for (int p = tid; p < HW; p += 256) {
    int c = c_lds[p];
    float e = expf(s_lds[p] - Mf[c]);
    s_lds[p] = e;
    atomicAdd(&Zf[c], e);
  }
  __syncthreads();
  for (int p = tid; p < HW; p += 256) {
    int c = c_lds[p];
    wgtP[((size_t)b * 32 + c) * HW + p] = f2bf(s_lds[p] / Zf[c]);
  }
  if (tid < NK) countf_g[b * NK + tid] = (float)cnt[tid];
}

// ---------------------------------------------------------------------------
// x [B][CIN][HW] f32 -> xT [B][HW][CIN] bf16 (verified).
// ---------------------------------------------------------------------------
__global__ __launch_bounds__(256) void xpose(const float* __restrict__ x,
                                             unsigned short* __restrict__ xT) {
  __shared__ float tile[64][65];
  int b = blockIdx.z, c0 = blockIdx.y * 64, p0 = blockIdx.x * 64;
  int tid = threadIdx.x;
  int l = tid & 63, wid = tid >> 6;
#pragma unroll
  for (int r = 0; r < 4; ++r) {
    int cl = r * 16 + (tid >> 4);
    int pl = (tid & 15) * 4;
    float4 v = *(const float4*)&x[((size_t)b * CIN + c0 + cl) * HW + p0 + pl];
    tile[cl][pl + 0] = v.x;
    tile[cl][pl + 1] = v.y;
    tile[cl][pl + 2] = v.z;
    tile[cl][pl + 3] = v.w;
  }
  __syncthreads();
#pragma unroll
  for (int j = 0; j < 16; ++j) {
    int ploc = j * 4 + wid;
    xT[((size_t)b * HW + p0 + ploc) * CIN + c0 + l] = f2bf(tile[l][ploc]);
  }
}

// ---------------------------------------------------------------------------
// K2 as MFMA GEMM: cls_feat[b,k,c] += sum_p wgtP[k][p]*x[c][p] (verified).
// ---------------------------------------------------------------------------
__global__ __launch_bounds__(256) void k2_mfma(
    const float* __restrict__ x, const unsigned short* __restrict__ wgtP,
    float* __restrict__ cls_feat) {
  __shared__ __align__(16) unsigned short As[128 * 32];
  __shared__ __align__(16) unsigned short Bs[32 * 32];
  int b = blockIdx.z;
  int c0 = blockIdx.x * 128;
  int p_base = blockIdx.y * 512;
  int tid = threadIdx.x;
  int l = tid & 63, wv = tid >> 6;
  const float* xb = x + ((size_t)b * CIN + c0) * HW;
  const unsigned short* wb = wgtP + (size_t)b * 32 * HW;

  f32x4 acc[2][2];
#pragma unroll
  for (int i = 0; i < 2; ++i)
#pragma unroll
    for (int j = 0; j < 2; ++j) acc[i][j] = (f32x4){0.f, 0.f, 0.f, 0.f};

  int ch = tid & 7;
  int slot = ch >> 1, half = ch & 1;
  for (int t = 0; t < 16; ++t) {
    int p0 = p_base + t * 32;
    float4 av[4];
#pragma unroll
    for (int pr = 0; pr < 4; ++pr) {
      int crow = pr * 32 + (tid >> 3);
      av[pr] = *(const float4*)&xb[(size_t)crow * HW + p0 + ch * 4];
    }
    uint2 bv = {0, 0};
    {
      int krow = tid >> 3;
      bv = *(const uint2*)&wb[(size_t)krow * HW + p0 + ch * 4];
    }
    __syncthreads();
#pragma unroll
    for (int pr = 0; pr < 4; ++pr) {
      int crow = pr * 32 + (tid >> 3);
      union { unsigned int u[2]; unsigned short s[4]; } pk;
      pk.s[0] = f2bf(av[pr].x);
      pk.s[1] = f2bf(av[pr].y);
      pk.s[2] = f2bf(av[pr].z);
      pk.s[3] = f2bf(av[pr].w);
      *(uint2*)&As[crow * 32 + 8 * (slot ^ ((crow >> 1) & 3)) + 4 * half] =
          *(uint2*)pk.u;
    }
    {
      int krow = tid >> 3;
      *(uint2*)&Bs[krow * 32 + 8 * (slot ^ ((krow >> 1) & 3)) + 4 * half] = bv;
    }
    __syncthreads();
    short8 af[2], bf[2];
#pragma unroll
    for (int f = 0; f < 2; ++f) {
      int nl = wv * 32 + f * 16 + (l & 15);
      af[f] = *(const short8*)&As[nl * 32 + 8 * ((l >> 4) ^ ((nl >> 1) & 3))];
      int ml = f * 16 + (l & 15);
      bf[f] = *(const short8*)&Bs[ml * 32 + 8 * ((l >> 4) ^ ((ml >> 1) & 3))];
    }
#pragma unroll
    for (int i = 0; i < 2; ++i)
#pragma unroll
      for (int j = 0; j < 2; ++j)
        acc[i][j] =
            __builtin_amdgcn_mfma_f32_16x16x32_bf16(af[i], bf[j], acc[i][j], 0, 0, 0);
  }
#pragma unroll
  for (int j = 0; j < 2; ++j) {
    int k = j * 16 + (l & 15);
    if (k < NK) {
#pragma unroll
      for (int i = 0; i < 2; ++i) {
        int n = wv * 32 + i * 16 + (l >> 4) * 4;
#pragma unroll
        for (int r = 0; r < 4; ++r)
          atomicAdd(&cls_feat[((size_t)b * NK + k) * CIN + c0 + n + r],
                    acc[i][j][r]);
      }
    }
  }
}

// ---------------------------------------------------------------------------
// K3: per-(b,class) K/V projections. Kcls now written TRANSPOSED as bf16
// [b][19][256] (coalesced here AND in k5 staging). Vcls stays f32 [b][256][19].
// ---------------------------------------------------------------------------
__global__ __launch_bounds__(256) void k3_kv(
    const float* __restrict__ cls_feat,
    const float* __restrict__ kw1, const float* __restrict__ kg1, const float* __restrict__ kb1,
    const float* __restrict__ kw2, const float* __restrict__ kg2, const float* __restrict__ kb2,
    const float* __restrict__ vw, const float* __restrict__ vg, const float* __restrict__ vb,
    unsigned short* __restrict__ KclsT, float* __restrict__ Vcls) {
  int bk = blockIdx.x;
  int b = bk / NK, kc = bk % NK;
  __shared__ float cf[CIN];
  __shared__ float h1[CTC];
  int tid = threadIdx.x;
  const float* row = cls_feat + ((size_t)b * NK + kc) * CIN;
  for (int i = tid; i < CIN; i += 256) cf[i] = row[i];
  __syncthreads();
  {
    const float* wr = kw1 + (size_t)tid * CIN;
    float s = 0.f;
    for (int c2 = 0; c2 < CIN; ++c2) s += wr[c2] * cf[c2];
    h1[tid] = fmaxf(s * kg1[tid] + kb1[tid], 0.f);
  }
  {
    const float* wr = vw + (size_t)tid * CIN;
    float s = 0.f;
    for (int c2 = 0; c2 < CIN; ++c2) s += wr[c2] * cf[c2];
    Vcls[((size_t)b * CTC + tid) * NK + kc] = fmaxf(s * vg[tid] + vb[tid], 0.f);
  }
  __syncthreads();
  {
    const float* wr = kw2 + (size_t)tid * CTC;
    float s = 0.f;
    for (int c2 = 0; c2 < CTC; ++c2) s += wr[c2] * h1[c2];
    KclsT[((size_t)b * NK + kc) * CTC + tid] =
        f2bf(fmaxf(s * kg2[tid] + kb2[tid], 0.f));
  }
}

// ---------------------------------------------------------------------------
// MFMA GEMM (verified, unchanged).
// ---------------------------------------------------------------------------
template <int KD>
__global__ __launch_bounds__(256) void gemm_mfma(
    const unsigned short* __restrict__ A, const unsigned short* __restrict__ Wb,
    const float* __restrict__ g, const float* __restrict__ bb,
    void* __restrict__ Y, int M, int outmode) {
  __shared__ __align__(16) unsigned short As[2][128 * 32];
  __shared__ __align__(16) unsigned short Bs[2][128 * 32];
  int b = blockIdx.z;
  int n0 = blockIdx.x * 128;
  int m0 = blockIdx.y * 128;
  int tid = threadIdx.x;
  int l = tid & 63, wid = tid >> 6;
  int wr = wid >> 1, wc = wid & 1;
  const unsigned short* Ab = A + (size_t)b * HW * KD;

  f32x4 acc[4][4];
#pragma unroll
  for (int i = 0; i < 4; ++i)
#pragma unroll
    for (int j = 0; j < 4; ++j) acc[i][j] = (f32x4){0.f, 0.f, 0.f, 0.f};

  const int NT = KD / 32;
  auto STAGE = [&](int buf, int t) {
    int k0 = t * 32;
#pragma unroll
    for (int q = 0; q < 2; ++q) {
      int e = q * 2048 + tid * 8;
      int rl = e >> 5, sl = (e >> 3) & 3;
      gload16(Ab + (size_t)(n0 + rl) * KD + k0 + 8 * (sl ^ ((rl >> 1) & 3)),
              &As[buf][q * 2048 + wid * 512]);
    }
#pragma unroll
    for (int q = 0; q < 2; ++q) {
      int e = q * 2048 + tid * 8;
      int rl = e >> 5, sl = (e >> 3) & 3;
      gload16(Wb + (size_t)(m0 + rl) * KD + k0 + 8 * (sl ^ ((rl >> 1) & 3)),
              &Bs[buf][q * 2048 + wid * 512]);
    }
  };
  STAGE(0, 0);
  for (int t = 0; t < NT; ++t) {
    __syncthreads();
    if (t + 1 < NT) STAGE((t + 1) & 1, t + 1);
    int cur = t & 1;
    short8 af[4], bf[4];
#pragma unroll
    for (int f = 0; f < 4; ++f) {
      int nl = wr * 64 + f * 16 + (l & 15);
      af[f] = *(const short8*)&As[cur][nl * 32 + 8 * ((l >> 4) ^ ((nl >> 1) & 3))];
      int ml = wc * 64 + f * 16 + (l & 15);
      bf[f] = *(const short8*)&Bs[cur][ml * 32 + 8 * ((l >> 4) ^ ((ml >> 1) & 3))];
    }
#pragma unroll
    for (int i = 0; i < 4; ++i)
#pragma unroll
      for (int j = 0; j < 4; ++j)
        acc[i][j] =
            __builtin_amdgcn_mfma_f32_16x16x32_bf16(af[i], bf[j], acc[i][j], 0, 0, 0);
  }
  if (outmode == 0) {
    float* Yf = (float*)Y + (size_t)b * M * HW;
#pragma unroll
    for (int j = 0; j < 4; ++j) {
      int m = m0 + wc * 64 + j * 16 + (l & 15);
      float gm = g[m], bm = bb[m];
#pragma unroll
      for (int i = 0; i < 4; ++i) {
        int n = n0 + wr * 64 + i * 16 + (l >> 4) * 4;
        float4 o;
        o.x = fmaxf(acc[i][j][0] * gm + bm, 0.f);
        o.y = fmaxf(acc[i][j][1] * gm + bm, 0.f);
        o.z = fmaxf(acc[i][j][2] * gm + bm, 0.f);
        o.w = fmaxf(acc[i][j][3] * gm + bm, 0.f);
        *(float4*)&Yf[(size_t)m * HW + n] = o;
      }
    }
  } else {
    unsigned short* Yt = (unsigned short*)Y + (size_t)b * HW * M;
#pragma unroll
    for (int j = 0; j < 4; ++j) {
      int m = m0 + wc * 64 + j * 16 + (l & 15);
      float gm = g[m], bm = bb[m];
#pragma unroll
      for (int i = 0; i < 4; ++i) {
        int n = n0 + wr * 64 + i * 16 + (l >> 4) * 4;
#pragma unroll
        for (int r = 0; r < 4; ++r)
          Yt[(size_t)(n + r) * M + m] = f2bf(fmaxf(acc[i][j][r] * gm + bm, 0.f));
      }
    }
  }
}

// ---------------------------------------------------------------------------
// K5 via MFMA: sim = q2T·KclsT^T (MFMA, kd=channel), per-pixel 19-class
// softmax (LDS bounce, stride-33), ctx = P·Vcls (single-MFMA kd=class).
// Block = 128 pixels, 4 waves; grid = 256 blocks (1/CU).
// ---------------------------------------------------------------------------
__global__ __launch_bounds__(256) void k5_mfma(
    const unsigned short* __restrict__ q2T,
    const unsigned short* __restrict__ KclsT, const float* __restrict__ Vcls,
    const float* __restrict__ countf, unsigned short* __restrict__ ctxT) {
  __shared__ __align__(16) unsigned short Kl2[32 * 32 * 8];  // [kd-slot][class]x8
  __shared__ __align__(16) unsigned short Vl2[4 * 256 * 8];  // [k-slot][chan]x8
  __shared__ __align__(16) char RC[25088];  // Ql dbuf | simT+Pl (phase overlay)
  __shared__ float cntl[NK];
  unsigned short* Ql = (unsigned short*)RC;            // [2][128*32] bf16
  float* simT = (float*)RC;                            // [128][33] f32
  unsigned short* Pl = (unsigned short*)(RC + 16896);  // [4][128]x8 bf16

  int b = blockIdx.y;
  int p0 = blockIdx.x * 128;
  int tid = threadIdx.x;
  int l = tid & 63, w = tid >> 6;
  const unsigned short* qb = q2T + ((size_t)b * HW + p0) * CTC;

  // stage KclsT -> Kl2 [slot-major]; classes 19..31 left as junk (isolated cols)
  for (int i = tid; i < NK * 32; i += 256) {
    int m = i >> 5, s = i & 31;
    short8 v = *(const short8*)&KclsT[((size_t)b * NK + m) * CTC + s * 8];
    *(short8*)&Kl2[(s * 32 + m) * 8] = v;
  }
  // stage Vcls -> Vl2 [slot-major], zero-padded k>=19
  for (int i = tid; i < 4 * 256; i += 256) {
    int s = i >> 8, c = i & 255;
    union { short8 v; unsigned short u[8]; } pk;
    const float* vr = &Vcls[((size_t)b * CTC + c) * NK];
#pragma unroll
    for (int j = 0; j < 8; ++j) {
      int k = s * 8 + j;
      pk.u[j] = (k < NK) ? f2bf(vr[k]) : (unsigned short)0;
    }
    *(short8*)&Vl2[(s * 256 + c) * 8] = pk.v;
  }
  if (tid < NK) cntl[tid] = countf[b * NK + tid];

  auto STAGE_Q = [&](int buf, int t) {
#pragma unroll
    for (int q = 0; q < 2; ++q) {
      int e = q * 2048 + tid * 8;
      int rl = e >> 5, sl = (e >> 3) & 3;
      gload16(qb + (size_t)rl * CTC + t * 32 + 8 * (sl ^ ((rl >> 1) & 3)),
              &Ql[buf * 4096 + q * 2048 + w * 512]);
    }
  };
  f32x4 acc[2][2];
#pragma unroll
  for (int i = 0; i < 2; ++i)
#pragma unroll
    for (int j = 0; j < 2; ++j) acc[i][j] = (f32x4){0.f, 0.f, 0.f, 0.f};
  STAGE_Q(0, 0);
  for (int t = 0; t < 8; ++t) {
    __syncthreads();
    if (t + 1 < 8) STAGE_Q((t + 1) & 1, t + 1);
    int cur = t & 1;
    short8 aq[2], bk[2];
#pragma unroll
    for (int f = 0; f < 2; ++f) {
      int nl = w * 32 + f * 16 + (l & 15);
      aq[f] =
          *(const short8*)&Ql[cur * 4096 + nl * 32 + 8 * ((l >> 4) ^ ((nl >> 1) & 3))];
      int s = t * 4 + (l >> 4);
      int ml = f * 16 + (l & 15);
      bk[f] = *(const short8*)&Kl2[(s * 32 + ml) * 8];
    }
#pragma unroll
    for (int i = 0; i < 2; ++i)
#pragma unroll
      for (int j = 0; j < 2; ++j)
        acc[i][j] =
            __builtin_amdgcn_mfma_f32_16x16x32_bf16(aq[i], bk[j], acc[i][j], 0, 0, 0);
  }
  __syncthreads();  // all Ql reads done -> RC becomes simT
#pragma unroll
  for (int i = 0; i < 2; ++i)
#pragma unroll
    for (int j = 0; j < 2; ++j) {
      int m = j * 16 + (l & 15);
      if (m < NK) {
#pragma unroll
        for (int r = 0; r < 4; ++r) {
          int p = w * 32 + i * 16 + (l >> 4) * 4 + r;
          simT[p * 33 + m] = acc[i][j][r];
        }
      }
    }
  __syncthreads();
  if (tid < 128) {
    float sims[NK];
#pragma unroll
    for (int k = 0; k < NK; ++k) sims[k] = simT[tid * 33 + k] * 0.0625f;
    float m = -1e30f;
#pragma unroll
    for (int k = 0; k < NK; ++k)
      if (cntl[k] > 0.f) m = fmaxf(m, sims[k]);
    float d = 0.f;
#pragma unroll
    for (int k = 0; k < NK; ++k) {
      float e = (cntl[k] > 0.f) ? expf(sims[k] - m) : 0.f;
      sims[k] = cntl[k] * e;
      d += sims[k];
    }
    float inv = 1.f / d;
#pragma unroll
    for (int s = 0; s < 4; ++s) {
      union { short8 v; unsigned short u8[8]; } pk;
#pragma unroll
      for (int j = 0; j < 8; ++j) {
        int k = s * 8 + j;
        pk.u8[j] = (k < NK) ? f2bf(sims[k] * inv) : (unsigned short)0;
      }
      *(short8*)&Pl[(s * 128 + tid) * 8] = pk.v;
    }
  }
  __syncthreads();
  // PV: single kd-chunk (32 classes, zero-padded)
  short8 ap[2];
#pragma unroll
  for (int f = 0; f < 2; ++f) {
    int nl = w * 32 + f * 16 + (l & 15);
    ap[f] = *(const short8*)&Pl[((l >> 4) * 128 + nl) * 8];
  }
  unsigned short* cb = ctxT + ((size_t)b * HW + p0) * CTC;
#pragma unroll
  for (int mc = 0; mc < 4; ++mc) {
#pragma unroll
    for (int mf = 0; mf < 4; ++mf) {
      int ml = mc * 64 + mf * 16 + (l & 15);
      short8 bv = *(const short8*)&Vl2[((l >> 4) * 256 + ml) * 8];
#pragma unroll
      for (int nf = 0; nf < 2; ++nf) {
        f32x4 z = {0.f, 0.f, 0.f, 0.f};
        f32x4 o = __builtin_amdgcn_mfma_f32_16x16x32_bf16(ap[nf], bv, z, 0, 0, 0);
#pragma unroll
        for (int r = 0; r < 4; ++r) {
          int p = w * 32 + nf * 16 + (l >> 4) * 4 + r;
          cb[(size_t)p * CTC + ml] = f2bf(o[r]);
        }
      }
    }
  }
}

// ---------------------------------------------------------------------------
extern "C" void kernel_launch(void* const* d_in, const int* in_sizes, int n_in,
                              void* d_out, int out_size, void* d_ws, size_t ws_size,
                              hipStream_t stream) {
  const float* x = (const float*)d_in[0];
  const float* preds = (const float*)d_in[1];
  const float* q_w1 = (const float*)d_in[3];
  const float* q_g1 = (const float*)d_in[4];
  const float* q_b1 = (const float*)d_in[5];
  const float* q_w2 = (const float*)d_in[6];
  const float* q_g2 = (const float*)d_in[7];
  const float* q_b2 = (const float*)d_in[8];
  const float* k_w1 = (const float*)d_in[9];
  const float* k_g1 = (const float*)d_in[10];
  const float* k_b1 = (const float*)d_in[11];
  const float* k_w2 = (const float*)d_in[12];
  const float* k_g2 = (const float*)d_in[13];
  const float* k_b2 = (const float*)d_in[14];
  const float* v_w = (const float*)d_in[15];
  const float* v_g = (const float*)d_in[16];
  const float* v_b = (const float*)d_in[17];
  const float* o_w = (const float*)d_in[18];
  const float* o_g = (const float*)d_in[19];
  const float* o_b = (const float*)d_in[20];
  float* out = (float*)d_out;

  char* base = (char*)d_ws;
  unsigned short* xT = (unsigned short*)base;               // 33,554,432 B
  unsigned short* q2T = xT;                                 // overlay
  unsigned short* q1T = (unsigned short*)(base + 33554432); // 16,777,216 B
  unsigned short* ctxT = q1T;                               // overlay
  char* f32r = base + 50331648;
  unsigned short* wgtP = (unsigned short*)f32r;             // 2,097,152 B
  float* countf = (float*)(f32r + 2097152);                 // 1,024 B
  float* cls_feat = (float*)(f32r + 2098176);               // 311,296 B
  unsigned short* KclsT = (unsigned short*)(f32r + 2409472);// 77,824 B
  float* Vcls = (float*)(f32r + 2487296);                   // 155,648 B
  unsigned short* wb1 = (unsigned short*)(f32r + 2642944);  // 262,144 B
  unsigned short* wb2 = (unsigned short*)(f32r + 2905088);  // 131,072 B
  unsigned short* wbo = (unsigned short*)(f32r + 3036160);  // 262,144 B

  hipMemsetAsync(cls_feat, 0, (size_t)NB * NK * CIN * sizeof(float), stream);
  hipMemsetAsync(wgtP, 0, (size_t)NB * 32 * HW * sizeof(unsigned short), stream);

  wconv<<<320, 256, 0, stream>>>(q_w1, q_w2, o_w, wb1, wb2, wbo);
  k1_stats<<<NB, 256, 0, stream>>>(preds, wgtP, countf);
  xpose<<<dim3(HW / 64, CIN / 64, NB), 256, 0, stream>>>(x, xT);
  k2_mfma<<<dim3(CIN / 128, 8, NB), 256, 0, stream>>>(x, wgtP, cls_feat);
  k3_kv<<<NB * NK, 256, 0, stream>>>(cls_feat, k_w1, k_g1, k_b1, k_w2, k_g2,
                                     k_b2, v_w, v_g, v_b, KclsT, Vcls);
  gemm_mfma<CIN><<<dim3(32, 2, NB), 256, 0, stream>>>(xT, wb1, q_g1, q_b1,
                                                      (void*)q1T, CTC, 1);
  gemm_mfma<CTC><<<dim3(32, 2, NB), 256, 0, stream>>>(q1T, wb2, q_g2, q_b2,
                                                      (void*)q2T, CTC, 1);
  k5_mfma<<<dim3(HW / 128, NB), 256, 0, stream>>>(q2T, KclsT, Vcls, countf,
                                                  ctxT);
  gemm_mfma<CTC><<<dim3(32, 4, NB), 256, 0, stream>>>(ctxT, wbo, o_g, o_b,
                                                      (void*)out, CIN, 0);
}

// Round 7
// 167.955 us; speedup vs baseline: 2.9658x; 1.0437x over previous
//
#include <hip/hip_runtime.h>
#include <math.h>

#define HW 4096
#define NB 8
#define NK 19
#define CIN 512
#define CTC 256

typedef __attribute__((ext_vector_type(8))) short short8;
typedef __attribute__((ext_vector_type(4))) float f32x4;

__device__ inline unsigned short f2bf(float x) {
  unsigned u = __float_as_uint(x);
  return (unsigned short)((u + 0x7fffu + ((u >> 16) & 1u)) >> 16);  // RNE
}
__device__ inline float bf2f(unsigned short h) {
  return __uint_as_float(((unsigned)h) << 16);
}
__device__ inline void gload16(const void* g, void* l) {
  __builtin_amdgcn_global_load_lds(
      (const __attribute__((address_space(1))) void*)g,
      (__attribute__((address_space(3))) void*)l, 16, 0, 0);
}

// ---------------------------------------------------------------------------
// Weight f32 -> bf16 convert (q_w1, q_w2, o_w).
// ---------------------------------------------------------------------------
__global__ __launch_bounds__(256) void wconv(
    const float* __restrict__ w1, const float* __restrict__ w2,
    const float* __restrict__ wo, unsigned short* __restrict__ wb1,
    unsigned short* __restrict__ wb2, unsigned short* __restrict__ wbo) {
  int i = (blockIdx.x * 256 + threadIdx.x) * 4;
  const float* src;
  unsigned short* dst;
  int off;
  if (i < 131072) { src = w1; dst = wb1; off = i; }
  else if (i < 196608) { src = w2; dst = wb2; off = i - 131072; }
  else { src = wo; dst = wbo; off = i - 196608; }
  float4 v = *(const float4*)(src + off);
  dst[off + 0] = f2bf(v.x);
  dst[off + 1] = f2bf(v.y);
  dst[off + 2] = f2bf(v.z);
  dst[off + 3] = f2bf(v.w);
}

// ---------------------------------------------------------------------------
// K1: per-pixel argmax + per-class masked-softmax stats -> wgtP[b][32][HW]
// bf16 scatter matrix + countf. wgtP pre-zeroed. (verified)
// ---------------------------------------------------------------------------
__global__ __launch_bounds__(256) void k1_stats(
    const float* __restrict__ preds, unsigned short* __restrict__ wgtP,
    float* __restrict__ countf_g) {
  int b = blockIdx.x;
  __shared__ float s_lds[HW];
  __shared__ unsigned char c_lds[HW];
  __shared__ unsigned int Mu[NK];
  __shared__ float Mf[NK];
  __shared__ float Zf[NK];
  __shared__ unsigned int cnt[NK];
  int tid = threadIdx.x;
  if (tid < NK) { Mu[tid] = 0u; Zf[tid] = 0.f; cnt[tid] = 0u; }
  __syncthreads();
  const float* pb = preds + (size_t)b * NK * HW;
  for (int p = tid; p < HW; p += 256) {
    float best = pb[p];
    int bi = 0;
#pragma unroll
    for (int k = 1; k < NK; ++k) {
      float v = pb[k * HW + p];
      if (v > best) { best = v; bi = k; }
    }
    s_lds[p] = best;
    c_lds[p] = (unsigned char)bi;
    unsigned int fb = __float_as_uint(best);
    unsigned int key = (fb & 0x80000000u) ? ~fb : (fb | 0x80000000u);
    atomicMax(&Mu[bi], key);
    atomicAdd(&cnt[bi], 1u);
  }
  __syncthreads();
  if (tid < NK) {
    unsigned int key = Mu[tid];
    float m = -1e30f;
    if (key != 0u) {
      unsigned int fb = (key & 0x80000000u) ? (key & 0x7fffffffu) : ~key;
      m = __uint_as_float(fb);
    }
    Mf[tid] = m;
  }
  __syncthreads();
  for (int p = tid; p < HW; p += 256) {
    int c = c_lds[p];
    float e = expf(s_lds[p] - Mf[c]);
    s_lds[p] = e;
    atomicAdd(&Zf[c], e);
  }
  __syncthreads();
  for (int p = tid; p < HW; p += 256) {
    int c = c_lds[p];
    wgtP[((size_t)b * 32 + c) * HW + p] = f2bf(s_lds[p] / Zf[c]);
  }
  if (tid < NK) countf_g[b * NK + tid] = (float)cnt[tid];
}

// ---------------------------------------------------------------------------
// x [B][CIN][HW] f32 -> xT [B][HW][CIN] bf16 (verified).
// ---------------------------------------------------------------------------
__global__ __launch_bounds__(256) void xpose(const float* __restrict__ x,
                                             unsigned short* __restrict__ xT) {
  __shared__ float tile[64][65];
  int b = blockIdx.z, c0 = blockIdx.y * 64, p0 = blockIdx.x * 64;
  int tid = threadIdx.x;
  int l = tid & 63, wid = tid >> 6;
#pragma unroll
  for (int r = 0; r < 4; ++r) {
    int cl = r * 16 + (tid >> 4);
    int pl = (tid & 15) * 4;
    float4 v = *(const float4*)&x[((size_t)b * CIN + c0 + cl) * HW + p0 + pl];
    tile[cl][pl + 0] = v.x;
    tile[cl][pl + 1] = v.y;
    tile[cl][pl + 2] = v.z;
    tile[cl][pl + 3] = v.w;
  }
  __syncthreads();
#pragma unroll
  for (int j = 0; j < 16; ++j) {
    int ploc = j * 4 + wid;
    xT[((size_t)b * HW + p0 + ploc) * CIN + c0 + l] = f2bf(tile[l][ploc]);
  }
}

// ---------------------------------------------------------------------------
// K2 as MFMA GEMM: cls_feat[b,k,c] += sum_p wgtP[k][p]*x[c][p] (verified).
// ---------------------------------------------------------------------------
__global__ __launch_bounds__(256) void k2_mfma(
    const float* __restrict__ x, const unsigned short* __restrict__ wgtP,
    float* __restrict__ cls_feat) {
  __shared__ __align__(16) unsigned short As[128 * 32];
  __shared__ __align__(16) unsigned short Bs[32 * 32];
  int b = blockIdx.z;
  int c0 = blockIdx.x * 128;
  int p_base = blockIdx.y * 512;
  int tid = threadIdx.x;
  int l = tid & 63, wv = tid >> 6;
  const float* xb = x + ((size_t)b * CIN + c0) * HW;
  const unsigned short* wb = wgtP + (size_t)b * 32 * HW;

  f32x4 acc[2][2];
#pragma unroll
  for (int i = 0; i < 2; ++i)
#pragma unroll
    for (int j = 0; j < 2; ++j) acc[i][j] = (f32x4){0.f, 0.f, 0.f, 0.f};

  int ch = tid & 7;
  int slot = ch >> 1, half = ch & 1;
  for (int t = 0; t < 16; ++t) {
    int p0 = p_base + t * 32;
    float4 av[4];
#pragma unroll
    for (int pr = 0; pr < 4; ++pr) {
      int crow = pr * 32 + (tid >> 3);
      av[pr] = *(const float4*)&xb[(size_t)crow * HW + p0 + ch * 4];
    }
    uint2 bv = {0, 0};
    {
      int krow = tid >> 3;
      bv = *(const uint2*)&wb[(size_t)krow * HW + p0 + ch * 4];
    }
    __syncthreads();
#pragma unroll
    for (int pr = 0; pr < 4; ++pr) {
      int crow = pr * 32 + (tid >> 3);
      union { unsigned int u[2]; unsigned short s[4]; } pk;
      pk.s[0] = f2bf(av[pr].x);
      pk.s[1] = f2bf(av[pr].y);
      pk.s[2] = f2bf(av[pr].z);
      pk.s[3] = f2bf(av[pr].w);
      *(uint2*)&As[crow * 32 + 8 * (slot ^ ((crow >> 1) & 3)) + 4 * half] =
          *(uint2*)pk.u;
    }
    {
      int krow = tid >> 3;
      *(uint2*)&Bs[krow * 32 + 8 * (slot ^ ((krow >> 1) & 3)) + 4 * half] = bv;
    }
    __syncthreads();
    short8 af[2], bf[2];
#pragma unroll
    for (int f = 0; f < 2; ++f) {
      int nl = wv * 32 + f * 16 + (l & 15);
      af[f] = *(const short8*)&As[nl * 32 + 8 * ((l >> 4) ^ ((nl >> 1) & 3))];
      int ml = f * 16 + (l & 15);
      bf[f] = *(const short8*)&Bs[ml * 32 + 8 * ((l >> 4) ^ ((ml >> 1) & 3))];
    }
#pragma unroll
    for (int i = 0; i < 2; ++i)
#pragma unroll
      for (int j = 0; j < 2; ++j)
        acc[i][j] =
            __builtin_amdgcn_mfma_f32_16x16x32_bf16(af[i], bf[j], acc[i][j], 0, 0, 0);
  }
#pragma unroll
  for (int j = 0; j < 2; ++j) {
    int k = j * 16 + (l & 15);
    if (k < NK) {
#pragma unroll
      for (int i = 0; i < 2; ++i) {
        int n = wv * 32 + i * 16 + (l >> 4) * 4;
#pragma unroll
        for (int r = 0; r < 4; ++r)
          atomicAdd(&cls_feat[((size_t)b * NK + k) * CIN + c0 + n + r],
                    acc[i][j][r]);
      }
    }
  }
}

// ---------------------------------------------------------------------------
// K3a: h1[bk][m] = relu(g1*(cls_feat[bk,:]·kw1[m,:])+b1) and
//      Vcls[b][m][kc] = relu(g*(cls_feat[bk,:]·vw[m,:])+b), 64 cols per block.
// 2 threads per dot (256 elems, float4, 4 acc chains) + shuffle reduce.
// ---------------------------------------------------------------------------
__global__ __launch_bounds__(256) void k3a(
    const float* __restrict__ cls_feat, const float* __restrict__ kw1,
    const float* __restrict__ kg1, const float* __restrict__ kb1,
    const float* __restrict__ vw, const float* __restrict__ vg,
    const float* __restrict__ vb, float* __restrict__ h1g,
    float* __restrict__ Vcls) {
  int bk = blockIdx.y;
  int b = bk / NK, kc = bk % NK;
  int q = blockIdx.x;
  __shared__ float cf[CIN];
  int tid = threadIdx.x;
  const float* row = cls_feat + (size_t)bk * CIN;
  for (int i = tid; i < CIN; i += 256) cf[i] = row[i];
  __syncthreads();
  int o = tid >> 1, half = tid & 1;
  int col = q * 64 + (o & 63);
  const float* w =
      (o < 64) ? &kw1[(size_t)col * CIN] : &vw[(size_t)col * CIN];
  int base = half * 256;
  float acc[4] = {0.f, 0.f, 0.f, 0.f};
#pragma unroll 8
  for (int i = 0; i < 64; ++i) {
    float4 w4 = *(const float4*)&w[base + i * 4];
    const float* c4 = &cf[base + i * 4];
    acc[i & 3] += w4.x * c4[0] + w4.y * c4[1] + w4.z * c4[2] + w4.w * c4[3];
  }
  float s = (acc[0] + acc[1]) + (acc[2] + acc[3]);
  s += __shfl_xor(s, 1);
  if (half == 0) {
    if (o < 64) {
      h1g[(size_t)bk * CTC + col] = fmaxf(s * kg1[col] + kb1[col], 0.f);
    } else {
      Vcls[((size_t)b * CTC + col) * NK + kc] =
          fmaxf(s * vg[col] + vb[col], 0.f);
    }
  }
}

// ---------------------------------------------------------------------------
// K3b: KclsT[bk][m] = relu(g2*(h1[bk,:]·kw2[m,:])+b2) bf16, 64 cols/block.
// 4 threads per dot (64 elems each) + 2-step shuffle reduce.
// ---------------------------------------------------------------------------
__global__ __launch_bounds__(256) void k3b(
    const float* __restrict__ h1g, const float* __restrict__ kw2,
    const float* __restrict__ kg2, const float* __restrict__ kb2,
    unsigned short* __restrict__ KclsT) {
  int bk = blockIdx.y;
  int q = blockIdx.x;
  __shared__ float h1[CTC];
  int tid = threadIdx.x;
  const float* row = h1g + (size_t)bk * CTC;
  if (tid < CTC) h1[tid] = row[tid];
  __syncthreads();
  int o = tid >> 2, part = tid & 3;
  int col = q * 64 + o;
  const float* w = &kw2[(size_t)col * CTC + part * 64];
  const float* c = &h1[part * 64];
  float acc[4] = {0.f, 0.f, 0.f, 0.f};
#pragma unroll
  for (int i = 0; i < 16; ++i) {
    float4 w4 = *(const float4*)&w[i * 4];
    acc[i & 3] += w4.x * c[i * 4] + w4.y * c[i * 4 + 1] + w4.z * c[i * 4 + 2] +
                  w4.w * c[i * 4 + 3];
  }
  float s = (acc[0] + acc[1]) + (acc[2] + acc[3]);
  s += __shfl_xor(s, 1);
  s += __shfl_xor(s, 2);
  if (part == 0)
    KclsT[(size_t)bk * CTC + col] = f2bf(fmaxf(s * kg2[col] + kb2[col], 0.f));
}

// ---------------------------------------------------------------------------
// MFMA GEMM (verified, unchanged).
// ---------------------------------------------------------------------------
template <int KD>
__global__ __launch_bounds__(256) void gemm_mfma(
    const unsigned short* __restrict__ A, const unsigned short* __restrict__ Wb,
    const float* __restrict__ g, const float* __restrict__ bb,
    void* __restrict__ Y, int M, int outmode) {
  __shared__ __align__(16) unsigned short As[2][128 * 32];
  __shared__ __align__(16) unsigned short Bs[2][128 * 32];
  int b = blockIdx.z;
  int n0 = blockIdx.x * 128;
  int m0 = blockIdx.y * 128;
  int tid = threadIdx.x;
  int l = tid & 63, wid = tid >> 6;
  int wr = wid >> 1, wc = wid & 1;
  const unsigned short* Ab = A + (size_t)b * HW * KD;

  f32x4 acc[4][4];
#pragma unroll
  for (int i = 0; i < 4; ++i)
#pragma unroll
    for (int j = 0; j < 4; ++j) acc[i][j] = (f32x4){0.f, 0.f, 0.f, 0.f};

  const int NT = KD / 32;
  auto STAGE = [&](int buf, int t) {
    int k0 = t * 32;
#pragma unroll
    for (int q = 0; q < 2; ++q) {
      int e = q * 2048 + tid * 8;
      int rl = e >> 5, sl = (e >> 3) & 3;
      gload16(Ab + (size_t)(n0 + rl) * KD + k0 + 8 * (sl ^ ((rl >> 1) & 3)),
              &As[buf][q * 2048 + wid * 512]);
    }
#pragma unroll
    for (int q = 0; q < 2; ++q) {
      int e = q * 2048 + tid * 8;
      int rl = e >> 5, sl = (e >> 3) & 3;
      gload16(Wb + (size_t)(m0 + rl) * KD + k0 + 8 * (sl ^ ((rl >> 1) & 3)),
              &Bs[buf][q * 2048 + wid * 512]);
    }
  };
  STAGE(0, 0);
  for (int t = 0; t < NT; ++t) {
    __syncthreads();
    if (t + 1 < NT) STAGE((t + 1) & 1, t + 1);
    int cur = t & 1;
    short8 af[4], bf[4];
#pragma unroll
    for (int f = 0; f < 4; ++f) {
      int nl = wr * 64 + f * 16 + (l & 15);
      af[f] = *(const short8*)&As[cur][nl * 32 + 8 * ((l >> 4) ^ ((nl >> 1) & 3))];
      int ml = wc * 64 + f * 16 + (l & 15);
      bf[f] = *(const short8*)&Bs[cur][ml * 32 + 8 * ((l >> 4) ^ ((ml >> 1) & 3))];
    }
#pragma unroll
    for (int i = 0; i < 4; ++i)
#pragma unroll
      for (int j = 0; j < 4; ++j)
        acc[i][j] =
            __builtin_amdgcn_mfma_f32_16x16x32_bf16(af[i], bf[j], acc[i][j], 0, 0, 0);
  }
  if (outmode == 0) {
    float* Yf = (float*)Y + (size_t)b * M * HW;
#pragma unroll
    for (int j = 0; j < 4; ++j) {
      int m = m0 + wc * 64 + j * 16 + (l & 15);
      float gm = g[m], bm = bb[m];
#pragma unroll
      for (int i = 0; i < 4; ++i) {
        int n = n0 + wr * 64 + i * 16 + (l >> 4) * 4;
        float4 o;
        o.x = fmaxf(acc[i][j][0] * gm + bm, 0.f);
        o.y = fmaxf(acc[i][j][1] * gm + bm, 0.f);
        o.z = fmaxf(acc[i][j][2] * gm + bm, 0.f);
        o.w = fmaxf(acc[i][j][3] * gm + bm, 0.f);
        *(float4*)&Yf[(size_t)m * HW + n] = o;
      }
    }
  } else {
    unsigned short* Yt = (unsigned short*)Y + (size_t)b * HW * M;
#pragma unroll
    for (int j = 0; j < 4; ++j) {
      int m = m0 + wc * 64 + j * 16 + (l & 15);
      float gm = g[m], bm = bb[m];
#pragma unroll
      for (int i = 0; i < 4; ++i) {
        int n = n0 + wr * 64 + i * 16 + (l >> 4) * 4;
#pragma unroll
        for (int r = 0; r < 4; ++r)
          Yt[(size_t)(n + r) * M + m] = f2bf(fmaxf(acc[i][j][r] * gm + bm, 0.f));
      }
    }
  }
}

// ---------------------------------------------------------------------------
// K5 via MFMA (verified round 6).
// ---------------------------------------------------------------------------
__global__ __launch_bounds__(256) void k5_mfma(
    const unsigned short* __restrict__ q2T,
    const unsigned short* __restrict__ KclsT, const float* __restrict__ Vcls,
    const float* __restrict__ countf, unsigned short* __restrict__ ctxT) {
  __shared__ __align__(16) unsigned short Kl2[32 * 32 * 8];
  __shared__ __align__(16) unsigned short Vl2[4 * 256 * 8];
  __shared__ __align__(16) char RC[25088];
  __shared__ float cntl[NK];
  unsigned short* Ql = (unsigned short*)RC;
  float* simT = (float*)RC;
  unsigned short* Pl = (unsigned short*)(RC + 16896);

  int b = blockIdx.y;
  int p0 = blockIdx.x * 128;
  int tid = threadIdx.x;
  int l = tid & 63, w = tid >> 6;
  const unsigned short* qb = q2T + ((size_t)b * HW + p0) * CTC;

  for (int i = tid; i < NK * 32; i += 256) {
    int m = i >> 5, s = i & 31;
    short8 v = *(const short8*)&KclsT[((size_t)b * NK + m) * CTC + s * 8];
    *(short8*)&Kl2[(s * 32 + m) * 8] = v;
  }
  for (int i = tid; i < 4 * 256; i += 256) {
    int s = i >> 8, c = i & 255;
    union { short8 v; unsigned short u[8]; } pk;
    const float* vr = &Vcls[((size_t)b * CTC + c) * NK];
#pragma unroll
    for (int j = 0; j < 8; ++j) {
      int k = s * 8 + j;
      pk.u[j] = (k < NK) ? f2bf(vr[k]) : (unsigned short)0;
    }
    *(short8*)&Vl2[(s * 256 + c) * 8] = pk.v;
  }
  if (tid < NK) cntl[tid] = countf[b * NK + tid];

  auto STAGE_Q = [&](int buf, int t) {
#pragma unroll
    for (int q = 0; q < 2; ++q) {
      int e = q * 2048 + tid * 8;
      int rl = e >> 5, sl = (e >> 3) & 3;
      gload16(qb + (size_t)rl * CTC + t * 32 + 8 * (sl ^ ((rl >> 1) & 3)),
              &Ql[buf * 4096 + q * 2048 + w * 512]);
    }
  };
  f32x4 acc[2][2];
#pragma unroll
  for (int i = 0; i < 2; ++i)
#pragma unroll
    for (int j = 0; j < 2; ++j) acc[i][j] = (f32x4){0.f, 0.f, 0.f, 0.f};
  STAGE_Q(0, 0);
  for (int t = 0; t < 8; ++t) {
    __syncthreads();
    if (t + 1 < 8) STAGE_Q((t + 1) & 1, t + 1);
    int cur = t & 1;
    short8 aq[2], bk[2];
#pragma unroll
    for (int f = 0; f < 2; ++f) {
      int nl = w * 32 + f * 16 + (l & 15);
      aq[f] =
          *(const short8*)&Ql[cur * 4096 + nl * 32 + 8 * ((l >> 4) ^ ((nl >> 1) & 3))];
      int s = t * 4 + (l >> 4);
      int ml = f * 16 + (l & 15);
      bk[f] = *(const short8*)&Kl2[(s * 32 + ml) * 8];
    }
#pragma unroll
    for (int i = 0; i < 2; ++i)
#pragma unroll
      for (int j = 0; j < 2; ++j)
        acc[i][j] =
            __builtin_amdgcn_mfma_f32_16x16x32_bf16(aq[i], bk[j], acc[i][j], 0, 0, 0);
  }
  __syncthreads();
#pragma unroll
  for (int i = 0; i < 2; ++i)
#pragma unroll
    for (int j = 0; j < 2; ++j) {
      int m = j * 16 + (l & 15);
      if (m < NK) {
#pragma unroll
        for (int r = 0; r < 4; ++r) {
          int p = w * 32 + i * 16 + (l >> 4) * 4 + r;
          simT[p * 33 + m] = acc[i][j][r];
        }
      }
    }
  __syncthreads();
  if (tid < 128) {
    float sims[NK];
#pragma unroll
    for (int k = 0; k < NK; ++k) sims[k] = simT[tid * 33 + k] * 0.0625f;
    float m = -1e30f;
#pragma unroll
    for (int k = 0; k < NK; ++k)
      if (cntl[k] > 0.f) m = fmaxf(m, sims[k]);
    float d = 0.f;
#pragma unroll
    for (int k = 0; k < NK; ++k) {
      float e = (cntl[k] > 0.f) ? expf(sims[k] - m) : 0.f;
      sims[k] = cntl[k] * e;
      d += sims[k];
    }
    float inv = 1.f / d;
#pragma unroll
    for (int s = 0; s < 4; ++s) {
      union { short8 v; unsigned short u8[8]; } pk;
#pragma unroll
      for (int j = 0; j < 8; ++j) {
        int k = s * 8 + j;
        pk.u8[j] = (k < NK) ? f2bf(sims[k] * inv) : (unsigned short)0;
      }
      *(short8*)&Pl[(s * 128 + tid) * 8] = pk.v;
    }
  }
  __syncthreads();
  short8 ap[2];
#pragma unroll
  for (int f = 0; f < 2; ++f) {
    int nl = w * 32 + f * 16 + (l & 15);
    ap[f] = *(const short8*)&Pl[((l >> 4) * 128 + nl) * 8];
  }
  unsigned short* cb = ctxT + ((size_t)b * HW + p0) * CTC;
#pragma unroll
  for (int mc = 0; mc < 4; ++mc) {
#pragma unroll
    for (int mf = 0; mf < 4; ++mf) {
      int ml = mc * 64 + mf * 16 + (l & 15);
      short8 bv = *(const short8*)&Vl2[((l >> 4) * 256 + ml) * 8];
#pragma unroll
      for (int nf = 0; nf < 2; ++nf) {
        f32x4 z = {0.f, 0.f, 0.f, 0.f};
        f32x4 o = __builtin_amdgcn_mfma_f32_16x16x32_bf16(ap[nf], bv, z, 0, 0, 0);
#pragma unroll
        for (int r = 0; r < 4; ++r) {
          int p = w * 32 + nf * 16 + (l >> 4) * 4 + r;
          cb[(size_t)p * CTC + ml] = f2bf(o[r]);
        }
      }
    }
  }
}

// ---------------------------------------------------------------------------
extern "C" void kernel_launch(void* const* d_in, const int* in_sizes, int n_in,
                              void* d_out, int out_size, void* d_ws, size_t ws_size,
                              hipStream_t stream) {
  const float* x = (const float*)d_in[0];
  const float* preds = (const float*)d_in[1];
  const float* q_w1 = (const float*)d_in[3];
  const float* q_g1 = (const float*)d_in[4];
  const float* q_b1 = (const float*)d_in[5];
  const float* q_w2 = (const float*)d_in[6];
  const float* q_g2 = (const float*)d_in[7];
  const float* q_b2 = (const float*)d_in[8];
  const float* k_w1 = (const float*)d_in[9];
  const float* k_g1 = (const float*)d_in[10];
  const float* k_b1 = (const float*)d_in[11];
  const float* k_w2 = (const float*)d_in[12];
  const float* k_g2 = (const float*)d_in[13];
  const float* k_b2 = (const float*)d_in[14];
  const float* v_w = (const float*)d_in[15];
  const float* v_g = (const float*)d_in[16];
  const float* v_b = (const float*)d_in[17];
  const float* o_w = (const float*)d_in[18];
  const float* o_g = (const float*)d_in[19];
  const float* o_b = (const float*)d_in[20];
  float* out = (float*)d_out;

  char* base = (char*)d_ws;
  unsigned short* xT = (unsigned short*)base;               // 33,554,432 B
  unsigned short* q2T = xT;                                 // overlay
  unsigned short* q1T = (unsigned short*)(base + 33554432); // 16,777,216 B
  unsigned short* ctxT = q1T;                               // overlay
  char* f32r = base + 50331648;
  unsigned short* wgtP = (unsigned short*)f32r;             // 2,097,152 B
  float* countf = (float*)(f32r + 2097152);                 // 1,024 B
  float* cls_feat = (float*)(f32r + 2098176);               // 311,296 B
  unsigned short* KclsT = (unsigned short*)(f32r + 2409472);// 77,824 B
  float* Vcls = (float*)(f32r + 2487296);                   // 155,648 B
  unsigned short* wb1 = (unsigned short*)(f32r + 2642944);  // 262,144 B
  unsigned short* wb2 = (unsigned short*)(f32r + 2905088);  // 131,072 B
  unsigned short* wbo = (unsigned short*)(f32r + 3036160);  // 262,144 B
  float* h1g = (float*)(f32r + 3298304);                    // 155,648 B

  hipMemsetAsync(cls_feat, 0, (size_t)NB * NK * CIN * sizeof(float), stream);
  hipMemsetAsync(wgtP, 0, (size_t)NB * 32 * HW * sizeof(unsigned short), stream);

  wconv<<<320, 256, 0, stream>>>(q_w1, q_w2, o_w, wb1, wb2, wbo);
  k1_stats<<<NB, 256, 0, stream>>>(preds, wgtP, countf);
  xpose<<<dim3(HW / 64, CIN / 64, NB), 256, 0, stream>>>(x, xT);
  k2_mfma<<<dim3(CIN / 128, 8, NB), 256, 0, stream>>>(x, wgtP, cls_feat);
  k3a<<<dim3(4, NB * NK), 256, 0, stream>>>(cls_feat, k_w1, k_g1, k_b1, v_w,
                                            v_g, v_b, h1g, Vcls);
  k3b<<<dim3(4, NB * NK), 256, 0, stream>>>(h1g, k_w2, k_g2, k_b2, KclsT);
  gemm_mfma<CIN><<<dim3(32, 2, NB), 256, 0, stream>>>(xT, wb1, q_g1, q_b1,
                                                      (void*)q1T, CTC, 1);
  gemm_mfma<CTC><<<dim3(32, 2, NB), 256, 0, stream>>>(q1T, wb2, q_g2, q_b2,
                                                      (void*)q2T, CTC, 1);
  k5_mfma<<<dim3(HW / 128, NB), 256, 0, stream>>>(q2T, KclsT, Vcls, countf,
                                                  ctxT);
  gemm_mfma<CTC><<<dim3(32, 4, NB), 256, 0, stream>>>(ctxT, wbo, o_g, o_b,
                                                      (void*)out, CIN, 0);
}

// Round 9
// 163.770 us; speedup vs baseline: 3.0416x; 1.0256x over previous
//
#include <hip/hip_runtime.h>
#include <math.h>

#define HW 4096
#define NB 8
#define NK 19
#define CIN 512
#define CTC 256

typedef __attribute__((ext_vector_type(8))) short short8;
typedef __attribute__((ext_vector_type(4))) float f32x4;

__device__ inline unsigned short f2bf(float x) {
  unsigned u = __float_as_uint(x);
  return (unsigned short)((u + 0x7fffu + ((u >> 16) & 1u)) >> 16);  // RNE
}
__device__ inline float bf2f(unsigned short h) {
  return __uint_as_float(((unsigned)h) << 16);
}
__device__ inline void gload16(const void* g, void* l) {
  __builtin_amdgcn_global_load_lds(
      (const __attribute__((address_space(1))) void*)g,
      (__attribute__((address_space(3))) void*)l, 16, 0, 0);
}

// ---------------------------------------------------------------------------
// wconv: weight f32->bf16 convert (ALL 327680 elements: 131072 w1 + 65536 w2
// + 131072 wo; grid 320*256*4 covers exactly) AND zero-fill wgtP + cls_feat
// (replaces the 40-us runtime fillBuffer kernels).
// ---------------------------------------------------------------------------
__global__ __launch_bounds__(256) void wconv(
    const float* __restrict__ w1, const float* __restrict__ w2,
    const float* __restrict__ wo, unsigned short* __restrict__ wb1,
    unsigned short* __restrict__ wb2, unsigned short* __restrict__ wbo,
    uint4* __restrict__ wgtP_z, uint4* __restrict__ cls_feat_z) {
  int gid = blockIdx.x * 256 + threadIdx.x;  // 81920 threads
  int i = gid * 4;                           // [0, 327680)
  const float* src;
  unsigned short* dst;
  int off;
  if (i < 131072) { src = w1; dst = wb1; off = i; }
  else if (i < 196608) { src = w2; dst = wb2; off = i - 131072; }
  else { src = wo; dst = wbo; off = i - 196608; }
  float4 v = *(const float4*)(src + off);
  dst[off + 0] = f2bf(v.x);
  dst[off + 1] = f2bf(v.y);
  dst[off + 2] = f2bf(v.z);
  dst[off + 3] = f2bf(v.w);
  uint4 z = {0u, 0u, 0u, 0u};
  for (int j = gid; j < 131072; j += 81920) wgtP_z[j] = z;    // 2 MB
  for (int j = gid; j < 19456; j += 81920) cls_feat_z[j] = z; // 304 KB
}

// ---------------------------------------------------------------------------
// K1: per-pixel argmax + per-class masked-softmax stats -> wgtP[b][32][HW]
// bf16 scatter matrix + countf. wgtP pre-zeroed (by wconv). (verified)
// ---------------------------------------------------------------------------
__global__ __launch_bounds__(256) void k1_stats(
    const float* __restrict__ preds, unsigned short* __restrict__ wgtP,
    float* __restrict__ countf_g) {
  int b = blockIdx.x;
  __shared__ float s_lds[HW];
  __shared__ unsigned char c_lds[HW];
  __shared__ unsigned int Mu[NK];
  __shared__ float Mf[NK];
  __shared__ float Zf[NK];
  __shared__ unsigned int cnt[NK];
  int tid = threadIdx.x;
  if (tid < NK) { Mu[tid] = 0u; Zf[tid] = 0.f; cnt[tid] = 0u; }
  __syncthreads();
  const float* pb = preds + (size_t)b * NK * HW;
  for (int p = tid; p < HW; p += 256) {
    float best = pb[p];
    int bi = 0;
#pragma unroll
    for (int k = 1; k < NK; ++k) {
      float v = pb[k * HW + p];
      if (v > best) { best = v; bi = k; }
    }
    s_lds[p] = best;
    c_lds[p] = (unsigned char)bi;
    unsigned int fb = __float_as_uint(best);
    unsigned int key = (fb & 0x80000000u) ? ~fb : (fb | 0x80000000u);
    atomicMax(&Mu[bi], key);
    atomicAdd(&cnt[bi], 1u);
  }
  __syncthreads();
  if (tid < NK) {
    unsigned int key = Mu[tid];
    float m = -1e30f;
    if (key != 0u) {
      unsigned int fb = (key & 0x80000000u) ? (key & 0x7fffffffu) : ~key;
      m = __uint_as_float(fb);
    }
    Mf[tid] = m;
  }
  __syncthreads();
  for (int p = tid; p < HW; p += 256) {
    int c = c_lds[p];
    float e = expf(s_lds[p] - Mf[c]);
    s_lds[p] = e;
    atomicAdd(&Zf[c], e);
  }
  __syncthreads();
  for (int p = tid; p < HW; p += 256) {
    int c = c_lds[p];
    wgtP[((size_t)b * 32 + c) * HW + p] = f2bf(s_lds[p] / Zf[c]);
  }
  if (tid < NK) countf_g[b * NK + tid] = (float)cnt[tid];
}

// ---------------------------------------------------------------------------
// x [B][CIN][HW] f32 -> xT [B][HW][CIN] bf16 (verified).
// ---------------------------------------------------------------------------
__global__ __launch_bounds__(256) void xpose(const float* __restrict__ x,
                                             unsigned short* __restrict__ xT) {
  __shared__ float tile[64][65];
  int b = blockIdx.z, c0 = blockIdx.y * 64, p0 = blockIdx.x * 64;
  int tid = threadIdx.x;
  int l = tid & 63, wid = tid >> 6;
#pragma unroll
  for (int r = 0; r < 4; ++r) {
    int cl = r * 16 + (tid >> 4);
    int pl = (tid & 15) * 4;
    float4 v = *(const float4*)&x[((size_t)b * CIN + c0 + cl) * HW + p0 + pl];
    tile[cl][pl + 0] = v.x;
    tile[cl][pl + 1] = v.y;
    tile[cl][pl + 2] = v.z;
    tile[cl][pl + 3] = v.w;
  }
  __syncthreads();
#pragma unroll
  for (int j = 0; j < 16; ++j) {
    int ploc = j * 4 + wid;
    xT[((size_t)b * HW + p0 + ploc) * CIN + c0 + l] = f2bf(tile[l][ploc]);
  }
}

// ---------------------------------------------------------------------------
// K2 as MFMA GEMM: cls_feat[b,k,c] += sum_p wgtP[k][p]*x[c][p] (verified).
// ---------------------------------------------------------------------------
__global__ __launch_bounds__(256) void k2_mfma(
    const float* __restrict__ x, const unsigned short* __restrict__ wgtP,
    float* __restrict__ cls_feat) {
  __shared__ __align__(16) unsigned short As[128 * 32];
  __shared__ __align__(16) unsigned short Bs[32 * 32];
  int b = blockIdx.z;
  int c0 = blockIdx.x * 128;
  int p_base = blockIdx.y * 512;
  int tid = threadIdx.x;
  int l = tid & 63, wv = tid >> 6;
  const float* xb = x + ((size_t)b * CIN + c0) * HW;
  const unsigned short* wb = wgtP + (size_t)b * 32 * HW;

  f32x4 acc[2][2];
#pragma unroll
  for (int i = 0; i < 2; ++i)
#pragma unroll
    for (int j = 0; j < 2; ++j) acc[i][j] = (f32x4){0.f, 0.f, 0.f, 0.f};

  int ch = tid & 7;
  int slot = ch >> 1, half = ch & 1;
  for (int t = 0; t < 16; ++t) {
    int p0 = p_base + t * 32;
    float4 av[4];
#pragma unroll
    for (int pr = 0; pr < 4; ++pr) {
      int crow = pr * 32 + (tid >> 3);
      av[pr] = *(const float4*)&xb[(size_t)crow * HW + p0 + ch * 4];
    }
    uint2 bv = {0, 0};
    {
      int krow = tid >> 3;
      bv = *(const uint2*)&wb[(size_t)krow * HW + p0 + ch * 4];
    }
    __syncthreads();
#pragma unroll
    for (int pr = 0; pr < 4; ++pr) {
      int crow = pr * 32 + (tid >> 3);
      union { unsigned int u[2]; unsigned short s[4]; } pk;
      pk.s[0] = f2bf(av[pr].x);
      pk.s[1] = f2bf(av[pr].y);
      pk.s[2] = f2bf(av[pr].z);
      pk.s[3] = f2bf(av[pr].w);
      *(uint2*)&As[crow * 32 + 8 * (slot ^ ((crow >> 1) & 3)) + 4 * half] =
          *(uint2*)pk.u;
    }
    {
      int krow = tid >> 3;
      *(uint2*)&Bs[krow * 32 + 8 * (slot ^ ((krow >> 1) & 3)) + 4 * half] = bv;
    }
    __syncthreads();
    short8 af[2], bf[2];
#pragma unroll
    for (int f = 0; f < 2; ++f) {
      int nl = wv * 32 + f * 16 + (l & 15);
      af[f] = *(const short8*)&As[nl * 32 + 8 * ((l >> 4) ^ ((nl >> 1) & 3))];
      int ml = f * 16 + (l & 15);
      bf[f] = *(const short8*)&Bs[ml * 32 + 8 * ((l >> 4) ^ ((ml >> 1) & 3))];
    }
#pragma unroll
    for (int i = 0; i < 2; ++i)
#pragma unroll
      for (int j = 0; j < 2; ++j)
        acc[i][j] =
            __builtin_amdgcn_mfma_f32_16x16x32_bf16(af[i], bf[j], acc[i][j], 0, 0, 0);
  }
#pragma unroll
  for (int j = 0; j < 2; ++j) {
    int k = j * 16 + (l & 15);
    if (k < NK) {
#pragma unroll
      for (int i = 0; i < 2; ++i) {
        int n = wv * 32 + i * 16 + (l >> 4) * 4;
#pragma unroll
        for (int r = 0; r < 4; ++r)
          atomicAdd(&cls_feat[((size_t)b * NK + k) * CIN + c0 + n + r],
                    acc[i][j][r]);
      }
    }
  }
}

// ---------------------------------------------------------------------------
// K3a: h1 (kw1 path) + Vcls (vw path), 64 cols/block (verified round 7).
// ---------------------------------------------------------------------------
__global__ __launch_bounds__(256) void k3a(
    const float* __restrict__ cls_feat, const float* __restrict__ kw1,
    const float* __restrict__ kg1, const float* __restrict__ kb1,
    const float* __restrict__ vw, const float* __restrict__ vg,
    const float* __restrict__ vb, float* __restrict__ h1g,
    float* __restrict__ Vcls) {
  int bk = blockIdx.y;
  int b = bk / NK, kc = bk % NK;
  int q = blockIdx.x;
  __shared__ float cf[CIN];
  int tid = threadIdx.x;
  const float* row = cls_feat + (size_t)bk * CIN;
  for (int i = tid; i < CIN; i += 256) cf[i] = row[i];
  __syncthreads();
  int o = tid >> 1, half = tid & 1;
  int col = q * 64 + (o & 63);
  const float* w =
      (o < 64) ? &kw1[(size_t)col * CIN] : &vw[(size_t)col * CIN];
  int base = half * 256;
  float acc[4] = {0.f, 0.f, 0.f, 0.f};
#pragma unroll 8
  for (int i = 0; i < 64; ++i) {
    float4 w4 = *(const float4*)&w[base + i * 4];
    const float* c4 = &cf[base + i * 4];
    acc[i & 3] += w4.x * c4[0] + w4.y * c4[1] + w4.z * c4[2] + w4.w * c4[3];
  }
  float s = (acc[0] + acc[1]) + (acc[2] + acc[3]);
  s += __shfl_xor(s, 1);
  if (half == 0) {
    if (o < 64) {
      h1g[(size_t)bk * CTC + col] = fmaxf(s * kg1[col] + kb1[col], 0.f);
    } else {
      Vcls[((size_t)b * CTC + col) * NK + kc] =
          fmaxf(s * vg[col] + vb[col], 0.f);
    }
  }
}

// ---------------------------------------------------------------------------
// K3b: KclsT from h1 (verified round 7).
// ---------------------------------------------------------------------------
__global__ __launch_bounds__(256) void k3b(
    const float* __restrict__ h1g, const float* __restrict__ kw2,
    const float* __restrict__ kg2, const float* __restrict__ kb2,
    unsigned short* __restrict__ KclsT) {
  int bk = blockIdx.y;
  int q = blockIdx.x;
  __shared__ float h1[CTC];
  int tid = threadIdx.x;
  const float* row = h1g + (size_t)bk * CTC;
  if (tid < CTC) h1[tid] = row[tid];
  __syncthreads();
  int o = tid >> 2, part = tid & 3;
  int col = q * 64 + o;
  const float* w = &kw2[(size_t)col * CTC + part * 64];
  const float* c = &h1[part * 64];
  float acc[4] = {0.f, 0.f, 0.f, 0.f};
#pragma unroll
  for (int i = 0; i < 16; ++i) {
    float4 w4 = *(const float4*)&w[i * 4];
    acc[i & 3] += w4.x * c[i * 4] + w4.y * c[i * 4 + 1] + w4.z * c[i * 4 + 2] +
                  w4.w * c[i * 4 + 3];
  }
  float s = (acc[0] + acc[1]) + (acc[2] + acc[3]);
  s += __shfl_xor(s, 1);
  s += __shfl_xor(s, 2);
  if (part == 0)
    KclsT[(size_t)bk * CTC + col] = f2bf(fmaxf(s * kg2[col] + kb2[col], 0.f));
}

// ---------------------------------------------------------------------------
// MFMA GEMM (verified, unchanged).
// ---------------------------------------------------------------------------
template <int KD>
__global__ __launch_bounds__(256) void gemm_mfma(
    const unsigned short* __restrict__ A, const unsigned short* __restrict__ Wb,
    const float* __restrict__ g, const float* __restrict__ bb,
    void* __restrict__ Y, int M, int outmode) {
  __shared__ __align__(16) unsigned short As[2][128 * 32];
  __shared__ __align__(16) unsigned short Bs[2][128 * 32];
  int b = blockIdx.z;
  int n0 = blockIdx.x * 128;
  int m0 = blockIdx.y * 128;
  int tid = threadIdx.x;
  int l = tid & 63, wid = tid >> 6;
  int wr = wid >> 1, wc = wid & 1;
  const unsigned short* Ab = A + (size_t)b * HW * KD;

  f32x4 acc[4][4];
#pragma unroll
  for (int i = 0; i < 4; ++i)
#pragma unroll
    for (int j = 0; j < 4; ++j) acc[i][j] = (f32x4){0.f, 0.f, 0.f, 0.f};

  const int NT = KD / 32;
  auto STAGE = [&](int buf, int t) {
    int k0 = t * 32;
#pragma unroll
    for (int q = 0; q < 2; ++q) {
      int e = q * 2048 + tid * 8;
      int rl = e >> 5, sl = (e >> 3) & 3;
      gload16(Ab + (size_t)(n0 + rl) * KD + k0 + 8 * (sl ^ ((rl >> 1) & 3)),
              &As[buf][q * 2048 + wid * 512]);
    }
#pragma unroll
    for (int q = 0; q < 2; ++q) {
      int e = q * 2048 + tid * 8;
      int rl = e >> 5, sl = (e >> 3) & 3;
      gload16(Wb + (size_t)(m0 + rl) * KD + k0 + 8 * (sl ^ ((rl >> 1) & 3)),
              &Bs[buf][q * 2048 + wid * 512]);
    }
  };
  STAGE(0, 0);
  for (int t = 0; t < NT; ++t) {
    __syncthreads();
    if (t + 1 < NT) STAGE((t + 1) & 1, t + 1);
    int cur = t & 1;
    short8 af[4], bf[4];
#pragma unroll
    for (int f = 0; f < 4; ++f) {
      int nl = wr * 64 + f * 16 + (l & 15);
      af[f] = *(const short8*)&As[cur][nl * 32 + 8 * ((l >> 4) ^ ((nl >> 1) & 3))];
      int ml = wc * 64 + f * 16 + (l & 15);
      bf[f] = *(const short8*)&Bs[cur][ml * 32 + 8 * ((l >> 4) ^ ((ml >> 1) & 3))];
    }
#pragma unroll
    for (int i = 0; i < 4; ++i)
#pragma unroll
      for (int j = 0; j < 4; ++j)
        acc[i][j] =
            __builtin_amdgcn_mfma_f32_16x16x32_bf16(af[i], bf[j], acc[i][j], 0, 0, 0);
  }
  if (outmode == 0) {
    float* Yf = (float*)Y + (size_t)b * M * HW;
#pragma unroll
    for (int j = 0; j < 4; ++j) {
      int m = m0 + wc * 64 + j * 16 + (l & 15);
      float gm = g[m], bm = bb[m];
#pragma unroll
      for (int i = 0; i < 4; ++i) {
        int n = n0 + wr * 64 + i * 16 + (l >> 4) * 4;
        float4 o;
        o.x = fmaxf(acc[i][j][0] * gm + bm, 0.f);
        o.y = fmaxf(acc[i][j][1] * gm + bm, 0.f);
        o.z = fmaxf(acc[i][j][2] * gm + bm, 0.f);
        o.w = fmaxf(acc[i][j][3] * gm + bm, 0.f);
        *(float4*)&Yf[(size_t)m * HW + n] = o;
      }
    }
  } else {
    unsigned short* Yt = (unsigned short*)Y + (size_t)b * HW * M;
#pragma unroll
    for (int j = 0; j < 4; ++j) {
      int m = m0 + wc * 64 + j * 16 + (l & 15);
      float gm = g[m], bm = bb[m];
#pragma unroll
      for (int i = 0; i < 4; ++i) {
        int n = n0 + wr * 64 + i * 16 + (l >> 4) * 4;
#pragma unroll
        for (int r = 0; r < 4; ++r)
          Yt[(size_t)(n + r) * M + m] = f2bf(fmaxf(acc[i][j][r] * gm + bm, 0.f));
      }
    }
  }
}

// ---------------------------------------------------------------------------
// K5 via MFMA (verified round 6).
// ---------------------------------------------------------------------------
__global__ __launch_bounds__(256) void k5_mfma(
    const unsigned short* __restrict__ q2T,
    const unsigned short* __restrict__ KclsT, const float* __restrict__ Vcls,
    const float* __restrict__ countf, unsigned short* __restrict__ ctxT) {
  __shared__ __align__(16) unsigned short Kl2[32 * 32 * 8];
  __shared__ __align__(16) unsigned short Vl2[4 * 256 * 8];
  __shared__ __align__(16) char RC[25088];
  __shared__ float cntl[NK];
  unsigned short* Ql = (unsigned short*)RC;
  float* simT = (float*)RC;
  unsigned short* Pl = (unsigned short*)(RC + 16896);

  int b = blockIdx.y;
  int p0 = blockIdx.x * 128;
  int tid = threadIdx.x;
  int l = tid & 63, w = tid >> 6;
  const unsigned short* qb = q2T + ((size_t)b * HW + p0) * CTC;

  for (int i = tid; i < NK * 32; i += 256) {
    int m = i >> 5, s = i & 31;
    short8 v = *(const short8*)&KclsT[((size_t)b * NK + m) * CTC + s * 8];
    *(short8*)&Kl2[(s * 32 + m) * 8] = v;
  }
  for (int i = tid; i < 4 * 256; i += 256) {
    int s = i >> 8, c = i & 255;
    union { short8 v; unsigned short u[8]; } pk;
    const float* vr = &Vcls[((size_t)b * CTC + c) * NK];
#pragma unroll
    for (int j = 0; j < 8; ++j) {
      int k = s * 8 + j;
      pk.u[j] = (k < NK) ? f2bf(vr[k]) : (unsigned short)0;
    }
    *(short8*)&Vl2[(s * 256 + c) * 8] = pk.v;
  }
  if (tid < NK) cntl[tid] = countf[b * NK + tid];

  auto STAGE_Q = [&](int buf, int t) {
#pragma unroll
    for (int q = 0; q < 2; ++q) {
      int e = q * 2048 + tid * 8;
      int rl = e >> 5, sl = (e >> 3) & 3;
      gload16(qb + (size_t)rl * CTC + t * 32 + 8 * (sl ^ ((rl >> 1) & 3)),
              &Ql[buf * 4096 + q * 2048 + w * 512]);
    }
  };
  f32x4 acc[2][2];
#pragma unroll
  for (int i = 0; i < 2; ++i)
#pragma unroll
    for (int j = 0; j < 2; ++j) acc[i][j] = (f32x4){0.f, 0.f, 0.f, 0.f};
  STAGE_Q(0, 0);
  for (int t = 0; t < 8; ++t) {
    __syncthreads();
    if (t + 1 < 8) STAGE_Q((t + 1) & 1, t + 1);
    int cur = t & 1;
    short8 aq[2], bk[2];
#pragma unroll
    for (int f = 0; f < 2; ++f) {
      int nl = w * 32 + f * 16 + (l & 15);
      aq[f] =
          *(const short8*)&Ql[cur * 4096 + nl * 32 + 8 * ((l >> 4) ^ ((nl >> 1) & 3))];
      int s = t * 4 + (l >> 4);
      int ml = f * 16 + (l & 15);
      bk[f] = *(const short8*)&Kl2[(s * 32 + ml) * 8];
    }
#pragma unroll
    for (int i = 0; i < 2; ++i)
#pragma unroll
      for (int j = 0; j < 2; ++j)
        acc[i][j] =
            __builtin_amdgcn_mfma_f32_16x16x32_bf16(aq[i], bk[j], acc[i][j], 0, 0, 0);
  }
  __syncthreads();
#pragma unroll
  for (int i = 0; i < 2; ++i)
#pragma unroll
    for (int j = 0; j < 2; ++j) {
      int m = j * 16 + (l & 15);
      if (m < NK) {
#pragma unroll
        for (int r = 0; r < 4; ++r) {
          int p = w * 32 + i * 16 + (l >> 4) * 4 + r;
          simT[p * 33 + m] = acc[i][j][r];
        }
      }
    }
  __syncthreads();
  if (tid < 128) {
    float sims[NK];
#pragma unroll
    for (int k = 0; k < NK; ++k) sims[k] = simT[tid * 33 + k] * 0.0625f;
    float m = -1e30f;
#pragma unroll
    for (int k = 0; k < NK; ++k)
      if (cntl[k] > 0.f) m = fmaxf(m, sims[k]);
    float d = 0.f;
#pragma unroll
    for (int k = 0; k < NK; ++k) {
      float e = (cntl[k] > 0.f) ? expf(sims[k] - m) : 0.f;
      sims[k] = cntl[k] * e;
      d += sims[k];
    }
    float inv = 1.f / d;
#pragma unroll
    for (int s = 0; s < 4; ++s) {
      union { short8 v; unsigned short u8[8]; } pk;
#pragma unroll
      for (int j = 0; j < 8; ++j) {
        int k = s * 8 + j;
        pk.u8[j] = (k < NK) ? f2bf(sims[k] * inv) : (unsigned short)0;
      }
      *(short8*)&Pl[(s * 128 + tid) * 8] = pk.v;
    }
  }
  __syncthreads();
  short8 ap[2];
#pragma unroll
  for (int f = 0; f < 2; ++f) {
    int nl = w * 32 + f * 16 + (l & 15);
    ap[f] = *(const short8*)&Pl[((l >> 4) * 128 + nl) * 8];
  }
  unsigned short* cb = ctxT + ((size_t)b * HW + p0) * CTC;
#pragma unroll
  for (int mc = 0; mc < 4; ++mc) {
#pragma unroll
    for (int mf = 0; mf < 4; ++mf) {
      int ml = mc * 64 + mf * 16 + (l & 15);
      short8 bv = *(const short8*)&Vl2[((l >> 4) * 256 + ml) * 8];
#pragma unroll
      for (int nf = 0; nf < 2; ++nf) {
        f32x4 z = {0.f, 0.f, 0.f, 0.f};
        f32x4 o = __builtin_amdgcn_mfma_f32_16x16x32_bf16(ap[nf], bv, z, 0, 0, 0);
#pragma unroll
        for (int r = 0; r < 4; ++r) {
          int p = w * 32 + nf * 16 + (l >> 4) * 4 + r;
          cb[(size_t)p * CTC + ml] = f2bf(o[r]);
        }
      }
    }
  }
}

// ---------------------------------------------------------------------------
extern "C" void kernel_launch(void* const* d_in, const int* in_sizes, int n_in,
                              void* d_out, int out_size, void* d_ws, size_t ws_size,
                              hipStream_t stream) {
  const float* x = (const float*)d_in[0];
  const float* preds = (const float*)d_in[1];
  const float* q_w1 = (const float*)d_in[3];
  const float* q_g1 = (const float*)d_in[4];
  const float* q_b1 = (const float*)d_in[5];
  const float* q_w2 = (const float*)d_in[6];
  const float* q_g2 = (const float*)d_in[7];
  const float* q_b2 = (const float*)d_in[8];
  const float* k_w1 = (const float*)d_in[9];
  const float* k_g1 = (const float*)d_in[10];
  const float* k_b1 = (const float*)d_in[11];
  const float* k_w2 = (const float*)d_in[12];
  const float* k_g2 = (const float*)d_in[13];
  const float* k_b2 = (const float*)d_in[14];
  const float* v_w = (const float*)d_in[15];
  const float* v_g = (const float*)d_in[16];
  const float* v_b = (const float*)d_in[17];
  const float* o_w = (const float*)d_in[18];
  const float* o_g = (const float*)d_in[19];
  const float* o_b = (const float*)d_in[20];
  float* out = (float*)d_out;

  char* base = (char*)d_ws;
  unsigned short* xT = (unsigned short*)base;               // 33,554,432 B
  unsigned short* q2T = xT;                                 // overlay
  unsigned short* q1T = (unsigned short*)(base + 33554432); // 16,777,216 B
  unsigned short* ctxT = q1T;                               // overlay
  char* f32r = base + 50331648;
  unsigned short* wgtP = (unsigned short*)f32r;             // 2,097,152 B
  float* countf = (float*)(f32r + 2097152);                 // 1,024 B
  float* cls_feat = (float*)(f32r + 2098176);               // 311,296 B
  unsigned short* KclsT = (unsigned short*)(f32r + 2409472);// 77,824 B
  float* Vcls = (float*)(f32r + 2487296);                   // 155,648 B
  unsigned short* wb1 = (unsigned short*)(f32r + 2642944);  // 262,144 B
  unsigned short* wb2 = (unsigned short*)(f32r + 2905088);  // 131,072 B
  unsigned short* wbo = (unsigned short*)(f32r + 3036160);  // 262,144 B
  float* h1g = (float*)(f32r + 3298304);                    // 155,648 B

  wconv<<<320, 256, 0, stream>>>(q_w1, q_w2, o_w, wb1, wb2, wbo,
                                 (uint4*)wgtP, (uint4*)cls_feat);
  k1_stats<<<NB, 256, 0, stream>>>(preds, wgtP, countf);
  xpose<<<dim3(HW / 64, CIN / 64, NB), 256, 0, stream>>>(x, xT);
  k2_mfma<<<dim3(CIN / 128, 8, NB), 256, 0, stream>>>(x, wgtP, cls_feat);
  k3a<<<dim3(4, NB * NK), 256, 0, stream>>>(cls_feat, k_w1, k_g1, k_b1, v_w,
                                            v_g, v_b, h1g, Vcls);
  k3b<<<dim3(4, NB * NK), 256, 0, stream>>>(h1g, k_w2, k_g2, k_b2, KclsT);
  gemm_mfma<CIN><<<dim3(32, 2, NB), 256, 0, stream>>>(xT, wb1, q_g1, q_b1,
                                                      (void*)q1T, CTC, 1);
  gemm_mfma<CTC><<<dim3(32, 2, NB), 256, 0, stream>>>(q1T, wb2, q_g2, q_b2,
                                                      (void*)q2T, CTC, 1);
  k5_mfma<<<dim3(HW / 128, NB), 256, 0, stream>>>(q2T, KclsT, Vcls, countf,
                                                  ctxT);
  gemm_mfma<CTC><<<dim3(32, 4, NB), 256, 0, stream>>>(ctxT, wbo, o_g, o_b,
                                                      (void*)out, CIN, 0);
}

// Round 10
// 137.196 us; speedup vs baseline: 3.6307x; 1.1937x over previous
//
#include <hip/hip_runtime.h>
#include <math.h>

#define HW 4096
#define NB 8
#define NK 19
#define CIN 512
#define CTC 256

typedef __attribute__((ext_vector_type(8))) short short8;
typedef __attribute__((ext_vector_type(4))) float f32x4;

__device__ inline unsigned short f2bf(float x) {
  unsigned u = __float_as_uint(x);
  return (unsigned short)((u + 0x7fffu + ((u >> 16) & 1u)) >> 16);  // RNE
}
__device__ inline float bf2f(unsigned short h) {
  return __uint_as_float(((unsigned)h) << 16);
}
__device__ inline void gload16(const void* g, void* l) {
  __builtin_amdgcn_global_load_lds(
      (const __attribute__((address_space(1))) void*)g,
      (__attribute__((address_space(3))) void*)l, 16, 0, 0);
}

// ---------------------------------------------------------------------------
// wconv: weight f32->bf16 convert (327680 elems, grid covers exactly) AND
// zero-fill wgtP + cls_feat + k1 atomic scratch (Mu/cnt/Zf).
// ---------------------------------------------------------------------------
__global__ __launch_bounds__(256) void wconv(
    const float* __restrict__ w1, const float* __restrict__ w2,
    const float* __restrict__ wo, unsigned short* __restrict__ wb1,
    unsigned short* __restrict__ wb2, unsigned short* __restrict__ wbo,
    uint4* __restrict__ wgtP_z, uint4* __restrict__ cls_feat_z,
    uint4* __restrict__ atom_z) {
  int gid = blockIdx.x * 256 + threadIdx.x;  // 81920 threads
  int i = gid * 4;                           // [0, 327680)
  const float* src;
  unsigned short* dst;
  int off;
  if (i < 131072) { src = w1; dst = wb1; off = i; }
  else if (i < 196608) { src = w2; dst = wb2; off = i - 131072; }
  else { src = wo; dst = wbo; off = i - 196608; }
  float4 v = *(const float4*)(src + off);
  dst[off + 0] = f2bf(v.x);
  dst[off + 1] = f2bf(v.y);
  dst[off + 2] = f2bf(v.z);
  dst[off + 3] = f2bf(v.w);
  uint4 z = {0u, 0u, 0u, 0u};
  for (int j = gid; j < 131072; j += 81920) wgtP_z[j] = z;     // 2 MB
  for (int j = gid; j < 19456; j += 81920) cls_feat_z[j] = z;  // 304 KB
  if (gid < 192) atom_z[gid] = z;                              // Mu/cnt/Zf
}

// ---------------------------------------------------------------------------
// K1 split into 3 streaming passes, grid (16, NB) = 128 blocks each.
// k1a: per-pixel argmax -> bestg/clsg; per-class max (uint key) + count via
//      LDS partials -> global atomics.
// ---------------------------------------------------------------------------
__global__ __launch_bounds__(256) void k1a(
    const float* __restrict__ preds, float* __restrict__ bestg,
    int* __restrict__ clsg, unsigned int* __restrict__ Mu_g,
    unsigned int* __restrict__ cnt_g) {
  int b = blockIdx.y;
  int p = blockIdx.x * 256 + threadIdx.x;
  __shared__ unsigned int Mw[NK];
  __shared__ unsigned int Cw[NK];
  int tid = threadIdx.x;
  if (tid < NK) { Mw[tid] = 0u; Cw[tid] = 0u; }
  __syncthreads();
  const float* pb = preds + (size_t)b * NK * HW;
  float best = pb[p];
  int bi = 0;
#pragma unroll
  for (int k = 1; k < NK; ++k) {
    float v = pb[k * HW + p];
    if (v > best) { best = v; bi = k; }  // strict > = jnp.argmax first-index
  }
  bestg[b * HW + p] = best;
  clsg[b * HW + p] = bi;
  unsigned fb = __float_as_uint(best);
  unsigned key = (fb & 0x80000000u) ? ~fb : (fb | 0x80000000u);
  atomicMax(&Mw[bi], key);
  atomicAdd(&Cw[bi], 1u);
  __syncthreads();
  if (tid < NK) {
    if (Mw[tid]) atomicMax(&Mu_g[b * 32 + tid], Mw[tid]);
    if (Cw[tid]) atomicAdd(&cnt_g[b * 32 + tid], Cw[tid]);
  }
}

// k1b: e = exp(best - Mf[cls]); per-class sum via LDS partials -> global.
__global__ __launch_bounds__(256) void k1b(
    float* __restrict__ bestg, const int* __restrict__ clsg,
    const unsigned int* __restrict__ Mu_g, float* __restrict__ Zf_g) {
  int b = blockIdx.y;
  int p = blockIdx.x * 256 + threadIdx.x;
  __shared__ float Mf[NK];
  __shared__ float Zw[NK];
  int tid = threadIdx.x;
  if (tid < NK) {
    unsigned key = Mu_g[b * 32 + tid];
    float m = -1e30f;
    if (key) {
      unsigned fb = (key & 0x80000000u) ? (key & 0x7fffffffu) : ~key;
      m = __uint_as_float(fb);
    }
    Mf[tid] = m;
    Zw[tid] = 0.f;
  }
  __syncthreads();
  int c = clsg[b * HW + p];
  float e = expf(bestg[b * HW + p] - Mf[c]);
  bestg[b * HW + p] = e;  // in-place (per-thread read-then-write)
  atomicAdd(&Zw[c], e);
  __syncthreads();
  if (tid < NK && Zw[tid] != 0.f) atomicAdd(&Zf_g[b * 32 + tid], Zw[tid]);
}

// k1c: wgtP scatter write + countf.
__global__ __launch_bounds__(256) void k1c(
    const float* __restrict__ eg, const int* __restrict__ clsg,
    const float* __restrict__ Zf_g, const unsigned int* __restrict__ cnt_g,
    unsigned short* __restrict__ wgtP, float* __restrict__ countf) {
  int b = blockIdx.y;
  int p = blockIdx.x * 256 + threadIdx.x;
  __shared__ float Zl[NK];
  int tid = threadIdx.x;
  if (tid < NK) Zl[tid] = Zf_g[b * 32 + tid];
  __syncthreads();
  int c = clsg[b * HW + p];
  wgtP[((size_t)b * 32 + c) * HW + p] = f2bf(eg[b * HW + p] / Zl[c]);
  if (blockIdx.x == 0 && tid < NK)
    countf[b * NK + tid] = (float)cnt_g[b * 32 + tid];
}

// ---------------------------------------------------------------------------
// FUSED xk2: single pass over x (f32, read ONCE). Block = 64c x 512p.
// (a) writes xT [b][p][c] bf16 (verified xpose pattern, 65-pad tile);
// (b) cls_feat[k][c] += sum_p wgtP[k][p]*x[c][p] via MFMA: A-frags converted
//     in-register from the f32 tile; wgtP staged in LDS rows padded to 516
//     shorts (bank-uniform ds_read_b128 B-frags). Split-p atomics epilogue.
// ---------------------------------------------------------------------------
__global__ __launch_bounds__(256) void xk2(
    const float* __restrict__ x, const unsigned short* __restrict__ wgtP,
    unsigned short* __restrict__ xT, float* __restrict__ cls_feat) {
  __shared__ float tile[64][65];               // 16.6 KB
  __shared__ unsigned short Bs[32 * 516];      // 33.0 KB, row pad 516
  int b = blockIdx.z, c0 = blockIdx.y * 64, pbase = blockIdx.x * 512;
  int tid = threadIdx.x;
  int l = tid & 63, w = tid >> 6;
  // stage wgtP [32 classes][512 p] (zero rows for k>=19 contribute nothing)
  {
    const unsigned short* wb =
        wgtP + ((size_t)b * 32 + (tid >> 3)) * HW + pbase;
    int cof = (tid & 7) * 8;
#pragma unroll
    for (int it = 0; it < 8; ++it)
      *(short8*)&Bs[(tid >> 3) * 516 + cof + it * 64] =
          *(const short8*)&wb[cof + it * 64];
  }
  f32x4 acc[2];
  acc[0] = (f32x4){0.f, 0.f, 0.f, 0.f};
  acc[1] = (f32x4){0.f, 0.f, 0.f, 0.f};
  int cbase = w * 16;  // wave's 16-channel slice of the 64-channel tile
  for (int s = 0; s < 8; ++s) {
    int ps = pbase + s * 64;
    __syncthreads();  // prev sub-tile consumed (and Bs staged, s=0)
#pragma unroll
    for (int r = 0; r < 4; ++r) {
      int cl = r * 16 + (tid >> 4);
      int pl = (tid & 15) * 4;
      float4 v = *(const float4*)&x[((size_t)b * CIN + c0 + cl) * HW + ps + pl];
      tile[cl][pl + 0] = v.x;
      tile[cl][pl + 1] = v.y;
      tile[cl][pl + 2] = v.z;
      tile[cl][pl + 3] = v.w;
    }
    __syncthreads();
    // (a) transpose writes: lane = channel, 128B-contiguous global stores
#pragma unroll
    for (int j = 0; j < 16; ++j) {
      int ploc = j * 4 + w;
      xT[((size_t)b * HW + ps + ploc) * CIN + c0 + l] = f2bf(tile[l][ploc]);
    }
    // (b) two K=32 MFMA chunks over this sub-tile's pixels
#pragma unroll
    for (int ch = 0; ch < 2; ++ch) {
      int pt = ch * 32 + (l >> 4) * 8;  // pixel offset within sub-tile
      union { short8 v; unsigned short u[8]; } af;
      const float* tp = &tile[cbase + (l & 15)][pt];
#pragma unroll
      for (int j = 0; j < 8; ++j) af.u[j] = f2bf(tp[j]);
      int pg = s * 64 + pt;  // pixel offset within block's 512 range
#pragma unroll
      for (int mf = 0; mf < 2; ++mf) {
        short8 bf = *(const short8*)&Bs[(mf * 16 + (l & 15)) * 516 + pg];
        acc[mf] =
            __builtin_amdgcn_mfma_f32_16x16x32_bf16(af.v, bf, acc[mf], 0, 0, 0);
      }
    }
  }
  // epilogue: col = class = mf*16+(l&15); row = channel = cbase+(l>>4)*4+r
#pragma unroll
  for (int mf = 0; mf < 2; ++mf) {
    int k = mf * 16 + (l & 15);
    if (k < NK) {
#pragma unroll
      for (int r = 0; r < 4; ++r) {
        int c = c0 + cbase + (l >> 4) * 4 + r;
        atomicAdd(&cls_feat[((size_t)b * NK + k) * CIN + c], acc[mf][r]);
      }
    }
  }
}

// ---------------------------------------------------------------------------
// K3a: h1 (kw1 path) + Vcls (vw path), 64 cols/block (verified round 7).
// ---------------------------------------------------------------------------
__global__ __launch_bounds__(256) void k3a(
    const float* __restrict__ cls_feat, const float* __restrict__ kw1,
    const float* __restrict__ kg1, const float* __restrict__ kb1,
    const float* __restrict__ vw, const float* __restrict__ vg,
    const float* __restrict__ vb, float* __restrict__ h1g,
    float* __restrict__ Vcls) {
  int bk = blockIdx.y;
  int b = bk / NK, kc = bk % NK;
  int q = blockIdx.x;
  __shared__ float cf[CIN];
  int tid = threadIdx.x;
  const float* row = cls_feat + (size_t)bk * CIN;
  for (int i = tid; i < CIN; i += 256) cf[i] = row[i];
  __syncthreads();
  int o = tid >> 1, half = tid & 1;
  int col = q * 64 + (o & 63);
  const float* w =
      (o < 64) ? &kw1[(size_t)col * CIN] : &vw[(size_t)col * CIN];
  int base = half * 256;
  float acc[4] = {0.f, 0.f, 0.f, 0.f};
#pragma unroll 8
  for (int i = 0; i < 64; ++i) {
    float4 w4 = *(const float4*)&w[base + i * 4];
    const float* c4 = &cf[base + i * 4];
    acc[i & 3] += w4.x * c4[0] + w4.y * c4[1] + w4.z * c4[2] + w4.w * c4[3];
  }
  float s = (acc[0] + acc[1]) + (acc[2] + acc[3]);
  s += __shfl_xor(s, 1);
  if (half == 0) {
    if (o < 64) {
      h1g[(size_t)bk * CTC + col] = fmaxf(s * kg1[col] + kb1[col], 0.f);
    } else {
      Vcls[((size_t)b * CTC + col) * NK + kc] =
          fmaxf(s * vg[col] + vb[col], 0.f);
    }
  }
}

// ---------------------------------------------------------------------------
// K3b: KclsT from h1 (verified round 7).
// ---------------------------------------------------------------------------
__global__ __launch_bounds__(256) void k3b(
    const float* __restrict__ h1g, const float* __restrict__ kw2,
    const float* __restrict__ kg2, const float* __restrict__ kb2,
    unsigned short* __restrict__ KclsT) {
  int bk = blockIdx.y;
  int q = blockIdx.x;
  __shared__ float h1[CTC];
  int tid = threadIdx.x;
  const float* row = h1g + (size_t)bk * CTC;
  if (tid < CTC) h1[tid] = row[tid];
  __syncthreads();
  int o = tid >> 2, part = tid & 3;
  int col = q * 64 + o;
  const float* w = &kw2[(size_t)col * CTC + part * 64];
  const float* c = &h1[part * 64];
  float acc[4] = {0.f, 0.f, 0.f, 0.f};
#pragma unroll
  for (int i = 0; i < 16; ++i) {
    float4 w4 = *(const float4*)&w[i * 4];
    acc[i & 3] += w4.x * c[i * 4] + w4.y * c[i * 4 + 1] + w4.z * c[i * 4 + 2] +
                  w4.w * c[i * 4 + 3];
  }
  float s = (acc[0] + acc[1]) + (acc[2] + acc[3]);
  s += __shfl_xor(s, 1);
  s += __shfl_xor(s, 2);
  if (part == 0)
    KclsT[(size_t)bk * CTC + col] = f2bf(fmaxf(s * kg2[col] + kb2[col], 0.f));
}

// ---------------------------------------------------------------------------
// MFMA GEMM (verified, unchanged).
// ---------------------------------------------------------------------------
template <int KD>
__global__ __launch_bounds__(256) void gemm_mfma(
    const unsigned short* __restrict__ A, const unsigned short* __restrict__ Wb,
    const float* __restrict__ g, const float* __restrict__ bb,
    void* __restrict__ Y, int M, int outmode) {
  __shared__ __align__(16) unsigned short As[2][128 * 32];
  __shared__ __align__(16) unsigned short Bs[2][128 * 32];
  int b = blockIdx.z;
  int n0 = blockIdx.x * 128;
  int m0 = blockIdx.y * 128;
  int tid = threadIdx.x;
  int l = tid & 63, wid = tid >> 6;
  int wr = wid >> 1, wc = wid & 1;
  const unsigned short* Ab = A + (size_t)b * HW * KD;

  f32x4 acc[4][4];
#pragma unroll
  for (int i = 0; i < 4; ++i)
#pragma unroll
    for (int j = 0; j < 4; ++j) acc[i][j] = (f32x4){0.f, 0.f, 0.f, 0.f};

  const int NT = KD / 32;
  auto STAGE = [&](int buf, int t) {
    int k0 = t * 32;
#pragma unroll
    for (int q = 0; q < 2; ++q) {
      int e = q * 2048 + tid * 8;
      int rl = e >> 5, sl = (e >> 3) & 3;
      gload16(Ab + (size_t)(n0 + rl) * KD + k0 + 8 * (sl ^ ((rl >> 1) & 3)),
              &As[buf][q * 2048 + wid * 512]);
    }
#pragma unroll
    for (int q = 0; q < 2; ++q) {
      int e = q * 2048 + tid * 8;
      int rl = e >> 5, sl = (e >> 3) & 3;
      gload16(Wb + (size_t)(m0 + rl) * KD + k0 + 8 * (sl ^ ((rl >> 1) & 3)),
              &Bs[buf][q * 2048 + wid * 512]);
    }
  };
  STAGE(0, 0);
  for (int t = 0; t < NT; ++t) {
    __syncthreads();
    if (t + 1 < NT) STAGE((t + 1) & 1, t + 1);
    int cur = t & 1;
    short8 af[4], bf[4];
#pragma unroll
    for (int f = 0; f < 4; ++f) {
      int nl = wr * 64 + f * 16 + (l & 15);
      af[f] = *(const short8*)&As[cur][nl * 32 + 8 * ((l >> 4) ^ ((nl >> 1) & 3))];
      int ml = wc * 64 + f * 16 + (l & 15);
      bf[f] = *(const short8*)&Bs[cur][ml * 32 + 8 * ((l >> 4) ^ ((ml >> 1) & 3))];
    }
#pragma unroll
    for (int i = 0; i < 4; ++i)
#pragma unroll
      for (int j = 0; j < 4; ++j)
        acc[i][j] =
            __builtin_amdgcn_mfma_f32_16x16x32_bf16(af[i], bf[j], acc[i][j], 0, 0, 0);
  }
  if (outmode == 0) {
    float* Yf = (float*)Y + (size_t)b * M * HW;
#pragma unroll
    for (int j = 0; j < 4; ++j) {
      int m = m0 + wc * 64 + j * 16 + (l & 15);
      float gm = g[m], bm = bb[m];
#pragma unroll
      for (int i = 0; i < 4; ++i) {
        int n = n0 + wr * 64 + i * 16 + (l >> 4) * 4;
        float4 o;
        o.x = fmaxf(acc[i][j][0] * gm + bm, 0.f);
        o.y = fmaxf(acc[i][j][1] * gm + bm, 0.f);
        o.z = fmaxf(acc[i][j][2] * gm + bm, 0.f);
        o.w = fmaxf(acc[i][j][3] * gm + bm, 0.f);
        *(float4*)&Yf[(size_t)m * HW + n] = o;
      }
    }
  } else {
    unsigned short* Yt = (unsigned short*)Y + (size_t)b * HW * M;
#pragma unroll
    for (int j = 0; j < 4; ++j) {
      int m = m0 + wc * 64 + j * 16 + (l & 15);
      float gm = g[m], bm = bb[m];
#pragma unroll
      for (int i = 0; i < 4; ++i) {
        int n = n0 + wr * 64 + i * 16 + (l >> 4) * 4;
#pragma unroll
        for (int r = 0; r < 4; ++r)
          Yt[(size_t)(n + r) * M + m] = f2bf(fmaxf(acc[i][j][r] * gm + bm, 0.f));
      }
    }
  }
}

// ---------------------------------------------------------------------------
// K5 via MFMA (verified round 6).
// ---------------------------------------------------------------------------
__global__ __launch_bounds__(256) void k5_mfma(
    const unsigned short* __restrict__ q2T,
    const unsigned short* __restrict__ KclsT, const float* __restrict__ Vcls,
    const float* __restrict__ countf, unsigned short* __restrict__ ctxT) {
  __shared__ __align__(16) unsigned short Kl2[32 * 32 * 8];
  __shared__ __align__(16) unsigned short Vl2[4 * 256 * 8];
  __shared__ __align__(16) char RC[25088];
  __shared__ float cntl[NK];
  unsigned short* Ql = (unsigned short*)RC;
  float* simT = (float*)RC;
  unsigned short* Pl = (unsigned short*)(RC + 16896);

  int b = blockIdx.y;
  int p0 = blockIdx.x * 128;
  int tid = threadIdx.x;
  int l = tid & 63, w = tid >> 6;
  const unsigned short* qb = q2T + ((size_t)b * HW + p0) * CTC;

  for (int i = tid; i < NK * 32; i += 256) {
    int m = i >> 5, s = i & 31;
    short8 v = *(const short8*)&KclsT[((size_t)b * NK + m) * CTC + s * 8];
    *(short8*)&Kl2[(s * 32 + m) * 8] = v;
  }
  for (int i = tid; i < 4 * 256; i += 256) {
    int s = i >> 8, c = i & 255;
    union { short8 v; unsigned short u[8]; } pk;
    const float* vr = &Vcls[((size_t)b * CTC + c) * NK];
#pragma unroll
    for (int j = 0; j < 8; ++j) {
      int k = s * 8 + j;
      pk.u[j] = (k < NK) ? f2bf(vr[k]) : (unsigned short)0;
    }
    *(short8*)&Vl2[(s * 256 + c) * 8] = pk.v;
  }
  if (tid < NK) cntl[tid] = countf[b * NK + tid];

  auto STAGE_Q = [&](int buf, int t) {
#pragma unroll
    for (int q = 0; q < 2; ++q) {
      int e = q * 2048 + tid * 8;
      int rl = e >> 5, sl = (e >> 3) & 3;
      gload16(qb + (size_t)rl * CTC + t * 32 + 8 * (sl ^ ((rl >> 1) & 3)),
              &Ql[buf * 4096 + q * 2048 + w * 512]);
    }
  };
  f32x4 acc[2][2];
#pragma unroll
  for (int i = 0; i < 2; ++i)
#pragma unroll
    for (int j = 0; j < 2; ++j) acc[i][j] = (f32x4){0.f, 0.f, 0.f, 0.f};
  STAGE_Q(0, 0);
  for (int t = 0; t < 8; ++t) {
    __syncthreads();
    if (t + 1 < 8) STAGE_Q((t + 1) & 1, t + 1);
    int cur = t & 1;
    short8 aq[2], bk[2];
#pragma unroll
    for (int f = 0; f < 2; ++f) {
      int nl = w * 32 + f * 16 + (l & 15);
      aq[f] =
          *(const short8*)&Ql[cur * 4096 + nl * 32 + 8 * ((l >> 4) ^ ((nl >> 1) & 3))];
      int s = t * 4 + (l >> 4);
      int ml = f * 16 + (l & 15);
      bk[f] = *(const short8*)&Kl2[(s * 32 + ml) * 8];
    }
#pragma unroll
    for (int i = 0; i < 2; ++i)
#pragma unroll
      for (int j = 0; j < 2; ++j)
        acc[i][j] =
            __builtin_amdgcn_mfma_f32_16x16x32_bf16(aq[i], bk[j], acc[i][j], 0, 0, 0);
  }
  __syncthreads();
#pragma unroll
  for (int i = 0; i < 2; ++i)
#pragma unroll
    for (int j = 0; j < 2; ++j) {
      int m = j * 16 + (l & 15);
      if (m < NK) {
#pragma unroll
        for (int r = 0; r < 4; ++r) {
          int p = w * 32 + i * 16 + (l >> 4) * 4 + r;
          simT[p * 33 + m] = acc[i][j][r];
        }
      }
    }
  __syncthreads();
  if (tid < 128) {
    float sims[NK];
#pragma unroll
    for (int k = 0; k < NK; ++k) sims[k] = simT[tid * 33 + k] * 0.0625f;
    float m = -1e30f;
#pragma unroll
    for (int k = 0; k < NK; ++k)
      if (cntl[k] > 0.f) m = fmaxf(m, sims[k]);
    float d = 0.f;
#pragma unroll
    for (int k = 0; k < NK; ++k) {
      float e = (cntl[k] > 0.f) ? expf(sims[k] - m) : 0.f;
      sims[k] = cntl[k] * e;
      d += sims[k];
    }
    float inv = 1.f / d;
#pragma unroll
    for (int s = 0; s < 4; ++s) {
      union { short8 v; unsigned short u8[8]; } pk;
#pragma unroll
      for (int j = 0; j < 8; ++j) {
        int k = s * 8 + j;
        pk.u8[j] = (k < NK) ? f2bf(sims[k] * inv) : (unsigned short)0;
      }
      *(short8*)&Pl[(s * 128 + tid) * 8] = pk.v;
    }
  }
  __syncthreads();
  short8 ap[2];
#pragma unroll
  for (int f = 0; f < 2; ++f) {
    int nl = w * 32 + f * 16 + (l & 15);
    ap[f] = *(const short8*)&Pl[((l >> 4) * 128 + nl) * 8];
  }
  unsigned short* cb = ctxT + ((size_t)b * HW + p0) * CTC;
#pragma unroll
  for (int mc = 0; mc < 4; ++mc) {
#pragma unroll
    for (int mf = 0; mf < 4; ++mf) {
      int ml = mc * 64 + mf * 16 + (l & 15);
      short8 bv = *(const short8*)&Vl2[((l >> 4) * 256 + ml) * 8];
#pragma unroll
      for (int nf = 0; nf < 2; ++nf) {
        f32x4 z = {0.f, 0.f, 0.f, 0.f};
        f32x4 o = __builtin_amdgcn_mfma_f32_16x16x32_bf16(ap[nf], bv, z, 0, 0, 0);
#pragma unroll
        for (int r = 0; r < 4; ++r) {
          int p = w * 32 + nf * 16 + (l >> 4) * 4 + r;
          cb[(size_t)p * CTC + ml] = f2bf(o[r]);
        }
      }
    }
  }
}

// ---------------------------------------------------------------------------
extern "C" void kernel_launch(void* const* d_in, const int* in_sizes, int n_in,
                              void* d_out, int out_size, void* d_ws, size_t ws_size,
                              hipStream_t stream) {
  const float* x = (const float*)d_in[0];
  const float* preds = (const float*)d_in[1];
  const float* q_w1 = (const float*)d_in[3];
  const float* q_g1 = (const float*)d_in[4];
  const float* q_b1 = (const float*)d_in[5];
  const float* q_w2 = (const float*)d_in[6];
  const float* q_g2 = (const float*)d_in[7];
  const float* q_b2 = (const float*)d_in[8];
  const float* k_w1 = (const float*)d_in[9];
  const float* k_g1 = (const float*)d_in[10];
  const float* k_b1 = (const float*)d_in[11];
  const float* k_w2 = (const float*)d_in[12];
  const float* k_g2 = (const float*)d_in[13];
  const float* k_b2 = (const float*)d_in[14];
  const float* v_w = (const float*)d_in[15];
  const float* v_g = (const float*)d_in[16];
  const float* v_b = (const float*)d_in[17];
  const float* o_w = (const float*)d_in[18];
  const float* o_g = (const float*)d_in[19];
  const float* o_b = (const float*)d_in[20];
  float* out = (float*)d_out;

  char* base = (char*)d_ws;
  unsigned short* xT = (unsigned short*)base;               // 33,554,432 B
  unsigned short* q2T = xT;                                 // overlay
  unsigned short* q1T = (unsigned short*)(base + 33554432); // 16,777,216 B
  unsigned short* ctxT = q1T;                               // overlay
  char* f32r = base + 50331648;
  unsigned short* wgtP = (unsigned short*)f32r;              // 2,097,152 B
  float* countf = (float*)(f32r + 2097152);                  // 1,024 B
  float* cls_feat = (float*)(f32r + 2098176);                // 311,296 B
  unsigned short* KclsT = (unsigned short*)(f32r + 2409472); // 77,824 B
  float* Vcls = (float*)(f32r + 2487296);                    // 155,648 B
  unsigned short* wb1 = (unsigned short*)(f32r + 2642944);   // 262,144 B
  unsigned short* wb2 = (unsigned short*)(f32r + 2905088);   // 131,072 B
  unsigned short* wbo = (unsigned short*)(f32r + 3036160);   // 262,144 B
  float* h1g = (float*)(f32r + 3298304);                     // 155,648 B
  float* bestg = (float*)(f32r + 3453952);                   // 131,072 B
  int* clsg = (int*)(f32r + 3585024);                        // 131,072 B
  unsigned int* Mu_g = (unsigned int*)(f32r + 3716096);      // 1,024 B
  unsigned int* cnt_g = (unsigned int*)(f32r + 3717120);     // 1,024 B
  float* Zf_g = (float*)(f32r + 3718144);                    // 1,024 B

  wconv<<<320, 256, 0, stream>>>(q_w1, q_w2, o_w, wb1, wb2, wbo,
                                 (uint4*)wgtP, (uint4*)cls_feat,
                                 (uint4*)Mu_g);  // Mu/cnt/Zf contiguous 3 KB
  k1a<<<dim3(16, NB), 256, 0, stream>>>(preds, bestg, clsg, Mu_g, cnt_g);
  k1b<<<dim3(16, NB), 256, 0, stream>>>(bestg, clsg, Mu_g, Zf_g);
  k1c<<<dim3(16, NB), 256, 0, stream>>>(bestg, clsg, Zf_g, cnt_g, wgtP,
                                        countf);
  xk2<<<dim3(8, 8, NB), 256, 0, stream>>>(x, wgtP, xT, cls_feat);
  k3a<<<dim3(4, NB * NK), 256, 0, stream>>>(cls_feat, k_w1, k_g1, k_b1, v_w,
                                            v_g, v_b, h1g, Vcls);
  k3b<<<dim3(4, NB * NK), 256, 0, stream>>>(h1g, k_w2, k_g2, k_b2, KclsT);
  gemm_mfma<CIN><<<dim3(32, 2, NB), 256, 0, stream>>>(xT, wb1, q_g1, q_b1,
                                                      (void*)q1T, CTC, 1);
  gemm_mfma<CTC><<<dim3(32, 2, NB), 256, 0, stream>>>(q1T, wb2, q_g2, q_b2,
                                                      (void*)q2T, CTC, 1);
  k5_mfma<<<dim3(HW / 128, NB), 256, 0, stream>>>(q2T, KclsT, Vcls, countf,
                                                  ctxT);
  gemm_mfma<CTC><<<dim3(32, 4, NB), 256, 0, stream>>>(ctxT, wbo, o_g, o_b,
                                                      (void*)out, CIN, 0);
}

// Round 11
// 132.621 us; speedup vs baseline: 3.7559x; 1.0345x over previous
//
#include <hip/hip_runtime.h>
#include <math.h>

#define HW 4096
#define NB 8
#define NK 19
#define CIN 512
#define CTC 256

typedef __attribute__((ext_vector_type(8))) short short8;
typedef __attribute__((ext_vector_type(4))) float f32x4;

__device__ inline unsigned short f2bf(float x) {
  unsigned u = __float_as_uint(x);
  return (unsigned short)((u + 0x7fffu + ((u >> 16) & 1u)) >> 16);  // RNE
}
__device__ inline float bf2f(unsigned short h) {
  return __uint_as_float(((unsigned)h) << 16);
}
__device__ inline void gload16(const void* g, void* l) {
  __builtin_amdgcn_global_load_lds(
      (const __attribute__((address_space(1))) void*)g,
      (__attribute__((address_space(3))) void*)l, 16, 0, 0);
}

// ---------------------------------------------------------------------------
// wconv: weight f32->bf16 convert (327680 elems exactly) + zero-fills.
// ---------------------------------------------------------------------------
__global__ __launch_bounds__(256) void wconv(
    const float* __restrict__ w1, const float* __restrict__ w2,
    const float* __restrict__ wo, unsigned short* __restrict__ wb1,
    unsigned short* __restrict__ wb2, unsigned short* __restrict__ wbo,
    uint4* __restrict__ wgtP_z, uint4* __restrict__ cls_feat_z,
    uint4* __restrict__ atom_z) {
  int gid = blockIdx.x * 256 + threadIdx.x;
  int i = gid * 4;
  const float* src;
  unsigned short* dst;
  int off;
  if (i < 131072) { src = w1; dst = wb1; off = i; }
  else if (i < 196608) { src = w2; dst = wb2; off = i - 131072; }
  else { src = wo; dst = wbo; off = i - 196608; }
  float4 v = *(const float4*)(src + off);
  dst[off + 0] = f2bf(v.x);
  dst[off + 1] = f2bf(v.y);
  dst[off + 2] = f2bf(v.z);
  dst[off + 3] = f2bf(v.w);
  uint4 z = {0u, 0u, 0u, 0u};
  for (int j = gid; j < 131072; j += 81920) wgtP_z[j] = z;
  for (int j = gid; j < 19456; j += 81920) cls_feat_z[j] = z;
  if (gid < 192) atom_z[gid] = z;
}

// ---------------------------------------------------------------------------
// K1 split (verified round 10): k1a argmax+max+count, k1b exp+sum, k1c scatter.
// ---------------------------------------------------------------------------
__global__ __launch_bounds__(256) void k1a(
    const float* __restrict__ preds, float* __restrict__ bestg,
    int* __restrict__ clsg, unsigned int* __restrict__ Mu_g,
    unsigned int* __restrict__ cnt_g) {
  int b = blockIdx.y;
  int p = blockIdx.x * 256 + threadIdx.x;
  __shared__ unsigned int Mw[NK];
  __shared__ unsigned int Cw[NK];
  int tid = threadIdx.x;
  if (tid < NK) { Mw[tid] = 0u; Cw[tid] = 0u; }
  __syncthreads();
  const float* pb = preds + (size_t)b * NK * HW;
  float best = pb[p];
  int bi = 0;
#pragma unroll
  for (int k = 1; k < NK; ++k) {
    float v = pb[k * HW + p];
    if (v > best) { best = v; bi = k; }
  }
  bestg[b * HW + p] = best;
  clsg[b * HW + p] = bi;
  unsigned fb = __float_as_uint(best);
  unsigned key = (fb & 0x80000000u) ? ~fb : (fb | 0x80000000u);
  atomicMax(&Mw[bi], key);
  atomicAdd(&Cw[bi], 1u);
  __syncthreads();
  if (tid < NK) {
    if (Mw[tid]) atomicMax(&Mu_g[b * 32 + tid], Mw[tid]);
    if (Cw[tid]) atomicAdd(&cnt_g[b * 32 + tid], Cw[tid]);
  }
}

__global__ __launch_bounds__(256) void k1b(
    float* __restrict__ bestg, const int* __restrict__ clsg,
    const unsigned int* __restrict__ Mu_g, float* __restrict__ Zf_g) {
  int b = blockIdx.y;
  int p = blockIdx.x * 256 + threadIdx.x;
  __shared__ float Mf[NK];
  __shared__ float Zw[NK];
  int tid = threadIdx.x;
  if (tid < NK) {
    unsigned key = Mu_g[b * 32 + tid];
    float m = -1e30f;
    if (key) {
      unsigned fb = (key & 0x80000000u) ? (key & 0x7fffffffu) : ~key;
      m = __uint_as_float(fb);
    }
    Mf[tid] = m;
    Zw[tid] = 0.f;
  }
  __syncthreads();
  int c = clsg[b * HW + p];
  float e = expf(bestg[b * HW + p] - Mf[c]);
  bestg[b * HW + p] = e;
  atomicAdd(&Zw[c], e);
  __syncthreads();
  if (tid < NK && Zw[tid] != 0.f) atomicAdd(&Zf_g[b * 32 + tid], Zw[tid]);
}

__global__ __launch_bounds__(256) void k1c(
    const float* __restrict__ eg, const int* __restrict__ clsg,
    const float* __restrict__ Zf_g, const unsigned int* __restrict__ cnt_g,
    unsigned short* __restrict__ wgtP, float* __restrict__ countf) {
  int b = blockIdx.y;
  int p = blockIdx.x * 256 + threadIdx.x;
  __shared__ float Zl[NK];
  int tid = threadIdx.x;
  if (tid < NK) Zl[tid] = Zf_g[b * 32 + tid];
  __syncthreads();
  int c = clsg[b * HW + p];
  wgtP[((size_t)b * 32 + c) * HW + p] = f2bf(eg[b * HW + p] / Zl[c]);
  if (blockIdx.x == 0 && tid < NK)
    countf[b * NK + tid] = (float)cnt_g[b * 32 + tid];
}

// ---------------------------------------------------------------------------
// FUSED xk2 (verified round 10): x read once -> xT transpose + cls_feat MFMA.
// ---------------------------------------------------------------------------
__global__ __launch_bounds__(256) void xk2(
    const float* __restrict__ x, const unsigned short* __restrict__ wgtP,
    unsigned short* __restrict__ xT, float* __restrict__ cls_feat) {
  __shared__ float tile[64][65];
  __shared__ unsigned short Bs[32 * 516];
  int b = blockIdx.z, c0 = blockIdx.y * 64, pbase = blockIdx.x * 512;
  int tid = threadIdx.x;
  int l = tid & 63, w = tid >> 6;
  {
    const unsigned short* wb =
        wgtP + ((size_t)b * 32 + (tid >> 3)) * HW + pbase;
    int cof = (tid & 7) * 8;
#pragma unroll
    for (int it = 0; it < 8; ++it)
      *(short8*)&Bs[(tid >> 3) * 516 + cof + it * 64] =
          *(const short8*)&wb[cof + it * 64];
  }
  f32x4 acc[2];
  acc[0] = (f32x4){0.f, 0.f, 0.f, 0.f};
  acc[1] = (f32x4){0.f, 0.f, 0.f, 0.f};
  int cbase = w * 16;
  for (int s = 0; s < 8; ++s) {
    int ps = pbase + s * 64;
    __syncthreads();
#pragma unroll
    for (int r = 0; r < 4; ++r) {
      int cl = r * 16 + (tid >> 4);
      int pl = (tid & 15) * 4;
      float4 v = *(const float4*)&x[((size_t)b * CIN + c0 + cl) * HW + ps + pl];
      tile[cl][pl + 0] = v.x;
      tile[cl][pl + 1] = v.y;
      tile[cl][pl + 2] = v.z;
      tile[cl][pl + 3] = v.w;
    }
    __syncthreads();
#pragma unroll
    for (int j = 0; j < 16; ++j) {
      int ploc = j * 4 + w;
      xT[((size_t)b * HW + ps + ploc) * CIN + c0 + l] = f2bf(tile[l][ploc]);
    }
#pragma unroll
    for (int ch = 0; ch < 2; ++ch) {
      int pt = ch * 32 + (l >> 4) * 8;
      union { short8 v; unsigned short u[8]; } af;
      const float* tp = &tile[cbase + (l & 15)][pt];
#pragma unroll
      for (int j = 0; j < 8; ++j) af.u[j] = f2bf(tp[j]);
      int pg = s * 64 + pt;
#pragma unroll
      for (int mf = 0; mf < 2; ++mf) {
        short8 bf = *(const short8*)&Bs[(mf * 16 + (l & 15)) * 516 + pg];
        acc[mf] =
            __builtin_amdgcn_mfma_f32_16x16x32_bf16(af.v, bf, acc[mf], 0, 0, 0);
      }
    }
  }
#pragma unroll
  for (int mf = 0; mf < 2; ++mf) {
    int k = mf * 16 + (l & 15);
    if (k < NK) {
#pragma unroll
      for (int r = 0; r < 4; ++r) {
        int c = c0 + cbase + (l >> 4) * 4 + r;
        atomicAdd(&cls_feat[((size_t)b * NK + k) * CIN + c], acc[mf][r]);
      }
    }
  }
}

// ---------------------------------------------------------------------------
// K3a / K3b (verified round 7).
// ---------------------------------------------------------------------------
__global__ __launch_bounds__(256) void k3a(
    const float* __restrict__ cls_feat, const float* __restrict__ kw1,
    const float* __restrict__ kg1, const float* __restrict__ kb1,
    const float* __restrict__ vw, const float* __restrict__ vg,
    const float* __restrict__ vb, float* __restrict__ h1g,
    float* __restrict__ Vcls) {
  int bk = blockIdx.y;
  int b = bk / NK, kc = bk % NK;
  int q = blockIdx.x;
  __shared__ float cf[CIN];
  int tid = threadIdx.x;
  const float* row = cls_feat + (size_t)bk * CIN;
  for (int i = tid; i < CIN; i += 256) cf[i] = row[i];
  __syncthreads();
  int o = tid >> 1, half = tid & 1;
  int col = q * 64 + (o & 63);
  const float* w =
      (o < 64) ? &kw1[(size_t)col * CIN] : &vw[(size_t)col * CIN];
  int base = half * 256;
  float acc[4] = {0.f, 0.f, 0.f, 0.f};
#pragma unroll 8
  for (int i = 0; i < 64; ++i) {
    float4 w4 = *(const float4*)&w[base + i * 4];
    const float* c4 = &cf[base + i * 4];
    acc[i & 3] += w4.x * c4[0] + w4.y * c4[1] + w4.z * c4[2] + w4.w * c4[3];
  }
  float s = (acc[0] + acc[1]) + (acc[2] + acc[3]);
  s += __shfl_xor(s, 1);
  if (half == 0) {
    if (o < 64) {
      h1g[(size_t)bk * CTC + col] = fmaxf(s * kg1[col] + kb1[col], 0.f);
    } else {
      Vcls[((size_t)b * CTC + col) * NK + kc] =
          fmaxf(s * vg[col] + vb[col], 0.f);
    }
  }
}

__global__ __launch_bounds__(256) void k3b(
    const float* __restrict__ h1g, const float* __restrict__ kw2,
    const float* __restrict__ kg2, const float* __restrict__ kb2,
    unsigned short* __restrict__ KclsT) {
  int bk = blockIdx.y;
  int q = blockIdx.x;
  __shared__ float h1[CTC];
  int tid = threadIdx.x;
  const float* row = h1g + (size_t)bk * CTC;
  if (tid < CTC) h1[tid] = row[tid];
  __syncthreads();
  int o = tid >> 2, part = tid & 3;
  int col = q * 64 + o;
  const float* w = &kw2[(size_t)col * CTC + part * 64];
  const float* c = &h1[part * 64];
  float acc[4] = {0.f, 0.f, 0.f, 0.f};
#pragma unroll
  for (int i = 0; i < 16; ++i) {
    float4 w4 = *(const float4*)&w[i * 4];
    acc[i & 3] += w4.x * c[i * 4] + w4.y * c[i * 4 + 1] + w4.z * c[i * 4 + 2] +
                  w4.w * c[i * 4 + 3];
  }
  float s = (acc[0] + acc[1]) + (acc[2] + acc[3]);
  s += __shfl_xor(s, 1);
  s += __shfl_xor(s, 2);
  if (part == 0)
    KclsT[(size_t)bk * CTC + col] = f2bf(fmaxf(s * kg2[col] + kb2[col], 0.f));
}

// ---------------------------------------------------------------------------
// MFMA GEMM (verified): used for gemm1 (KD=512, outmode 1) and out-proj
// (KD=256, outmode 0).
// ---------------------------------------------------------------------------
template <int KD>
__global__ __launch_bounds__(256) void gemm_mfma(
    const unsigned short* __restrict__ A, const unsigned short* __restrict__ Wb,
    const float* __restrict__ g, const float* __restrict__ bb,
    void* __restrict__ Y, int M, int outmode) {
  __shared__ __align__(16) unsigned short As[2][128 * 32];
  __shared__ __align__(16) unsigned short Bs[2][128 * 32];
  int b = blockIdx.z;
  int n0 = blockIdx.x * 128;
  int m0 = blockIdx.y * 128;
  int tid = threadIdx.x;
  int l = tid & 63, wid = tid >> 6;
  int wr = wid >> 1, wc = wid & 1;
  const unsigned short* Ab = A + (size_t)b * HW * KD;

  f32x4 acc[4][4];
#pragma unroll
  for (int i = 0; i < 4; ++i)
#pragma unroll
    for (int j = 0; j < 4; ++j) acc[i][j] = (f32x4){0.f, 0.f, 0.f, 0.f};

  const int NT = KD / 32;
  auto STAGE = [&](int buf, int t) {
    int k0 = t * 32;
#pragma unroll
    for (int q = 0; q < 2; ++q) {
      int e = q * 2048 + tid * 8;
      int rl = e >> 5, sl = (e >> 3) & 3;
      gload16(Ab + (size_t)(n0 + rl) * KD + k0 + 8 * (sl ^ ((rl >> 1) & 3)),
              &As[buf][q * 2048 + wid * 512]);
    }
#pragma unroll
    for (int q = 0; q < 2; ++q) {
      int e = q * 2048 + tid * 8;
      int rl = e >> 5, sl = (e >> 3) & 3;
      gload16(Wb + (size_t)(m0 + rl) * KD + k0 + 8 * (sl ^ ((rl >> 1) & 3)),
              &Bs[buf][q * 2048 + wid * 512]);
    }
  };
  STAGE(0, 0);
  for (int t = 0; t < NT; ++t) {
    __syncthreads();
    if (t + 1 < NT) STAGE((t + 1) & 1, t + 1);
    int cur = t & 1;
    short8 af[4], bf[4];
#pragma unroll
    for (int f = 0; f < 4; ++f) {
      int nl = wr * 64 + f * 16 + (l & 15);
      af[f] = *(const short8*)&As[cur][nl * 32 + 8 * ((l >> 4) ^ ((nl >> 1) & 3))];
      int ml = wc * 64 + f * 16 + (l & 15);
      bf[f] = *(const short8*)&Bs[cur][ml * 32 + 8 * ((l >> 4) ^ ((ml >> 1) & 3))];
    }
#pragma unroll
    for (int i = 0; i < 4; ++i)
#pragma unroll
      for (int j = 0; j < 4; ++j)
        acc[i][j] =
            __builtin_amdgcn_mfma_f32_16x16x32_bf16(af[i], bf[j], acc[i][j], 0, 0, 0);
  }
  if (outmode == 0) {
    float* Yf = (float*)Y + (size_t)b * M * HW;
#pragma unroll
    for (int j = 0; j < 4; ++j) {
      int m = m0 + wc * 64 + j * 16 + (l & 15);
      float gm = g[m], bm = bb[m];
#pragma unroll
      for (int i = 0; i < 4; ++i) {
        int n = n0 + wr * 64 + i * 16 + (l >> 4) * 4;
        float4 o;
        o.x = fmaxf(acc[i][j][0] * gm + bm, 0.f);
        o.y = fmaxf(acc[i][j][1] * gm + bm, 0.f);
        o.z = fmaxf(acc[i][j][2] * gm + bm, 0.f);
        o.w = fmaxf(acc[i][j][3] * gm + bm, 0.f);
        *(float4*)&Yf[(size_t)m * HW + n] = o;
      }
    }
  } else {
    unsigned short* Yt = (unsigned short*)Y + (size_t)b * HW * M;
#pragma unroll
    for (int j = 0; j < 4; ++j) {
      int m = m0 + wc * 64 + j * 16 + (l & 15);
      float gm = g[m], bm = bb[m];
#pragma unroll
      for (int i = 0; i < 4; ++i) {
        int n = n0 + wr * 64 + i * 16 + (l >> 4) * 4;
#pragma unroll
        for (int r = 0; r < 4; ++r)
          Yt[(size_t)(n + r) * M + m] = f2bf(fmaxf(acc[i][j][r] * gm + bm, 0.f));
      }
    }
  }
}

// ---------------------------------------------------------------------------
// FUSED g2k5: q2 = relu(g2*(W2·q1)+b2) computed per 128-pixel block for ALL
// 256 channels (acc[2][16], 4 waves = 32-pixel strips), bounced to LDS Qf in
// k5's verified chunk-swizzle layout, then sim -> softmax -> PV -> ctxT.
// q2 never touches HBM. ctxT-overlays-q1T is safe: each (b,p) row is fully
// read (K-loop) before the same block overwrites it (ctxT epilogue).
// ---------------------------------------------------------------------------
__global__ __launch_bounds__(256, 1) void g2k5(
    const unsigned short* __restrict__ q1T, const unsigned short* __restrict__ W2,
    const float* __restrict__ g2, const float* __restrict__ b2,
    const unsigned short* __restrict__ KclsT, const float* __restrict__ Vcls,
    const float* __restrict__ countf, unsigned short* __restrict__ ctxT) {
  __shared__ __align__(16) char RC[49152];  // As(16K)+Bs(32K) | simT+Pl overlay
  __shared__ __align__(16) unsigned short Qf[8][4096];  // 64 KB q2 tile
  __shared__ __align__(16) unsigned short Kl2[32 * 32 * 8];  // 16 KB
  __shared__ __align__(16) unsigned short Vl2[4 * 256 * 8];  // 16 KB
  __shared__ float cntl[NK];
  unsigned short* As = (unsigned short*)RC;            // [2][128*32]
  unsigned short* Bs = (unsigned short*)(RC + 16384);  // [2][256*32]
  float* simT = (float*)RC;                            // phase-2 overlay
  unsigned short* Pl = (unsigned short*)(RC + 16896);

  int b = blockIdx.y;
  int p0 = blockIdx.x * 128;
  int tid = threadIdx.x;
  int l = tid & 63, w = tid >> 6;
  const unsigned short* q1b = q1T + ((size_t)b * HW + p0) * CTC;

  // stage Kcls/Vcls/count (independent; visible after first barrier)
  for (int i = tid; i < NK * 32; i += 256) {
    int m = i >> 5, s = i & 31;
    short8 v = *(const short8*)&KclsT[((size_t)b * NK + m) * CTC + s * 8];
    *(short8*)&Kl2[(s * 32 + m) * 8] = v;
  }
  for (int i = tid; i < 4 * 256; i += 256) {
    int s = i >> 8, c = i & 255;
    union { short8 v; unsigned short u[8]; } pk;
    const float* vr = &Vcls[((size_t)b * CTC + c) * NK];
#pragma unroll
    for (int j = 0; j < 8; ++j) {
      int k = s * 8 + j;
      pk.u[j] = (k < NK) ? f2bf(vr[k]) : (unsigned short)0;
    }
    *(short8*)&Vl2[(s * 256 + c) * 8] = pk.v;
  }
  if (tid < NK) cntl[tid] = countf[b * NK + tid];

  // ---- stage 1: q2 tile GEMM (128 p x 256 m, K=256) ----
  auto STAGE_A = [&](int buf, int t) {
    int k0 = t * 32;
#pragma unroll
    for (int q = 0; q < 2; ++q) {
      int e = q * 2048 + tid * 8;
      int rl = e >> 5, sl = (e >> 3) & 3;
      gload16(q1b + (size_t)rl * CTC + k0 + 8 * (sl ^ ((rl >> 1) & 3)),
              &As[buf * 4096 + q * 2048 + w * 512]);
    }
  };
  auto STAGE_B = [&](int buf, int t) {
    int k0 = t * 32;
#pragma unroll
    for (int q = 0; q < 4; ++q) {
      int e = q * 2048 + tid * 8;
      int rl = e >> 5, sl = (e >> 3) & 3;
      gload16(W2 + (size_t)rl * CTC + k0 + 8 * (sl ^ ((rl >> 1) & 3)),
              &Bs[buf * 8192 + q * 2048 + w * 512]);
    }
  };
  f32x4 acc[2][16];
#pragma unroll
  for (int i = 0; i < 2; ++i)
#pragma unroll
    for (int j = 0; j < 16; ++j) acc[i][j] = (f32x4){0.f, 0.f, 0.f, 0.f};
  STAGE_A(0, 0);
  STAGE_B(0, 0);
  for (int t = 0; t < 8; ++t) {
    __syncthreads();
    if (t + 1 < 8) { STAGE_A((t + 1) & 1, t + 1); STAGE_B((t + 1) & 1, t + 1); }
    int cur = t & 1;
    short8 af[2];
#pragma unroll
    for (int f = 0; f < 2; ++f) {
      int nl = w * 32 + f * 16 + (l & 15);
      af[f] =
          *(const short8*)&As[cur * 4096 + nl * 32 + 8 * ((l >> 4) ^ ((nl >> 1) & 3))];
    }
#pragma unroll
    for (int mf = 0; mf < 16; ++mf) {
      int ml = mf * 16 + (l & 15);
      short8 bf =
          *(const short8*)&Bs[cur * 8192 + ml * 32 + 8 * ((l >> 4) ^ ((ml >> 1) & 3))];
      acc[0][mf] =
          __builtin_amdgcn_mfma_f32_16x16x32_bf16(af[0], bf, acc[0][mf], 0, 0, 0);
      acc[1][mf] =
          __builtin_amdgcn_mfma_f32_16x16x32_bf16(af[1], bf, acc[1][mf], 0, 0, 0);
    }
  }
  // epilogue: relu + bf16 -> Qf (k5's chunk-swizzle layout)
#pragma unroll
  for (int mf = 0; mf < 16; ++mf) {
    int ch = mf * 16 + (l & 15);
    float gm = g2[ch], bm = b2[ch];
    int tq = ch >> 5, slot = (ch >> 3) & 3, wi = ch & 7;
#pragma unroll
    for (int i = 0; i < 2; ++i) {
#pragma unroll
      for (int r = 0; r < 4; ++r) {
        int p = w * 32 + i * 16 + (l >> 4) * 4 + r;
        Qf[tq][p * 32 + 8 * (slot ^ ((p >> 1) & 3)) + wi] =
            f2bf(fmaxf(acc[i][mf][r] * gm + bm, 0.f));
      }
    }
  }
  __syncthreads();  // Qf complete (and all As/Bs reads long done)

  // ---- stage 2: sim = q2 . Kcls (verified k5 body, Qf-sourced) ----
  f32x4 a2[2][2];
#pragma unroll
  for (int i = 0; i < 2; ++i)
#pragma unroll
    for (int j = 0; j < 2; ++j) a2[i][j] = (f32x4){0.f, 0.f, 0.f, 0.f};
  for (int t = 0; t < 8; ++t) {
    short8 aq[2], bk[2];
#pragma unroll
    for (int f = 0; f < 2; ++f) {
      int nl = w * 32 + f * 16 + (l & 15);
      aq[f] = *(const short8*)&Qf[t][nl * 32 + 8 * ((l >> 4) ^ ((nl >> 1) & 3))];
      int s = t * 4 + (l >> 4);
      int ml = f * 16 + (l & 15);
      bk[f] = *(const short8*)&Kl2[(s * 32 + ml) * 8];
    }
#pragma unroll
    for (int i = 0; i < 2; ++i)
#pragma unroll
      for (int j = 0; j < 2; ++j)
        a2[i][j] =
            __builtin_amdgcn_mfma_f32_16x16x32_bf16(aq[i], bk[j], a2[i][j], 0, 0, 0);
  }
  __syncthreads();  // RC (As/Bs) dead -> becomes simT/Pl
#pragma unroll
  for (int i = 0; i < 2; ++i)
#pragma unroll
    for (int j = 0; j < 2; ++j) {
      int m = j * 16 + (l & 15);
      if (m < NK) {
#pragma unroll
        for (int r = 0; r < 4; ++r) {
          int p = w * 32 + i * 16 + (l >> 4) * 4 + r;
          simT[p * 33 + m] = a2[i][j][r];
        }
      }
    }
  __syncthreads();
  if (tid < 128) {
    float sims[NK];
#pragma unroll
    for (int k = 0; k < NK; ++k) sims[k] = simT[tid * 33 + k] * 0.0625f;
    float m = -1e30f;
#pragma unroll
    for (int k = 0; k < NK; ++k)
      if (cntl[k] > 0.f) m = fmaxf(m, sims[k]);
    float d = 0.f;
#pragma unroll
    for (int k = 0; k < NK; ++k) {
      float e = (cntl[k] > 0.f) ? expf(sims[k] - m) : 0.f;
      sims[k] = cntl[k] * e;
      d += sims[k];
    }
    float inv = 1.f / d;
#pragma unroll
    for (int s = 0; s < 4; ++s) {
      union { short8 v; unsigned short u8[8]; } pk;
#pragma unroll
      for (int j = 0; j < 8; ++j) {
        int k = s * 8 + j;
        pk.u8[j] = (k < NK) ? f2bf(sims[k] * inv) : (unsigned short)0;
      }
      *(short8*)&Pl[(s * 128 + tid) * 8] = pk.v;
    }
  }
  __syncthreads();
  short8 ap[2];
#pragma unroll
  for (int f = 0; f < 2; ++f) {
    int nl = w * 32 + f * 16 + (l & 15);
    ap[f] = *(const short8*)&Pl[((l >> 4) * 128 + nl) * 8];
  }
  unsigned short* cb = ctxT + ((size_t)b * HW + p0) * CTC;
#pragma unroll
  for (int mc = 0; mc < 4; ++mc) {
#pragma unroll
    for (int mf = 0; mf < 4; ++mf) {
      int ml = mc * 64 + mf * 16 + (l & 15);
      short8 bv = *(const short8*)&Vl2[((l >> 4) * 256 + ml) * 8];
#pragma unroll
      for (int nf = 0; nf < 2; ++nf) {
        f32x4 z = {0.f, 0.f, 0.f, 0.f};
        f32x4 o = __builtin_amdgcn_mfma_f32_16x16x32_bf16(ap[nf], bv, z, 0, 0, 0);
#pragma unroll
        for (int r = 0; r < 4; ++r) {
          int p = w * 32 + nf * 16 + (l >> 4) * 4 + r;
          cb[(size_t)p * CTC + ml] = f2bf(o[r]);
        }
      }
    }
  }
}

// ---------------------------------------------------------------------------
extern "C" void kernel_launch(void* const* d_in, const int* in_sizes, int n_in,
                              void* d_out, int out_size, void* d_ws, size_t ws_size,
                              hipStream_t stream) {
  const float* x = (const float*)d_in[0];
  const float* preds = (const float*)d_in[1];
  const float* q_w1 = (const float*)d_in[3];
  const float* q_g1 = (const float*)d_in[4];
  const float* q_b1 = (const float*)d_in[5];
  const float* q_w2 = (const float*)d_in[6];
  const float* q_g2 = (const float*)d_in[7];
  const float* q_b2 = (const float*)d_in[8];
  const float* k_w1 = (const float*)d_in[9];
  const float* k_g1 = (const float*)d_in[10];
  const float* k_b1 = (const float*)d_in[11];
  const float* k_w2 = (const float*)d_in[12];
  const float* k_g2 = (const float*)d_in[13];
  const float* k_b2 = (const float*)d_in[14];
  const float* v_w = (const float*)d_in[15];
  const float* v_g = (const float*)d_in[16];
  const float* v_b = (const float*)d_in[17];
  const float* o_w = (const float*)d_in[18];
  const float* o_g = (const float*)d_in[19];
  const float* o_b = (const float*)d_in[20];
  float* out = (float*)d_out;

  char* base = (char*)d_ws;
  unsigned short* xT = (unsigned short*)base;               // 33,554,432 B
  unsigned short* q1T = (unsigned short*)(base + 33554432); // 16,777,216 B
  unsigned short* ctxT = q1T;                               // overlay (safe, see g2k5)
  char* f32r = base + 50331648;
  unsigned short* wgtP = (unsigned short*)f32r;              // 2,097,152 B
  float* countf = (float*)(f32r + 2097152);                  // 1,024 B
  float* cls_feat = (float*)(f32r + 2098176);                // 311,296 B
  unsigned short* KclsT = (unsigned short*)(f32r + 2409472); // 77,824 B
  float* Vcls = (float*)(f32r + 2487296);                    // 155,648 B
  unsigned short* wb1 = (unsigned short*)(f32r + 2642944);   // 262,144 B
  unsigned short* wb2 = (unsigned short*)(f32r + 2905088);   // 131,072 B
  unsigned short* wbo = (unsigned short*)(f32r + 3036160);   // 262,144 B
  float* h1g = (float*)(f32r + 3298304);                     // 155,648 B
  float* bestg = (float*)(f32r + 3453952);                   // 131,072 B
  int* clsg = (int*)(f32r + 3585024);                        // 131,072 B
  unsigned int* Mu_g = (unsigned int*)(f32r + 3716096);      // 1,024 B
  unsigned int* cnt_g = (unsigned int*)(f32r + 3717120);     // 1,024 B
  float* Zf_g = (float*)(f32r + 3718144);                    // 1,024 B

  wconv<<<320, 256, 0, stream>>>(q_w1, q_w2, o_w, wb1, wb2, wbo,
                                 (uint4*)wgtP, (uint4*)cls_feat, (uint4*)Mu_g);
  k1a<<<dim3(16, NB), 256, 0, stream>>>(preds, bestg, clsg, Mu_g, cnt_g);
  k1b<<<dim3(16, NB), 256, 0, stream>>>(bestg, clsg, Mu_g, Zf_g);
  k1c<<<dim3(16, NB), 256, 0, stream>>>(bestg, clsg, Zf_g, cnt_g, wgtP,
                                        countf);
  xk2<<<dim3(8, 8, NB), 256, 0, stream>>>(x, wgtP, xT, cls_feat);
  k3a<<<dim3(4, NB * NK), 256, 0, stream>>>(cls_feat, k_w1, k_g1, k_b1, v_w,
                                            v_g, v_b, h1g, Vcls);
  k3b<<<dim3(4, NB * NK), 256, 0, stream>>>(h1g, k_w2, k_g2, k_b2, KclsT);
  gemm_mfma<CIN><<<dim3(32, 2, NB), 256, 0, stream>>>(xT, wb1, q_g1, q_b1,
                                                      (void*)q1T, CTC, 1);
  g2k5<<<dim3(HW / 128, NB), 256, 0, stream>>>(q1T, wb2, q_g2, q_b2, KclsT,
                                               Vcls, countf, ctxT);
  gemm_mfma<CTC><<<dim3(32, 4, NB), 256, 0, stream>>>(ctxT, wbo, o_g, o_b,
                                                      (void*)out, CIN, 0);
}

// Round 12
// 127.370 us; speedup vs baseline: 3.9108x; 1.0412x over previous
//
#include <hip/hip_runtime.h>
#include <math.h>

#define HW 4096
#define NB 8
#define NK 19
#define CIN 512
#define CTC 256

typedef __attribute__((ext_vector_type(8))) short short8;
typedef __attribute__((ext_vector_type(4))) float f32x4;

__device__ inline unsigned short f2bf(float x) {
  unsigned u = __float_as_uint(x);
  return (unsigned short)((u + 0x7fffu + ((u >> 16) & 1u)) >> 16);  // RNE
}
__device__ inline float bf2f(unsigned short h) {
  return __uint_as_float(((unsigned)h) << 16);
}
__device__ inline void gload16(const void* g, void* l) {
  __builtin_amdgcn_global_load_lds(
      (const __attribute__((address_space(1))) void*)g,
      (__attribute__((address_space(3))) void*)l, 16, 0, 0);
}

// ---------------------------------------------------------------------------
// wk1a: blocks [0,320) = weight f32->bf16 convert + cls_feat zero-fill;
// blocks [320,448) = k1a per-256-pixel argmax, writing per-block partials
// Mu_part/cnt_part[b][16][32] (every slot written -> no pre-zero needed).
// The two halves are independent (safe in one dispatch).
// ---------------------------------------------------------------------------
__global__ __launch_bounds__(256) void wk1a(
    const float* __restrict__ w1, const float* __restrict__ w2,
    const float* __restrict__ wo, unsigned short* __restrict__ wb1,
    unsigned short* __restrict__ wb2, unsigned short* __restrict__ wbo,
    uint4* __restrict__ cls_feat_z, const float* __restrict__ preds,
    float* __restrict__ bestg, int* __restrict__ clsg,
    unsigned int* __restrict__ Mu_part, unsigned int* __restrict__ cnt_part) {
  __shared__ unsigned int Mw[NK];
  __shared__ unsigned int Cw[NK];
  int bx = blockIdx.x;
  int tid = threadIdx.x;
  if (bx < 320) {
    int gid = bx * 256 + tid;
    int i = gid * 4;  // [0, 327680)
    const float* src;
    unsigned short* dst;
    int off;
    if (i < 131072) { src = w1; dst = wb1; off = i; }
    else if (i < 196608) { src = w2; dst = wb2; off = i - 131072; }
    else { src = wo; dst = wbo; off = i - 196608; }
    float4 v = *(const float4*)(src + off);
    dst[off + 0] = f2bf(v.x);
    dst[off + 1] = f2bf(v.y);
    dst[off + 2] = f2bf(v.z);
    dst[off + 3] = f2bf(v.w);
    uint4 z = {0u, 0u, 0u, 0u};
    for (int j = gid; j < 19456; j += 81920) cls_feat_z[j] = z;  // cls_feat
  } else {
    int bq = bx - 320;
    int b = bq >> 4, pblk = bq & 15;
    if (tid < NK) { Mw[tid] = 0u; Cw[tid] = 0u; }
    __syncthreads();
    int p = pblk * 256 + tid;
    const float* pb = preds + (size_t)b * NK * HW;
    float best = pb[p];
    int bi = 0;
#pragma unroll
    for (int k = 1; k < NK; ++k) {
      float v = pb[k * HW + p];
      if (v > best) { best = v; bi = k; }  // strict > = jnp.argmax first-index
    }
    bestg[b * HW + p] = best;
    clsg[b * HW + p] = bi;
    unsigned fb = __float_as_uint(best);
    unsigned key = (fb & 0x80000000u) ? ~fb : (fb | 0x80000000u);
    atomicMax(&Mw[bi], key);
    atomicAdd(&Cw[bi], 1u);
    __syncthreads();
    if (tid < 32) {
      Mu_part[(b * 16 + pblk) * 32 + tid] = (tid < NK) ? Mw[tid] : 0u;
      cnt_part[(b * 16 + pblk) * 32 + tid] = (tid < NK) ? Cw[tid] : 0u;
    }
  }
}

// ---------------------------------------------------------------------------
// k1b: reduce Mu parts -> Mf; e = exp(best - Mf[cls]) in-place into bestg;
// per-class LDS sum -> Zf_part[b][16][32] (every slot written).
// ---------------------------------------------------------------------------
__global__ __launch_bounds__(256) void k1b(
    float* __restrict__ bestg, const int* __restrict__ clsg,
    const unsigned int* __restrict__ Mu_part, float* __restrict__ Zf_part) {
  int b = blockIdx.y, pblk = blockIdx.x;
  int tid = threadIdx.x;
  __shared__ float Mf[NK];
  __shared__ float Zw[NK];
  if (tid < NK) {
    unsigned key = 0u;
#pragma unroll
    for (int j = 0; j < 16; ++j) {
      unsigned v = Mu_part[(b * 16 + j) * 32 + tid];
      key = (v > key) ? v : key;
    }
    float m = -1e30f;
    if (key) {
      unsigned fb = (key & 0x80000000u) ? (key & 0x7fffffffu) : ~key;
      m = __uint_as_float(fb);
    }
    Mf[tid] = m;
    Zw[tid] = 0.f;
  }
  __syncthreads();
  int p = pblk * 256 + tid;
  int c = clsg[b * HW + p];
  float e = expf(bestg[b * HW + p] - Mf[c]);
  bestg[b * HW + p] = e;
  atomicAdd(&Zw[c], e);
  __syncthreads();
  if (tid < 32) Zf_part[(b * 16 + pblk) * 32 + tid] = (tid < NK) ? Zw[tid] : 0.f;
}

// ---------------------------------------------------------------------------
// FUSED xk2 (round-10-verified loop body): x read once -> xT transpose +
// cls_feat MFMA. NEW: Bs scatter tile computed inline from eg/clsg/Zf_part
// (wgtP never materialized in HBM).
// ---------------------------------------------------------------------------
__global__ __launch_bounds__(256) void xk2(
    const float* __restrict__ x, const float* __restrict__ eg,
    const int* __restrict__ clsg, const float* __restrict__ Zf_part,
    unsigned short* __restrict__ xT, float* __restrict__ cls_feat) {
  __shared__ float tile[64][65];
  __shared__ unsigned short Bs[32 * 516];
  __shared__ float Zl[NK];
  int b = blockIdx.z, c0 = blockIdx.y * 64, pbase = blockIdx.x * 512;
  int tid = threadIdx.x;
  int l = tid & 63, w = tid >> 6;
  // reduce Zf parts; zero Bs
  if (tid < NK) {
    float s = 0.f;
#pragma unroll
    for (int j = 0; j < 16; ++j) s += Zf_part[(b * 16 + j) * 32 + tid];
    Zl[tid] = s;
  }
  {
    uint4 z = {0u, 0u, 0u, 0u};
    for (int i = tid; i < 2064; i += 256) ((uint4*)Bs)[i] = z;  // 33024 B
  }
  __syncthreads();
  // scatter: Bs[cls(p)][p_local] = e/Z (rows for absent classes stay 0)
  for (int i = tid; i < 512; i += 256) {
    int c = clsg[b * HW + pbase + i];
    Bs[c * 516 + i] = f2bf(eg[b * HW + pbase + i] / Zl[c]);
  }
  f32x4 acc[2];
  acc[0] = (f32x4){0.f, 0.f, 0.f, 0.f};
  acc[1] = (f32x4){0.f, 0.f, 0.f, 0.f};
  int cbase = w * 16;
  for (int s = 0; s < 8; ++s) {
    int ps = pbase + s * 64;
    __syncthreads();  // Bs scatter visible (s=0); prev sub-tile consumed
#pragma unroll
    for (int r = 0; r < 4; ++r) {
      int cl = r * 16 + (tid >> 4);
      int pl = (tid & 15) * 4;
      float4 v = *(const float4*)&x[((size_t)b * CIN + c0 + cl) * HW + ps + pl];
      tile[cl][pl + 0] = v.x;
      tile[cl][pl + 1] = v.y;
      tile[cl][pl + 2] = v.z;
      tile[cl][pl + 3] = v.w;
    }
    __syncthreads();
#pragma unroll
    for (int j = 0; j < 16; ++j) {
      int ploc = j * 4 + w;
      xT[((size_t)b * HW + ps + ploc) * CIN + c0 + l] = f2bf(tile[l][ploc]);
    }
#pragma unroll
    for (int ch = 0; ch < 2; ++ch) {
      int pt = ch * 32 + (l >> 4) * 8;
      union { short8 v; unsigned short u[8]; } af;
      const float* tp = &tile[cbase + (l & 15)][pt];
#pragma unroll
      for (int j = 0; j < 8; ++j) af.u[j] = f2bf(tp[j]);
      int pg = s * 64 + pt;
#pragma unroll
      for (int mf = 0; mf < 2; ++mf) {
        short8 bf = *(const short8*)&Bs[(mf * 16 + (l & 15)) * 516 + pg];
        acc[mf] =
            __builtin_amdgcn_mfma_f32_16x16x32_bf16(af.v, bf, acc[mf], 0, 0, 0);
      }
    }
  }
#pragma unroll
  for (int mf = 0; mf < 2; ++mf) {
    int k = mf * 16 + (l & 15);
    if (k < NK) {
#pragma unroll
      for (int r = 0; r < 4; ++r) {
        int c = c0 + cbase + (l >> 4) * 4 + r;
        atomicAdd(&cls_feat[((size_t)b * NK + k) * CIN + c], acc[mf][r]);
      }
    }
  }
}

// ---------------------------------------------------------------------------
// K3a / K3b (verified round 7).
// ---------------------------------------------------------------------------
__global__ __launch_bounds__(256) void k3a(
    const float* __restrict__ cls_feat, const float* __restrict__ kw1,
    const float* __restrict__ kg1, const float* __restrict__ kb1,
    const float* __restrict__ vw, const float* __restrict__ vg,
    const float* __restrict__ vb, float* __restrict__ h1g,
    float* __restrict__ Vcls) {
  int bk = blockIdx.y;
  int b = bk / NK, kc = bk % NK;
  int q = blockIdx.x;
  __shared__ float cf[CIN];
  int tid = threadIdx.x;
  const float* row = cls_feat + (size_t)bk * CIN;
  for (int i = tid; i < CIN; i += 256) cf[i] = row[i];
  __syncthreads();
  int o = tid >> 1, half = tid & 1;
  int col = q * 64 + (o & 63);
  const float* w =
      (o < 64) ? &kw1[(size_t)col * CIN] : &vw[(size_t)col * CIN];
  int base = half * 256;
  float acc[4] = {0.f, 0.f, 0.f, 0.f};
#pragma unroll 8
  for (int i = 0; i < 64; ++i) {
    float4 w4 = *(const float4*)&w[base + i * 4];
    const float* c4 = &cf[base + i * 4];
    acc[i & 3] += w4.x * c4[0] + w4.y * c4[1] + w4.z * c4[2] + w4.w * c4[3];
  }
  float s = (acc[0] + acc[1]) + (acc[2] + acc[3]);
  s += __shfl_xor(s, 1);
  if (half == 0) {
    if (o < 64) {
      h1g[(size_t)bk * CTC + col] = fmaxf(s * kg1[col] + kb1[col], 0.f);
    } else {
      Vcls[((size_t)b * CTC + col) * NK + kc] =
          fmaxf(s * vg[col] + vb[col], 0.f);
    }
  }
}

__global__ __launch_bounds__(256) void k3b(
    const float* __restrict__ h1g, const float* __restrict__ kw2,
    const float* __restrict__ kg2, const float* __restrict__ kb2,
    unsigned short* __restrict__ KclsT) {
  int bk = blockIdx.y;
  int q = blockIdx.x;
  __shared__ float h1[CTC];
  int tid = threadIdx.x;
  const float* row = h1g + (size_t)bk * CTC;
  if (tid < CTC) h1[tid] = row[tid];
  __syncthreads();
  int o = tid >> 2, part = tid & 3;
  int col = q * 64 + o;
  const float* w = &kw2[(size_t)col * CTC + part * 64];
  const float* c = &h1[part * 64];
  float acc[4] = {0.f, 0.f, 0.f, 0.f};
#pragma unroll
  for (int i = 0; i < 16; ++i) {
    float4 w4 = *(const float4*)&w[i * 4];
    acc[i & 3] += w4.x * c[i * 4] + w4.y * c[i * 4 + 1] + w4.z * c[i * 4 + 2] +
                  w4.w * c[i * 4 + 3];
  }
  float s = (acc[0] + acc[1]) + (acc[2] + acc[3]);
  s += __shfl_xor(s, 1);
  s += __shfl_xor(s, 2);
  if (part == 0)
    KclsT[(size_t)bk * CTC + col] = f2bf(fmaxf(s * kg2[col] + kb2[col], 0.f));
}

// ---------------------------------------------------------------------------
// MFMA GEMM (verified): gemm1 (KD=512, outmode 1) and out-proj (KD=256, 0).
// ---------------------------------------------------------------------------
template <int KD>
__global__ __launch_bounds__(256) void gemm_mfma(
    const unsigned short* __restrict__ A, const unsigned short* __restrict__ Wb,
    const float* __restrict__ g, const float* __restrict__ bb,
    void* __restrict__ Y, int M, int outmode) {
  __shared__ __align__(16) unsigned short As[2][128 * 32];
  __shared__ __align__(16) unsigned short Bs[2][128 * 32];
  int b = blockIdx.z;
  int n0 = blockIdx.x * 128;
  int m0 = blockIdx.y * 128;
  int tid = threadIdx.x;
  int l = tid & 63, wid = tid >> 6;
  int wr = wid >> 1, wc = wid & 1;
  const unsigned short* Ab = A + (size_t)b * HW * KD;

  f32x4 acc[4][4];
#pragma unroll
  for (int i = 0; i < 4; ++i)
#pragma unroll
    for (int j = 0; j < 4; ++j) acc[i][j] = (f32x4){0.f, 0.f, 0.f, 0.f};

  const int NT = KD / 32;
  auto STAGE = [&](int buf, int t) {
    int k0 = t * 32;
#pragma unroll
    for (int q = 0; q < 2; ++q) {
      int e = q * 2048 + tid * 8;
      int rl = e >> 5, sl = (e >> 3) & 3;
      gload16(Ab + (size_t)(n0 + rl) * KD + k0 + 8 * (sl ^ ((rl >> 1) & 3)),
              &As[buf][q * 2048 + wid * 512]);
    }
#pragma unroll
    for (int q = 0; q < 2; ++q) {
      int e = q * 2048 + tid * 8;
      int rl = e >> 5, sl = (e >> 3) & 3;
      gload16(Wb + (size_t)(m0 + rl) * KD + k0 + 8 * (sl ^ ((rl >> 1) & 3)),
              &Bs[buf][q * 2048 + wid * 512]);
    }
  };
  STAGE(0, 0);
  for (int t = 0; t < NT; ++t) {
    __syncthreads();
    if (t + 1 < NT) STAGE((t + 1) & 1, t + 1);
    int cur = t & 1;
    short8 af[4], bf[4];
#pragma unroll
    for (int f = 0; f < 4; ++f) {
      int nl = wr * 64 + f * 16 + (l & 15);
      af[f] = *(const short8*)&As[cur][nl * 32 + 8 * ((l >> 4) ^ ((nl >> 1) & 3))];
      int ml = wc * 64 + f * 16 + (l & 15);
      bf[f] = *(const short8*)&Bs[cur][ml * 32 + 8 * ((l >> 4) ^ ((ml >> 1) & 3))];
    }
#pragma unroll
    for (int i = 0; i < 4; ++i)
#pragma unroll
      for (int j = 0; j < 4; ++j)
        acc[i][j] =
            __builtin_amdgcn_mfma_f32_16x16x32_bf16(af[i], bf[j], acc[i][j], 0, 0, 0);
  }
  if (outmode == 0) {
    float* Yf = (float*)Y + (size_t)b * M * HW;
#pragma unroll
    for (int j = 0; j < 4; ++j) {
      int m = m0 + wc * 64 + j * 16 + (l & 15);
      float gm = g[m], bm = bb[m];
#pragma unroll
      for (int i = 0; i < 4; ++i) {
        int n = n0 + wr * 64 + i * 16 + (l >> 4) * 4;
        float4 o;
        o.x = fmaxf(acc[i][j][0] * gm + bm, 0.f);
        o.y = fmaxf(acc[i][j][1] * gm + bm, 0.f);
        o.z = fmaxf(acc[i][j][2] * gm + bm, 0.f);
        o.w = fmaxf(acc[i][j][3] * gm + bm, 0.f);
        *(float4*)&Yf[(size_t)m * HW + n] = o;
      }
    }
  } else {
    unsigned short* Yt = (unsigned short*)Y + (size_t)b * HW * M;
#pragma unroll
    for (int j = 0; j < 4; ++j) {
      int m = m0 + wc * 64 + j * 16 + (l & 15);
      float gm = g[m], bm = bb[m];
#pragma unroll
      for (int i = 0; i < 4; ++i) {
        int n = n0 + wr * 64 + i * 16 + (l >> 4) * 4;
#pragma unroll
        for (int r = 0; r < 4; ++r)
          Yt[(size_t)(n + r) * M + m] = f2bf(fmaxf(acc[i][j][r] * gm + bm, 0.f));
      }
    }
  }
}

// ---------------------------------------------------------------------------
// FUSED g2k5 (verified round 11); cntl now reduced from cnt_part.
// ---------------------------------------------------------------------------
__global__ __launch_bounds__(256, 1) void g2k5(
    const unsigned short* __restrict__ q1T, const unsigned short* __restrict__ W2,
    const float* __restrict__ g2, const float* __restrict__ b2,
    const unsigned short* __restrict__ KclsT, const float* __restrict__ Vcls,
    const unsigned int* __restrict__ cnt_part, unsigned short* __restrict__ ctxT) {
  __shared__ __align__(16) char RC[49152];
  __shared__ __align__(16) unsigned short Qf[8][4096];
  __shared__ __align__(16) unsigned short Kl2[32 * 32 * 8];
  __shared__ __align__(16) unsigned short Vl2[4 * 256 * 8];
  __shared__ float cntl[NK];
  unsigned short* As = (unsigned short*)RC;
  unsigned short* Bs = (unsigned short*)(RC + 16384);
  float* simT = (float*)RC;
  unsigned short* Pl = (unsigned short*)(RC + 16896);

  int b = blockIdx.y;
  int p0 = blockIdx.x * 128;
  int tid = threadIdx.x;
  int l = tid & 63, w = tid >> 6;
  const unsigned short* q1b = q1T + ((size_t)b * HW + p0) * CTC;

  for (int i = tid; i < NK * 32; i += 256) {
    int m = i >> 5, s = i & 31;
    short8 v = *(const short8*)&KclsT[((size_t)b * NK + m) * CTC + s * 8];
    *(short8*)&Kl2[(s * 32 + m) * 8] = v;
  }
  for (int i = tid; i < 4 * 256; i += 256) {
    int s = i >> 8, c = i & 255;
    union { short8 v; unsigned short u[8]; } pk;
    const float* vr = &Vcls[((size_t)b * CTC + c) * NK];
#pragma unroll
    for (int j = 0; j < 8; ++j) {
      int k = s * 8 + j;
      pk.u[j] = (k < NK) ? f2bf(vr[k]) : (unsigned short)0;
    }
    *(short8*)&Vl2[(s * 256 + c) * 8] = pk.v;
  }
  if (tid < NK) {
    unsigned int s = 0u;
#pragma unroll
    for (int j = 0; j < 16; ++j) s += cnt_part[(b * 16 + j) * 32 + tid];
    cntl[tid] = (float)s;
  }

  auto STAGE_A = [&](int buf, int t) {
    int k0 = t * 32;
#pragma unroll
    for (int q = 0; q < 2; ++q) {
      int e = q * 2048 + tid * 8;
      int rl = e >> 5, sl = (e >> 3) & 3;
      gload16(q1b + (size_t)rl * CTC + k0 + 8 * (sl ^ ((rl >> 1) & 3)),
              &As[buf * 4096 + q * 2048 + w * 512]);
    }
  };
  auto STAGE_B = [&](int buf, int t) {
    int k0 = t * 32;
#pragma unroll
    for (int q = 0; q < 4; ++q) {
      int e = q * 2048 + tid * 8;
      int rl = e >> 5, sl = (e >> 3) & 3;
      gload16(W2 + (size_t)rl * CTC + k0 + 8 * (sl ^ ((rl >> 1) & 3)),
              &Bs[buf * 8192 + q * 2048 + w * 512]);
    }
  };
  f32x4 acc[2][16];
#pragma unroll
  for (int i = 0; i < 2; ++i)
#pragma unroll
    for (int j = 0; j < 16; ++j) acc[i][j] = (f32x4){0.f, 0.f, 0.f, 0.f};
  STAGE_A(0, 0);
  STAGE_B(0, 0);
  for (int t = 0; t < 8; ++t) {
    __syncthreads();
    if (t + 1 < 8) { STAGE_A((t + 1) & 1, t + 1); STAGE_B((t + 1) & 1, t + 1); }
    int cur = t & 1;
    short8 af[2];
#pragma unroll
    for (int f = 0; f < 2; ++f) {
      int nl = w * 32 + f * 16 + (l & 15);
      af[f] =
          *(const short8*)&As[cur * 4096 + nl * 32 + 8 * ((l >> 4) ^ ((nl >> 1) & 3))];
    }
#pragma unroll
    for (int mf = 0; mf < 16; ++mf) {
      int ml = mf * 16 + (l & 15);
      short8 bf =
          *(const short8*)&Bs[cur * 8192 + ml * 32 + 8 * ((l >> 4) ^ ((ml >> 1) & 3))];
      acc[0][mf] =
          __builtin_amdgcn_mfma_f32_16x16x32_bf16(af[0], bf, acc[0][mf], 0, 0, 0);
      acc[1][mf] =
          __builtin_amdgcn_mfma_f32_16x16x32_bf16(af[1], bf, acc[1][mf], 0, 0, 0);
    }
  }
#pragma unroll
  for (int mf = 0; mf < 16; ++mf) {
    int ch = mf * 16 + (l & 15);
    float gm = g2[ch], bm = b2[ch];
    int tq = ch >> 5, slot = (ch >> 3) & 3, wi = ch & 7;
#pragma unroll
    for (int i = 0; i < 2; ++i) {
#pragma unroll
      for (int r = 0; r < 4; ++r) {
        int p = w * 32 + i * 16 + (l >> 4) * 4 + r;
        Qf[tq][p * 32 + 8 * (slot ^ ((p >> 1) & 3)) + wi] =
            f2bf(fmaxf(acc[i][mf][r] * gm + bm, 0.f));
      }
    }
  }
  __syncthreads();

  f32x4 a2[2][2];
#pragma unroll
  for (int i = 0; i < 2; ++i)
#pragma unroll
    for (int j = 0; j < 2; ++j) a2[i][j] = (f32x4){0.f, 0.f, 0.f, 0.f};
  for (int t = 0; t < 8; ++t) {
    short8 aq[2], bk[2];
#pragma unroll
    for (int f = 0; f < 2; ++f) {
      int nl = w * 32 + f * 16 + (l & 15);
      aq[f] = *(const short8*)&Qf[t][nl * 32 + 8 * ((l >> 4) ^ ((nl >> 1) & 3))];
      int s = t * 4 + (l >> 4);
      int ml = f * 16 + (l & 15);
      bk[f] = *(const short8*)&Kl2[(s * 32 + ml) * 8];
    }
#pragma unroll
    for (int i = 0; i < 2; ++i)
#pragma unroll
      for (int j = 0; j < 2; ++j)
        a2[i][j] =
            __builtin_amdgcn_mfma_f32_16x16x32_bf16(aq[i], bk[j], a2[i][j], 0, 0, 0);
  }
  __syncthreads();
#pragma unroll
  for (int i = 0; i < 2; ++i)
#pragma unroll
    for (int j = 0; j < 2; ++j) {
      int m = j * 16 + (l & 15);
      if (m < NK) {
#pragma unroll
        for (int r = 0; r < 4; ++r) {
          int p = w * 32 + i * 16 + (l >> 4) * 4 + r;
          simT[p * 33 + m] = a2[i][j][r];
        }
      }
    }
  __syncthreads();
  if (tid < 128) {
    float sims[NK];
#pragma unroll
    for (int k = 0; k < NK; ++k) sims[k] = simT[tid * 33 + k] * 0.0625f;
    float m = -1e30f;
#pragma unroll
    for (int k = 0; k < NK; ++k)
      if (cntl[k] > 0.f) m = fmaxf(m, sims[k]);
    float d = 0.f;
#pragma unroll
    for (int k = 0; k < NK; ++k) {
      float e = (cntl[k] > 0.f) ? expf(sims[k] - m) : 0.f;
      sims[k] = cntl[k] * e;
      d += sims[k];
    }
    float inv = 1.f / d;
#pragma unroll
    for (int s = 0; s < 4; ++s) {
      union { short8 v; unsigned short u8[8]; } pk;
#pragma unroll
      for (int j = 0; j < 8; ++j) {
        int k = s * 8 + j;
        pk.u8[j] = (k < NK) ? f2bf(sims[k] * inv) : (unsigned short)0;
      }
      *(short8*)&Pl[(s * 128 + tid) * 8] = pk.v;
    }
  }
  __syncthreads();
  short8 ap[2];
#pragma unroll
  for (int f = 0; f < 2; ++f) {
    int nl = w * 32 + f * 16 + (l & 15);
    ap[f] = *(const short8*)&Pl[((l >> 4) * 128 + nl) * 8];
  }
  unsigned short* cb = ctxT + ((size_t)b * HW + p0) * CTC;
#pragma unroll
  for (int mc = 0; mc < 4; ++mc) {
#pragma unroll
    for (int mf = 0; mf < 4; ++mf) {
      int ml = mc * 64 + mf * 16 + (l & 15);
      short8 bv = *(const short8*)&Vl2[((l >> 4) * 256 + ml) * 8];
#pragma unroll
      for (int nf = 0; nf < 2; ++nf) {
        f32x4 z = {0.f, 0.f, 0.f, 0.f};
        f32x4 o = __builtin_amdgcn_mfma_f32_16x16x32_bf16(ap[nf], bv, z, 0, 0, 0);
#pragma unroll
        for (int r = 0; r < 4; ++r) {
          int p = w * 32 + nf * 16 + (l >> 4) * 4 + r;
          cb[(size_t)p * CTC + ml] = f2bf(o[r]);
        }
      }
    }
  }
}

// ---------------------------------------------------------------------------
extern "C" void kernel_launch(void* const* d_in, const int* in_sizes, int n_in,
                              void* d_out, int out_size, void* d_ws, size_t ws_size,
                              hipStream_t stream) {
  const float* x = (const float*)d_in[0];
  const float* preds = (const float*)d_in[1];
  const float* q_w1 = (const float*)d_in[3];
  const float* q_g1 = (const float*)d_in[4];
  const float* q_b1 = (const float*)d_in[5];
  const float* q_w2 = (const float*)d_in[6];
  const float* q_g2 = (const float*)d_in[7];
  const float* q_b2 = (const float*)d_in[8];
  const float* k_w1 = (const float*)d_in[9];
  const float* k_g1 = (const float*)d_in[10];
  const float* k_b1 = (const float*)d_in[11];
  const float* k_w2 = (const float*)d_in[12];
  const float* k_g2 = (const float*)d_in[13];
  const float* k_b2 = (const float*)d_in[14];
  const float* v_w = (const float*)d_in[15];
  const float* v_g = (const float*)d_in[16];
  const float* v_b = (const float*)d_in[17];
  const float* o_w = (const float*)d_in[18];
  const float* o_g = (const float*)d_in[19];
  const float* o_b = (const float*)d_in[20];
  float* out = (float*)d_out;

  char* base = (char*)d_ws;
  unsigned short* xT = (unsigned short*)base;               // 33,554,432 B
  unsigned short* q1T = (unsigned short*)(base + 33554432); // 16,777,216 B
  unsigned short* ctxT = q1T;                               // overlay (safe, see g2k5)
  char* f32r = base + 50331648;
  float* cls_feat = (float*)f32r;                            // 311,296 B
  unsigned short* KclsT = (unsigned short*)(f32r + 311296);  // 77,824 B
  float* Vcls = (float*)(f32r + 389120);                     // 155,648 B
  unsigned short* wb1 = (unsigned short*)(f32r + 544768);    // 262,144 B
  unsigned short* wb2 = (unsigned short*)(f32r + 806912);    // 131,072 B
  unsigned short* wbo = (unsigned short*)(f32r + 937984);    // 262,144 B
  float* h1g = (float*)(f32r + 1200128);                     // 155,648 B
  float* bestg = (float*)(f32r + 1355776);                   // 131,072 B
  int* clsg = (int*)(f32r + 1486848);                        // 131,072 B
  unsigned int* Mu_part = (unsigned int*)(f32r + 1617920);   // 16,384 B
  unsigned int* cnt_part = (unsigned int*)(f32r + 1634304);  // 16,384 B
  float* Zf_part = (float*)(f32r + 1650688);                 // 16,384 B

  wk1a<<<448, 256, 0, stream>>>(q_w1, q_w2, o_w, wb1, wb2, wbo,
                                (uint4*)cls_feat, preds, bestg, clsg, Mu_part,
                                cnt_part);
  k1b<<<dim3(16, NB), 256, 0, stream>>>(bestg, clsg, Mu_part, Zf_part);
  xk2<<<dim3(8, 8, NB), 256, 0, stream>>>(x, bestg, clsg, Zf_part, xT,
                                          cls_feat);
  k3a<<<dim3(4, NB * NK), 256, 0, stream>>>(cls_feat, k_w1, k_g1, k_b1, v_w,
                                            v_g, v_b, h1g, Vcls);
  k3b<<<dim3(4, NB * NK), 256, 0, stream>>>(h1g, k_w2, k_g2, k_b2, KclsT);
  gemm_mfma<CIN><<<dim3(32, 2, NB), 256, 0, stream>>>(xT, wb1, q_g1, q_b1,
                                                      (void*)q1T, CTC, 1);
  g2k5<<<dim3(HW / 128, NB), 256, 0, stream>>>(q1T, wb2, q_g2, q_b2, KclsT,
                                               Vcls, cnt_part, ctxT);
  gemm_mfma<CTC><<<dim3(32, 4, NB), 256, 0, stream>>>(ctxT, wbo, o_g, o_b,
                                                      (void*)out, CIN, 0);
}